// Round 12
// baseline (1080.095 us; speedup 1.0000x reference)
//
#include <hip/hip_runtime.h>
#include <hip/hip_bf16.h>
#include <hip/hip_fp16.h>

typedef unsigned short u16;
typedef unsigned int u32;
typedef short s16x8 __attribute__((ext_vector_type(8)));
typedef float f32x4 __attribute__((ext_vector_type(4)));

#define FE_LD 2944
#define EDGE_LD 2816

static __device__ __forceinline__ int sdot4(u32 a, u32 b, int acc) {
  return __builtin_amdgcn_sdot4((int)a, (int)b, acc, false);
}
static __device__ __forceinline__ float fsig(float x) {
  return __builtin_amdgcn_rcpf(1.f + __expf(-x));
}
static __device__ __forceinline__ float ftanh(float x) {
  return 1.f - 2.f * __builtin_amdgcn_rcpf(1.f + __expf(2.f * x));
}

#define GLD_LDS16(gsrc, ldst) \
  __builtin_amdgcn_global_load_lds((const __attribute__((address_space(1))) void*)(gsrc), \
                                   (__attribute__((address_space(3))) void*)(ldst), 16, 0, 0)

// ---------------------------------------------------------------------------
// Generic bf16 MFMA GEMM: C[M=4096][N] = A[M][K] * B^T[N][K] (+bias), K%64==0.
// 128x128 tile, 4 waves (2x2), 4x4 frags of 16x16x32.
// Staging: global_load_lds width=16, linear LDS dest + pre-swizzled source.
// ---------------------------------------------------------------------------
__global__ __launch_bounds__(256) void gemm_kernel(
    const u16* __restrict__ A, int lda,
    const u16* __restrict__ B, int ldb,
    int K, int N,
    float* __restrict__ outF, __hip_bfloat16* __restrict__ outB, int ldc,
    const float* __restrict__ bias)
{
  __shared__ __align__(16) u16 As[128*64];
  __shared__ __align__(16) u16 Bs[128*64];
  const int tid = threadIdx.x;
  const int w = tid >> 6, lane = tid & 63;
  const int wm = w >> 1, wn = w & 1;
  const long bm = (long)blockIdx.x * 128;
  const long bn = (long)blockIdx.y * 128;
  f32x4 acc[4][4] = {};

  for (int k0 = 0; k0 < K; k0 += 64) {
    #pragma unroll
    for (int rr = 0; rr < 4; rr++) {
      int idx = rr * 256 + tid;
      int row = idx >> 3;
      int g   = idx & 7;
      int gs  = g ^ (row & 7);                 // pre-swizzled source group
      int ldst = (rr * 256 + (w << 6)) * 8;    // linear wave-uniform dest (elems)
      GLD_LDS16(A + (bm + row) * (long)lda + k0 + gs * 8, &As[ldst]);
      GLD_LDS16(B + (bn + row) * (long)ldb + k0 + gs * 8, &Bs[ldst]);
    }
    __syncthreads();
    #pragma unroll
    for (int kk = 0; kk < 2; kk++) {
      s16x8 af[4], bfr[4];
      #pragma unroll
      for (int i = 0; i < 4; i++) {
        int ra = wm * 64 + i * 16 + (lane & 15);
        int rb = wn * 64 + i * 16 + (lane & 15);
        int gg = kk * 4 + (lane >> 4);
        af[i]  = *(const s16x8*)&As[ra * 64 + ((gg ^ (ra & 7)) << 3)];
        bfr[i] = *(const s16x8*)&Bs[rb * 64 + ((gg ^ (rb & 7)) << 3)];
      }
      #pragma unroll
      for (int i = 0; i < 4; i++)
        #pragma unroll
        for (int j = 0; j < 4; j++)
          acc[i][j] = __builtin_amdgcn_mfma_f32_16x16x32_bf16(af[i], bfr[j], acc[i][j], 0, 0, 0);
    }
    __syncthreads();
  }

  #pragma unroll
  for (int i = 0; i < 4; i++)
    #pragma unroll
    for (int j = 0; j < 4; j++)
      #pragma unroll
      for (int v = 0; v < 4; v++) {
        long rr = bm + wm * 64 + i * 16 + (lane >> 4) * 4 + v;
        int  cc = (int)bn + wn * 64 + j * 16 + (lane & 15);
        if (cc < N) {
          float val = acc[i][j][v] + (bias ? bias[cc] : 0.f);
          if (outF) outF[rr * (long)ldc + cc] = val;
          else      outB[rr * (long)ldc + cc] = __float2bfloat16(val);
        }
      }
}

// ---------------------------------------------------------------------------
// Tiled transpose + cast fp32 -> bf16, zero pad, optional row remap.
// dst[n][k] = src[srck][n]
// ---------------------------------------------------------------------------
__global__ void transpose_cast(const float* __restrict__ src, __hip_bfloat16* __restrict__ dst,
                               int srcK, int srcN, int dstR, int dstC, int split, int split_off)
{
  __shared__ float tile[32][33];
  const int kt = blockIdx.x * 32, nt = blockIdx.y * 32;
  const int tx = threadIdx.x & 31, ty = threadIdx.x >> 5;
  for (int i = ty; i < 32; i += 8) {
    int k = kt + i;
    int srck = (k < split) ? (split_off + k) : (k - split);
    int n = nt + tx;
    tile[i][tx] = (srck < srcK && n < srcN) ? src[(size_t)srck * srcN + n] : 0.f;
  }
  __syncthreads();
  for (int i = ty; i < 32; i += 8) {
    int n = nt + i, k = kt + tx;
    if (n < dstR && k < dstC)
      dst[(size_t)n * dstC + k] = __float2bfloat16(tile[tx][i]);
  }
}

// ---------------------------------------------------------------------------
// Quantize whh fp32 [2][256][1024] -> i8, kg-split, 40reg/24lds layout.
// col = c4*256 + j; slot = kg*256 + j. Per (gate c4, kg): 16 u32 k-words.
//   gates 0,1: words 0..11 -> registers, 12..15 -> LDS uint4 q={0,1}
//   gates 2,3: words 0..7  -> registers, 8..15  -> LDS uint4 q={2,3},{4,5}
//   wreg[(d*40 + rb[c4]+w)*1024 + slot], rb = {0,12,24,32}
//   wsc[d*1024+col] = maxabs/(127*127)  (un-scales w-quant AND h-quant)
// ---------------------------------------------------------------------------
__global__ void pack_whh(const float* __restrict__ whh, u32* __restrict__ wreg,
                         u32* __restrict__ wlds, float* __restrict__ wsc)
{
  const int idx = blockIdx.x * 256 + threadIdx.x;   // 0..2047
  const int d = idx >> 10, col = idx & 1023;
  const int c4 = col >> 8, j = col & 255;
  const float* s = whh + (size_t)d * 256 * 1024 + col;
  float mx = 0.f;
  for (int k = 0; k < 256; k++) mx = fmaxf(mx, fabsf(s[(size_t)k * 1024]));
  float inv = (mx > 0.f) ? 127.f / mx : 0.f;
  wsc[d * 1024 + col] = (mx > 0.f) ? mx / (127.f * 127.f) : 0.f;
  const int rc = (c4 < 2) ? 12 : 8;
  const int rb = (c4 == 0) ? 0 : (c4 == 1) ? 12 : (c4 == 2) ? 24 : 32;
  for (int kg = 0; kg < 4; kg++) {
    const int slot = kg * 256 + j;
    for (int w = 0; w < 16; w++) {
      u32 v = 0;
      #pragma unroll
      for (int b = 0; b < 4; b++) {
        int q = __float2int_rn(s[(size_t)(kg * 64 + 4 * w + b) * 1024] * inv);
        q = max(-127, min(127, q));
        v |= ((u32)(q & 0xff)) << (8 * b);
      }
      if (w < rc) {
        wreg[(size_t)(d * 40 + rb + w) * 1024 + slot] = v;
      } else {
        int qq, comp;
        if (c4 == 0)      { qq = 0; comp = w - 12; }
        else if (c4 == 1) { qq = 1; comp = w - 12; }
        else if (c4 == 2) { qq = 2 + ((w - 8) >> 2); comp = (w - 8) & 3; }
        else              { qq = 4 + ((w - 8) >> 2); comp = (w - 8) & 3; }
        wlds[((size_t)(d * 6 + qq) * 1024 + slot) * 4 + comp] = v;
      }
    }
  }
}

// ---------------------------------------------------------------------------
// prep: softmax(151), probs->bf16 (padded 192), conf=max(probs[1:]),
// pos = relu(BN(center_size(boxes)) @ pos_w + pos_b), fmaps -> FE bf16.
// FE layout: [enc 0..512 | fmaps 512..2560 | embed 2560..2760 | pos 2760..2888 | pad]
// ---------------------------------------------------------------------------
__global__ void prep_kernel(
    const float* __restrict__ logits, const float* __restrict__ fmaps,
    const float* __restrict__ boxes,
    const float* __restrict__ bn_g, const float* __restrict__ bn_b,
    const float* __restrict__ bn_m, const float* __restrict__ bn_v,
    const float* __restrict__ pos_w, const float* __restrict__ pos_b,
    __hip_bfloat16* __restrict__ FE, __hip_bfloat16* __restrict__ probsb,
    float* __restrict__ conf)
{
  __shared__ float red[256];
  const int row = blockIdx.x, t = threadIdx.x;
  float v = (t < 151) ? logits[(size_t)row * 151 + t] : -3.0e38f;
  red[t] = v; __syncthreads();
  for (int s = 128; s > 0; s >>= 1) { if (t < s) red[t] = fmaxf(red[t], red[t + s]); __syncthreads(); }
  float mx = red[0]; __syncthreads();
  float p = (t < 151) ? expf(v - mx) : 0.f;
  red[t] = p; __syncthreads();
  for (int s = 128; s > 0; s >>= 1) { if (t < s) red[t] += red[t + s]; __syncthreads(); }
  float sum = red[0]; __syncthreads();
  p = p / sum;
  if (t < 192) probsb[(size_t)row * 192 + t] = __float2bfloat16((t < 151) ? p : 0.f);
  red[t] = (t >= 1 && t < 151) ? p : 0.f; __syncthreads();
  for (int s = 128; s > 0; s >>= 1) { if (t < s) red[t] = fmaxf(red[t], red[t + s]); __syncthreads(); }
  if (t == 0) conf[row] = red[0];

  if (t < 128) {
    float x1 = boxes[row * 4 + 0], y1 = boxes[row * 4 + 1];
    float x2 = boxes[row * 4 + 2], y2 = boxes[row * 4 + 3];
    float cs[4] = { (x1 + x2) * 0.5f, (y1 + y2) * 0.5f, x2 - x1, y2 - y1 };
    float a = pos_b[t];
    #pragma unroll
    for (int j = 0; j < 4; j++) {
      float cn = (cs[j] - bn_m[j]) * rsqrtf(bn_v[j] + 1e-5f) * bn_g[j] + bn_b[j];
      a += cn * pos_w[j * 128 + t];
    }
    FE[(size_t)row * FE_LD + 2760 + t] = __float2bfloat16(fmaxf(a, 0.f));
  }
  for (int c0 = t; c0 < 2048; c0 += 256)
    FE[(size_t)row * FE_LD + 512 + c0] = __float2bfloat16(fmaps[(size_t)row * 2048 + c0]);
}

// ---------------------------------------------------------------------------
// Per-image bitonic sort of conf desc (tie: index asc) -> perm (global rows).
// ---------------------------------------------------------------------------
__global__ void sort_kernel(const float* __restrict__ conf, int* __restrict__ perm)
{
  __shared__ float key[128];
  __shared__ int   idx[128];
  const int b = blockIdx.x, t = threadIdx.x;
  key[t] = conf[b * 128 + t]; idx[t] = t;
  __syncthreads();
  for (int k = 2; k <= 128; k <<= 1)
    for (int j = k >> 1; j > 0; j >>= 1) {
      int ixj = t ^ j;
      if (ixj > t) {
        bool up = (t & k) == 0;
        float ka = key[t], kb = key[ixj];
        int ia = idx[t], ib = idx[ixj];
        bool before = (ka > kb) || (ka == kb && ia < ib); // desc, stable
        if (before != up) { key[t] = kb; key[ixj] = ka; idx[t] = ib; idx[ixj] = ia; }
      }
      __syncthreads();
    }
  perm[b * 128 + t] = b * 128 + idx[t];
}

// ---------------------------------------------------------------------------
// LSTM scan, i8 weights, kg-split, 40 resident weight regs. 64 blocks =
// (img 32) x (dir 2), 1024 threads. Thread (kg=tid>>8, j=tid&255): int
// partials of 4 gates of h-dim j over k in [kg*64, kg*64+64).
// Weights: 40 u32 pinned VGPR + 24 u32 (6 uint4) in LDS (96 KB).
// Partials: int4 part[j*5+kg] (stride-5, conflict-free). P is bf16.
// ---------------------------------------------------------------------------
__global__ __launch_bounds__(1024) void rec_kernel(
    const __hip_bfloat16* __restrict__ P, // [4096][2048] pre-activations (+bias)
    const int* __restrict__ perm,         // [4096] global rows
    const u32* __restrict__ wreg_g,       // [2][40][1024]
    const uint4* __restrict__ wlds_g,     // [2][6][1024]
    const float* __restrict__ wsc_g,      // [2][1024]
    int gatherPerm, int outPerm,
    __hip_bfloat16* __restrict__ out_bf, int out_ld,
    float* __restrict__ out_f32, int f32_ld, int f32_off)
{
  __shared__ __align__(16) uint4 wt4[6 * 1024];    // 96 KB (k tails per col)
  __shared__ __align__(16) int4 part[256 * 5];     // 20 KB  [j][kg], stride 5
  __shared__ __align__(16) u32 hq[64];             // 256 i8 of h
  __shared__ int prow_lds[128];
  const int tid = threadIdx.x;
  const int kg = tid >> 8;
  const int img = blockIdx.x & 31, dir = blockIdx.x >> 5;

  u32 wv[40];
  {
    const u32* rp = wreg_g + (size_t)dir * 40960 + tid;
    #pragma unroll
    for (int i = 0; i < 40; i++) wv[i] = rp[(size_t)i * 1024];
  }
  #pragma unroll
  for (int i = 0; i < 40; i++) asm volatile("" : "+v"(wv[i]));   // forbid remat
  {
    const uint4* lp = wlds_g + (size_t)dir * 6144 + tid;
    #pragma unroll
    for (int q = 0; q < 6; q++) wt4[q * 1024 + tid] = lp[(size_t)q * 1024];
  }
  if (tid < 128) prow_lds[tid] = perm[img * 128 + tid];
  if (tid < 64) hq[tid] = 0;

  float sc0 = 0.f, sc1 = 0.f, sc2 = 0.f, sc3 = 0.f, cst = 0.f;
  if (tid < 256) {
    const float* sp = wsc_g + dir * 1024 + tid;
    sc0 = sp[0]; sc1 = sp[256]; sc2 = sp[512]; sc3 = sp[768];
  }
  __syncthreads();

  const uint4* hq4 = (const uint4*)hq;

  int st = dir ? 127 : 0;
  float p0 = 0.f, p1 = 0.f, p2 = 0.f, p3 = 0.f;
  if (tid < 256) {
    int prow0 = gatherPerm ? prow_lds[st] : (img * 128 + st);
    const __hip_bfloat16* pp = P + (size_t)prow0 * 2048 + dir * 1024 + tid;
    p0 = __bfloat162float(pp[0]);   p1 = __bfloat162float(pp[256]);
    p2 = __bfloat162float(pp[512]); p3 = __bfloat162float(pp[768]);
  }

  for (int t = 0; t < 128; t++) {
    float n0 = 0.f, n1 = 0.f, n2 = 0.f, n3 = 0.f;
    if (tid < 256 && t < 127) {
      int stn = dir ? (126 - t) : (t + 1);
      int prn = gatherPerm ? prow_lds[stn] : (img * 128 + stn);
      const __hip_bfloat16* pp = P + (size_t)prn * 2048 + dir * 1024 + tid;
      n0 = __bfloat162float(pp[0]);   n1 = __bfloat162float(pp[256]);
      n2 = __bfloat162float(pp[512]); n3 = __bfloat162float(pp[768]);
    }

    int a0 = 0, a1 = 0, a2 = 0, a3 = 0;
    {
      uint4 hv = hq4[kg * 4 + 0];         // k-words 0..3
      a0 = sdot4(hv.x, wv[0], a0);  a0 = sdot4(hv.y, wv[1], a0);
      a0 = sdot4(hv.z, wv[2], a0);  a0 = sdot4(hv.w, wv[3], a0);
      a1 = sdot4(hv.x, wv[12], a1); a1 = sdot4(hv.y, wv[13], a1);
      a1 = sdot4(hv.z, wv[14], a1); a1 = sdot4(hv.w, wv[15], a1);
      a2 = sdot4(hv.x, wv[24], a2); a2 = sdot4(hv.y, wv[25], a2);
      a2 = sdot4(hv.z, wv[26], a2); a2 = sdot4(hv.w, wv[27], a2);
      a3 = sdot4(hv.x, wv[32], a3); a3 = sdot4(hv.y, wv[33], a3);
      a3 = sdot4(hv.z, wv[34], a3); a3 = sdot4(hv.w, wv[35], a3);
    }
    {
      uint4 hv = hq4[kg * 4 + 1];         // k-words 4..7
      a0 = sdot4(hv.x, wv[4], a0);  a0 = sdot4(hv.y, wv[5], a0);
      a0 = sdot4(hv.z, wv[6], a0);  a0 = sdot4(hv.w, wv[7], a0);
      a1 = sdot4(hv.x, wv[16], a1); a1 = sdot4(hv.y, wv[17], a1);
      a1 = sdot4(hv.z, wv[18], a1); a1 = sdot4(hv.w, wv[19], a1);
      a2 = sdot4(hv.x, wv[28], a2); a2 = sdot4(hv.y, wv[29], a2);
      a2 = sdot4(hv.z, wv[30], a2); a2 = sdot4(hv.w, wv[31], a2);
      a3 = sdot4(hv.x, wv[36], a3); a3 = sdot4(hv.y, wv[37], a3);
      a3 = sdot4(hv.z, wv[38], a3); a3 = sdot4(hv.w, wv[39], a3);
    }
    {
      uint4 hv = hq4[kg * 4 + 2];         // k-words 8..11
      a0 = sdot4(hv.x, wv[8], a0);  a0 = sdot4(hv.y, wv[9], a0);
      a0 = sdot4(hv.z, wv[10], a0); a0 = sdot4(hv.w, wv[11], a0);
      a1 = sdot4(hv.x, wv[20], a1); a1 = sdot4(hv.y, wv[21], a1);
      a1 = sdot4(hv.z, wv[22], a1); a1 = sdot4(hv.w, wv[23], a1);
      uint4 wl = wt4[2 * 1024 + tid];     // gate2 words 8..11
      a2 = sdot4(hv.x, wl.x, a2); a2 = sdot4(hv.y, wl.y, a2);
      a2 = sdot4(hv.z, wl.z, a2); a2 = sdot4(hv.w, wl.w, a2);
      wl = wt4[4 * 1024 + tid];           // gate3 words 8..11
      a3 = sdot4(hv.x, wl.x, a3); a3 = sdot4(hv.y, wl.y, a3);
      a3 = sdot4(hv.z, wl.z, a3); a3 = sdot4(hv.w, wl.w, a3);
    }
    {
      uint4 hv = hq4[kg * 4 + 3];         // k-words 12..15
      uint4 wl = wt4[0 * 1024 + tid];     // gate0 words 12..15
      a0 = sdot4(hv.x, wl.x, a0); a0 = sdot4(hv.y, wl.y, a0);
      a0 = sdot4(hv.z, wl.z, a0); a0 = sdot4(hv.w, wl.w, a0);
      wl = wt4[1 * 1024 + tid];           // gate1 words 12..15
      a1 = sdot4(hv.x, wl.x, a1); a1 = sdot4(hv.y, wl.y, a1);
      a1 = sdot4(hv.z, wl.z, a1); a1 = sdot4(hv.w, wl.w, a1);
      wl = wt4[3 * 1024 + tid];           // gate2 words 12..15
      a2 = sdot4(hv.x, wl.x, a2); a2 = sdot4(hv.y, wl.y, a2);
      a2 = sdot4(hv.z, wl.z, a2); a2 = sdot4(hv.w, wl.w, a2);
      wl = wt4[5 * 1024 + tid];           // gate3 words 12..15
      a3 = sdot4(hv.x, wl.x, a3); a3 = sdot4(hv.y, wl.y, a3);
      a3 = sdot4(hv.z, wl.z, a3); a3 = sdot4(hv.w, wl.w, a3);
    }

    part[(tid & 255) * 5 + kg] = int4{a0, a1, a2, a3};
    __syncthreads();

    if (tid < 256) {
      int4 q0 = part[tid * 5 + 0], q1 = part[tid * 5 + 1];
      int4 q2 = part[tid * 5 + 2], q3 = part[tid * 5 + 3];
      float gi = (float)(q0.x + q1.x + q2.x + q3.x) * sc0 + p0;
      float gf = (float)(q0.y + q1.y + q2.y + q3.y) * sc1 + p1;
      float gg = (float)(q0.z + q1.z + q2.z + q3.z) * sc2 + p2;
      float go = (float)(q0.w + q1.w + q2.w + q3.w) * sc3 + p3;
      float si = fsig(gi), sf = fsig(gf), so = fsig(go);
      cst = sf * cst + si * ftanh(gg);
      float h = so * ftanh(cst);
      int qi = __float2int_rn(h * 127.f);
      ((signed char*)hq)[tid] = (signed char)qi;
      const int orow = outPerm ? prow_lds[st] : (img * 128 + st);
      if (out_bf)  out_bf[(size_t)orow * out_ld + dir * 256 + tid] = __float2bfloat16(h);
      if (out_f32) out_f32[(size_t)orow * f32_ld + f32_off + dir * 256 + tid] = h;
    }
    __syncthreads();
    p0 = n0; p1 = n1; p2 = n2; p3 = n3;
    st = dir ? (st - 1) : (st + 1);
  }
}

// ---------------------------------------------------------------------------
// argmax over obj_dists[:,1:151) -> preds (first max wins, like jnp.argmax)
// ---------------------------------------------------------------------------
__global__ void argmax_kernel(const float* __restrict__ dists, int* __restrict__ preds)
{
  const int row = blockIdx.x * 4 + (threadIdx.x >> 6);
  const int lane = threadIdx.x & 63;
  float best = -3.4e38f; int bi = 1000;
  for (int cc = 1 + lane; cc < 151; cc += 64) {
    float v = dists[(size_t)row * 663 + cc];
    if (v > best) { best = v; bi = cc; }
  }
  for (int off = 32; off > 0; off >>= 1) {
    float ov = __shfl_down(best, off);
    int   oi = __shfl_down(bi, off);
    if (ov > best || (ov == best && oi < bi)) { best = ov; bi = oi; }
  }
  if (lane == 0) preds[row] = bi;
}

// ---------------------------------------------------------------------------
// edge_in = [embed2[pred] (200) | enc (512, from FE) | fmaps (2048)] bf16
// ---------------------------------------------------------------------------
__global__ void edge_build(const int* __restrict__ preds,
                           const float* __restrict__ embed2,
                           const float* __restrict__ fmaps,
                           const __hip_bfloat16* __restrict__ FE,
                           __hip_bfloat16* __restrict__ EDGE)
{
  const int row = blockIdx.x, t = threadIdx.x;
  const int pr = preds[row];
  for (int c0 = t; c0 < 200; c0 += 256)
    EDGE[(size_t)row * EDGE_LD + c0] = __float2bfloat16(embed2[(size_t)pr * 200 + c0]);
  for (int c0 = t; c0 < 512; c0 += 256)
    EDGE[(size_t)row * EDGE_LD + 200 + c0] = FE[(size_t)row * FE_LD + c0];
  for (int c0 = t; c0 < 2048; c0 += 256)
    EDGE[(size_t)row * EDGE_LD + 712 + c0] = __float2bfloat16(fmaps[(size_t)row * 2048 + c0]);
}

// ---------------------------------------------------------------------------
extern "C" void kernel_launch(void* const* d_in, const int* in_sizes, int n_in,
                              void* d_out, int out_size, void* d_ws, size_t ws_size,
                              hipStream_t stream)
{
  const float* obj_fmaps    = (const float*)d_in[0];
  const float* obj_logits   = (const float*)d_in[1];
  const float* boxes        = (const float*)d_in[2];
  const float* obj_embed_w  = (const float*)d_in[4];
  const float* obj_embed2_w = (const float*)d_in[5];
  const float* bn_g = (const float*)d_in[6];
  const float* bn_b = (const float*)d_in[7];
  const float* bn_m = (const float*)d_in[8];
  const float* bn_v = (const float*)d_in[9];
  const float* pos_w = (const float*)d_in[10];
  const float* pos_b = (const float*)d_in[11];
  const float* obj_wih0 = (const float*)d_in[12];
  const float* obj_whh0 = (const float*)d_in[13];
  const float* obj_b0   = (const float*)d_in[14];
  const float* obj_wih1 = (const float*)d_in[15];
  const float* obj_whh1 = (const float*)d_in[16];
  const float* obj_b1   = (const float*)d_in[17];
  const float* edge_wih0 = (const float*)d_in[18];
  const float* edge_whh0 = (const float*)d_in[19];
  const float* edge_b0   = (const float*)d_in[20];
  const float* edge_wih1 = (const float*)d_in[21];
  const float* edge_whh1 = (const float*)d_in[22];
  const float* edge_b1   = (const float*)d_in[23];
  const float* dec_w = (const float*)d_in[24];
  const float* dec_b = (const float*)d_in[25];
  float* out = (float*)d_out;

  char* ws = (char*)d_ws;
  auto alloc = [&](size_t bytes) -> char* {
    char* p = ws; ws += (bytes + 255) & ~(size_t)255; return p;
  };
  __hip_bfloat16* FE     = (__hip_bfloat16*)alloc(4096ull * FE_LD * 2);
  __hip_bfloat16* EDGE   = (__hip_bfloat16*)alloc(4096ull * EDGE_LD * 2);
  __hip_bfloat16* Pbuf   = (__hip_bfloat16*)alloc(4096ull * 2048 * 2);
  __hip_bfloat16* hseq   = (__hip_bfloat16*)alloc(4096ull * 512 * 2);
  __hip_bfloat16* probsb = (__hip_bfloat16*)alloc(4096ull * 192 * 2);
  __hip_bfloat16* wih0T  = (__hip_bfloat16*)alloc(2048ull * 2432 * 2);
  __hip_bfloat16* wih1T  = (__hip_bfloat16*)alloc(2048ull * 512 * 2);
  __hip_bfloat16* ewih0T = (__hip_bfloat16*)alloc(2048ull * 2816 * 2);
  __hip_bfloat16* ewih1T = (__hip_bfloat16*)alloc(2048ull * 512 * 2);
  __hip_bfloat16* embedT = (__hip_bfloat16*)alloc(256ull * 192 * 2);
  __hip_bfloat16* decT   = (__hip_bfloat16*)alloc(256ull * 2944 * 2);
  // packed whh set: wreg 81920 u32 | wlds 49152 u32 | wsc 2048 f32
  u32* whh0pk  = (u32*)alloc(133120ull * 4);
  u32* whh1pk  = (u32*)alloc(133120ull * 4);
  u32* ewhh0pk = (u32*)alloc(133120ull * 4);
  u32* ewhh1pk = (u32*)alloc(133120ull * 4);
  int*   perm  = (int*)alloc(4096 * 4);
  float* conf  = (float*)alloc(4096 * 4);
  int*   preds = (int*)alloc(4096 * 4);
  (void)in_sizes; (void)n_in; (void)out_size; (void)ws_size;

  auto tr = [&](const float* src, __hip_bfloat16* dst, int srcK, int srcN,
                int dstR, int dstC, int split, int soff) {
    dim3 g((dstC + 31) / 32, (dstR + 31) / 32);
    transpose_cast<<<g, dim3(256), 0, stream>>>(src, dst, srcK, srcN, dstR, dstC, split, soff);
  };
  for (int d = 0; d < 2; d++) {
    tr(obj_wih0 + (size_t)d * 2376 * 1024, wih0T + (size_t)d * 1024 * 2432, 2376, 1024, 1024, 2432, 0, 0);
    tr(obj_wih1 + (size_t)d * 512 * 1024,  wih1T + (size_t)d * 1024 * 512,  512, 1024, 1024, 512, 0, 0);
    tr(edge_wih0 + (size_t)d * 2760 * 1024, ewih0T + (size_t)d * 1024 * 2816, 2760, 1024, 1024, 2816, 0, 0);
    tr(edge_wih1 + (size_t)d * 512 * 1024,  ewih1T + (size_t)d * 1024 * 512,  512, 1024, 1024, 512, 0, 0);
  }
  tr(obj_embed_w, embedT, 151, 200, 256, 192, 0, 0);
  tr(dec_w, decT, 2888, 151, 256, 2944, 512, 2376);  // [enc|feats] ordering remap

  auto pk = [&](const float* whh, u32* dst) {
    pack_whh<<<dim3(8), dim3(256), 0, stream>>>(whh, dst, dst + 81920, (float*)(dst + 131072));
  };
  pk(obj_whh0, whh0pk); pk(obj_whh1, whh1pk); pk(edge_whh0, ewhh0pk); pk(edge_whh1, ewhh1pk);

  prep_kernel<<<dim3(4096), dim3(256), 0, stream>>>(
      obj_logits, obj_fmaps, boxes, bn_g, bn_b, bn_m, bn_v, pos_w, pos_b, FE, probsb, conf);
  sort_kernel<<<dim3(32), dim3(128), 0, stream>>>(conf, perm);

  auto gemm = [&](const void* A, int lda, const void* B, int ldb, int K, int N,
                  float* oF, __hip_bfloat16* oB, int ldc, const float* bias) {
    dim3 g(32, (N + 127) / 128);
    gemm_kernel<<<g, dim3(256), 0, stream>>>(
        (const u16*)A, lda, (const u16*)B, ldb, K, N, oF, oB, ldc, bias);
  };
  auto rec = [&](const __hip_bfloat16* P, const u32* wpk, int gat, int op,
                 __hip_bfloat16* ob, int old_, float* of, int fld, int foff) {
    rec_kernel<<<dim3(64), dim3(1024), 0, stream>>>(
        P, perm, wpk, (const uint4*)(wpk + 81920), (const float*)(wpk + 131072),
        gat, op, ob, old_, of, fld, foff);
  };

  // obj_embed -> FE cols [2560,2760)
  gemm(probsb, 192, embedT, 192, 192, 200, nullptr, FE + 2560, FE_LD, nullptr);
  // obj layer 0
  gemm((const u16*)FE + 512, FE_LD, wih0T, 2432, 2432, 2048, nullptr, Pbuf, 2048, obj_b0);
  rec(Pbuf, whh0pk, 1, 0, hseq, 512, nullptr, 0, 0);
  // obj layer 1 -> enc into FE cols [0,512)
  gemm(hseq, 512, wih1T, 512, 512, 2048, nullptr, Pbuf, 2048, obj_b1);
  rec(Pbuf, whh1pk, 0, 1, FE, FE_LD, nullptr, 0, 0);
  // decoder -> out cols [0,151)
  gemm(FE, FE_LD, decT, 2944, 2944, 151, out, nullptr, 663, dec_b);
  argmax_kernel<<<dim3(1024), dim3(256), 0, stream>>>(out, preds);
  edge_build<<<dim3(4096), dim3(256), 0, stream>>>(preds, obj_embed2_w, obj_fmaps, FE, EDGE);
  // edge layer 0
  gemm(EDGE, EDGE_LD, ewih0T, 2816, 2816, 2048, nullptr, Pbuf, 2048, edge_b0);
  rec(Pbuf, ewhh0pk, 1, 0, hseq, 512, nullptr, 0, 0);
  // edge layer 1 -> out cols [151,663)
  gemm(hseq, 512, ewih1T, 512, 512, 2048, nullptr, Pbuf, 2048, edge_b1);
  rec(Pbuf, ewhh1pk, 0, 1, nullptr, 0, out, 663, 151);
}

// Round 13
// 869.874 us; speedup vs baseline: 1.2417x; 1.2417x over previous
//
#include <hip/hip_runtime.h>
#include <hip/hip_bf16.h>
#include <hip/hip_fp16.h>

typedef unsigned short u16;
typedef unsigned int u32;
typedef short s16x8 __attribute__((ext_vector_type(8)));
typedef float f32x4 __attribute__((ext_vector_type(4)));

#define FE_LD 2944
#define EDGE_LD 2816

static __device__ __forceinline__ int sdot4(u32 a, u32 b, int acc) {
  return __builtin_amdgcn_sdot4((int)a, (int)b, acc, false);
}
static __device__ __forceinline__ float fsig(float x) {
  return __builtin_amdgcn_rcpf(1.f + __expf(-x));
}
static __device__ __forceinline__ float ftanh(float x) {
  return 1.f - 2.f * __builtin_amdgcn_rcpf(1.f + __expf(2.f * x));
}

#define GLD_LDS16(gsrc, ldst) \
  __builtin_amdgcn_global_load_lds((const __attribute__((address_space(1))) void*)(gsrc), \
                                   (__attribute__((address_space(3))) void*)(ldst), 16, 0, 0)

// ---------------------------------------------------------------------------
// Generic bf16 MFMA GEMM: C[M=4096][N] = A[M][K] * B^T[N][K] (+bias), K%64==0.
// 128x128 tile, 4 waves (2x2), 4x4 frags of 16x16x32.
// Staging: global_load_lds width=16, linear LDS dest + pre-swizzled source.
// ---------------------------------------------------------------------------
__global__ __launch_bounds__(256) void gemm_kernel(
    const u16* __restrict__ A, int lda,
    const u16* __restrict__ B, int ldb,
    int K, int N,
    float* __restrict__ outF, __hip_bfloat16* __restrict__ outB, int ldc,
    const float* __restrict__ bias)
{
  __shared__ __align__(16) u16 As[128*64];
  __shared__ __align__(16) u16 Bs[128*64];
  const int tid = threadIdx.x;
  const int w = tid >> 6, lane = tid & 63;
  const int wm = w >> 1, wn = w & 1;
  const long bm = (long)blockIdx.x * 128;
  const long bn = (long)blockIdx.y * 128;
  f32x4 acc[4][4] = {};

  for (int k0 = 0; k0 < K; k0 += 64) {
    #pragma unroll
    for (int rr = 0; rr < 4; rr++) {
      int idx = rr * 256 + tid;
      int row = idx >> 3;
      int g   = idx & 7;
      int gs  = g ^ (row & 7);                 // pre-swizzled source group
      int ldst = (rr * 256 + (w << 6)) * 8;    // linear wave-uniform dest (elems)
      GLD_LDS16(A + (bm + row) * (long)lda + k0 + gs * 8, &As[ldst]);
      GLD_LDS16(B + (bn + row) * (long)ldb + k0 + gs * 8, &Bs[ldst]);
    }
    __syncthreads();
    #pragma unroll
    for (int kk = 0; kk < 2; kk++) {
      s16x8 af[4], bfr[4];
      #pragma unroll
      for (int i = 0; i < 4; i++) {
        int ra = wm * 64 + i * 16 + (lane & 15);
        int rb = wn * 64 + i * 16 + (lane & 15);
        int gg = kk * 4 + (lane >> 4);
        af[i]  = *(const s16x8*)&As[ra * 64 + ((gg ^ (ra & 7)) << 3)];
        bfr[i] = *(const s16x8*)&Bs[rb * 64 + ((gg ^ (rb & 7)) << 3)];
      }
      #pragma unroll
      for (int i = 0; i < 4; i++)
        #pragma unroll
        for (int j = 0; j < 4; j++)
          acc[i][j] = __builtin_amdgcn_mfma_f32_16x16x32_bf16(af[i], bfr[j], acc[i][j], 0, 0, 0);
    }
    __syncthreads();
  }

  #pragma unroll
  for (int i = 0; i < 4; i++)
    #pragma unroll
    for (int j = 0; j < 4; j++)
      #pragma unroll
      for (int v = 0; v < 4; v++) {
        long rr = bm + wm * 64 + i * 16 + (lane >> 4) * 4 + v;
        int  cc = (int)bn + wn * 64 + j * 16 + (lane & 15);
        if (cc < N) {
          float val = acc[i][j][v] + (bias ? bias[cc] : 0.f);
          if (outF) outF[rr * (long)ldc + cc] = val;
          else      outB[rr * (long)ldc + cc] = __float2bfloat16(val);
        }
      }
}

// ---------------------------------------------------------------------------
// Batched tiled transpose + cast fp32 -> bf16 (10 ops in one launch).
// dst[n][k] = src[srck][n], srck remapped by (split, soff).
// ---------------------------------------------------------------------------
#define N_TROPS 10
struct TrOps {
  const float* src[N_TROPS];
  __hip_bfloat16* dst[N_TROPS];
  int srcK[N_TROPS], srcN[N_TROPS], dstR[N_TROPS], dstC[N_TROPS];
  int split[N_TROPS], soff[N_TROPS];
  int tileBase[N_TROPS], tilesX[N_TROPS];
};
__global__ void transpose_batch(TrOps ops)
{
  __shared__ float tile[32][33];
  int bid = blockIdx.x;
  int op = 0;
  #pragma unroll
  for (int i = 1; i < N_TROPS; i++) if (bid >= ops.tileBase[i]) op = i;
  const int local = bid - ops.tileBase[op];
  const int kt = (local % ops.tilesX[op]) * 32;
  const int nt = (local / ops.tilesX[op]) * 32;
  const float* src = ops.src[op];
  __hip_bfloat16* dst = ops.dst[op];
  const int srcK = ops.srcK[op], srcN = ops.srcN[op];
  const int dstR = ops.dstR[op], dstC = ops.dstC[op];
  const int split = ops.split[op], soff = ops.soff[op];

  const int tx = threadIdx.x & 31, ty = threadIdx.x >> 5;
  for (int i = ty; i < 32; i += 8) {
    int k = kt + i;
    int srck = (k < split) ? (soff + k) : (k - split);
    int n = nt + tx;
    tile[i][tx] = (srck < srcK && n < srcN) ? src[(size_t)srck * srcN + n] : 0.f;
  }
  __syncthreads();
  for (int i = ty; i < 32; i += 8) {
    int n = nt + i, k = kt + tx;
    if (n < dstR && k < dstC)
      dst[(size_t)n * dstC + k] = __float2bfloat16(tile[tx][i]);
  }
}

// ---------------------------------------------------------------------------
// Batched whh quantize (4 sets in one launch, blockIdx.y = set).
// i8, kg-split, 40reg/24lds layout (see R12 comment).
// ---------------------------------------------------------------------------
struct PkOps {
  const float* whh[4];
  u32* wreg[4];
  u32* wlds[4];
  float* wsc[4];
};
__global__ void pack_batch(PkOps ops)
{
  const int set = blockIdx.y;
  const float* whh = ops.whh[set];
  u32* wreg = ops.wreg[set];
  u32* wlds = ops.wlds[set];
  float* wsc = ops.wsc[set];

  const int idx = blockIdx.x * 256 + threadIdx.x;   // 0..2047
  const int d = idx >> 10, col = idx & 1023;
  const int c4 = col >> 8, j = col & 255;
  const float* s = whh + (size_t)d * 256 * 1024 + col;
  float mx = 0.f;
  for (int k = 0; k < 256; k++) mx = fmaxf(mx, fabsf(s[(size_t)k * 1024]));
  float inv = (mx > 0.f) ? 127.f / mx : 0.f;
  wsc[d * 1024 + col] = (mx > 0.f) ? mx / (127.f * 127.f) : 0.f;
  const int rc = (c4 < 2) ? 12 : 8;
  const int rb = (c4 == 0) ? 0 : (c4 == 1) ? 12 : (c4 == 2) ? 24 : 32;
  for (int kg = 0; kg < 4; kg++) {
    const int slot = kg * 256 + j;
    for (int w = 0; w < 16; w++) {
      u32 v = 0;
      #pragma unroll
      for (int b = 0; b < 4; b++) {
        int q = __float2int_rn(s[(size_t)(kg * 64 + 4 * w + b) * 1024] * inv);
        q = max(-127, min(127, q));
        v |= ((u32)(q & 0xff)) << (8 * b);
      }
      if (w < rc) {
        wreg[(size_t)(d * 40 + rb + w) * 1024 + slot] = v;
      } else {
        int qq, comp;
        if (c4 == 0)      { qq = 0; comp = w - 12; }
        else if (c4 == 1) { qq = 1; comp = w - 12; }
        else if (c4 == 2) { qq = 2 + ((w - 8) >> 2); comp = (w - 8) & 3; }
        else              { qq = 4 + ((w - 8) >> 2); comp = (w - 8) & 3; }
        wlds[((size_t)(d * 6 + qq) * 1024 + slot) * 4 + comp] = v;
      }
    }
  }
}

// ---------------------------------------------------------------------------
// prep: softmax(151), probs->bf16 (padded 192), conf=max(probs[1:]),
// pos = relu(BN(center_size(boxes)) @ pos_w + pos_b), fmaps -> FE bf16.
// FE layout: [enc 0..512 | fmaps 512..2560 | embed 2560..2760 | pos 2760..2888 | pad]
// ---------------------------------------------------------------------------
__global__ void prep_kernel(
    const float* __restrict__ logits, const float* __restrict__ fmaps,
    const float* __restrict__ boxes,
    const float* __restrict__ bn_g, const float* __restrict__ bn_b,
    const float* __restrict__ bn_m, const float* __restrict__ bn_v,
    const float* __restrict__ pos_w, const float* __restrict__ pos_b,
    __hip_bfloat16* __restrict__ FE, __hip_bfloat16* __restrict__ probsb,
    float* __restrict__ conf)
{
  __shared__ float red[256];
  const int row = blockIdx.x, t = threadIdx.x;
  float v = (t < 151) ? logits[(size_t)row * 151 + t] : -3.0e38f;
  red[t] = v; __syncthreads();
  for (int s = 128; s > 0; s >>= 1) { if (t < s) red[t] = fmaxf(red[t], red[t + s]); __syncthreads(); }
  float mx = red[0]; __syncthreads();
  float p = (t < 151) ? expf(v - mx) : 0.f;
  red[t] = p; __syncthreads();
  for (int s = 128; s > 0; s >>= 1) { if (t < s) red[t] += red[t + s]; __syncthreads(); }
  float sum = red[0]; __syncthreads();
  p = p / sum;
  if (t < 192) probsb[(size_t)row * 192 + t] = __float2bfloat16((t < 151) ? p : 0.f);
  red[t] = (t >= 1 && t < 151) ? p : 0.f; __syncthreads();
  for (int s = 128; s > 0; s >>= 1) { if (t < s) red[t] = fmaxf(red[t], red[t + s]); __syncthreads(); }
  if (t == 0) conf[row] = red[0];

  if (t < 128) {
    float x1 = boxes[row * 4 + 0], y1 = boxes[row * 4 + 1];
    float x2 = boxes[row * 4 + 2], y2 = boxes[row * 4 + 3];
    float cs[4] = { (x1 + x2) * 0.5f, (y1 + y2) * 0.5f, x2 - x1, y2 - y1 };
    float a = pos_b[t];
    #pragma unroll
    for (int j = 0; j < 4; j++) {
      float cn = (cs[j] - bn_m[j]) * rsqrtf(bn_v[j] + 1e-5f) * bn_g[j] + bn_b[j];
      a += cn * pos_w[j * 128 + t];
    }
    FE[(size_t)row * FE_LD + 2760 + t] = __float2bfloat16(fmaxf(a, 0.f));
  }
  for (int c0 = t; c0 < 2048; c0 += 256)
    FE[(size_t)row * FE_LD + 512 + c0] = __float2bfloat16(fmaps[(size_t)row * 2048 + c0]);
}

// ---------------------------------------------------------------------------
// Per-image bitonic sort of conf desc (tie: index asc) -> perm (global rows).
// ---------------------------------------------------------------------------
__global__ void sort_kernel(const float* __restrict__ conf, int* __restrict__ perm)
{
  __shared__ float key[128];
  __shared__ int   idx[128];
  const int b = blockIdx.x, t = threadIdx.x;
  key[t] = conf[b * 128 + t]; idx[t] = t;
  __syncthreads();
  for (int k = 2; k <= 128; k <<= 1)
    for (int j = k >> 1; j > 0; j >>= 1) {
      int ixj = t ^ j;
      if (ixj > t) {
        bool up = (t & k) == 0;
        float ka = key[t], kb = key[ixj];
        int ia = idx[t], ib = idx[ixj];
        bool before = (ka > kb) || (ka == kb && ia < ib); // desc, stable
        if (before != up) { key[t] = kb; key[ixj] = ka; idx[t] = ib; idx[ixj] = ia; }
      }
      __syncthreads();
    }
  perm[b * 128 + t] = b * 128 + idx[t];
}

// ---------------------------------------------------------------------------
// LSTM scan, i8 weights, kg-split, 40 resident weight regs. 64 blocks =
// (img 32) x (dir 2), 1024 threads. Thread (kg=tid>>8, j=tid&255): int
// partials of 4 gates of h-dim j over k in [kg*64, kg*64+64).
// Weights: 40 u32 pinned VGPR + 24 u32 (6 uint4) in LDS (96 KB).
// Partials: int4 part[j*5+kg] (stride-5, conflict-free). P is bf16.
// ---------------------------------------------------------------------------
__global__ __launch_bounds__(1024) void rec_kernel(
    const __hip_bfloat16* __restrict__ P, // [4096][2048] pre-activations (+bias)
    const int* __restrict__ perm,         // [4096] global rows
    const u32* __restrict__ wreg_g,       // [2][40][1024]
    const uint4* __restrict__ wlds_g,     // [2][6][1024]
    const float* __restrict__ wsc_g,      // [2][1024]
    int gatherPerm, int outPerm,
    __hip_bfloat16* __restrict__ out_bf, int out_ld,
    float* __restrict__ out_f32, int f32_ld, int f32_off)
{
  __shared__ __align__(16) uint4 wt4[6 * 1024];    // 96 KB (k tails per col)
  __shared__ __align__(16) int4 part[256 * 5];     // 20 KB  [j][kg], stride 5
  __shared__ __align__(16) u32 hq[64];             // 256 i8 of h
  __shared__ int prow_lds[128];
  const int tid = threadIdx.x;
  const int kg = tid >> 8;
  const int img = blockIdx.x & 31, dir = blockIdx.x >> 5;

  u32 wv[40];
  {
    const u32* rp = wreg_g + (size_t)dir * 40960 + tid;
    #pragma unroll
    for (int i = 0; i < 40; i++) wv[i] = rp[(size_t)i * 1024];
  }
  #pragma unroll
  for (int i = 0; i < 40; i++) asm volatile("" : "+v"(wv[i]));   // forbid remat
  {
    const uint4* lp = wlds_g + (size_t)dir * 6144 + tid;
    #pragma unroll
    for (int q = 0; q < 6; q++) wt4[q * 1024 + tid] = lp[(size_t)q * 1024];
  }
  if (tid < 128) prow_lds[tid] = perm[img * 128 + tid];
  if (tid < 64) hq[tid] = 0;

  float sc0 = 0.f, sc1 = 0.f, sc2 = 0.f, sc3 = 0.f, cst = 0.f;
  if (tid < 256) {
    const float* sp = wsc_g + dir * 1024 + tid;
    sc0 = sp[0]; sc1 = sp[256]; sc2 = sp[512]; sc3 = sp[768];
  }
  __syncthreads();

  const uint4* hq4 = (const uint4*)hq;

  int st = dir ? 127 : 0;
  float p0 = 0.f, p1 = 0.f, p2 = 0.f, p3 = 0.f;
  if (tid < 256) {
    int prow0 = gatherPerm ? prow_lds[st] : (img * 128 + st);
    const __hip_bfloat16* pp = P + (size_t)prow0 * 2048 + dir * 1024 + tid;
    p0 = __bfloat162float(pp[0]);   p1 = __bfloat162float(pp[256]);
    p2 = __bfloat162float(pp[512]); p3 = __bfloat162float(pp[768]);
  }

  for (int t = 0; t < 128; t++) {
    float n0 = 0.f, n1 = 0.f, n2 = 0.f, n3 = 0.f;
    if (tid < 256 && t < 127) {
      int stn = dir ? (126 - t) : (t + 1);
      int prn = gatherPerm ? prow_lds[stn] : (img * 128 + stn);
      const __hip_bfloat16* pp = P + (size_t)prn * 2048 + dir * 1024 + tid;
      n0 = __bfloat162float(pp[0]);   n1 = __bfloat162float(pp[256]);
      n2 = __bfloat162float(pp[512]); n3 = __bfloat162float(pp[768]);
    }

    int a0 = 0, a1 = 0, a2 = 0, a3 = 0;
    {
      uint4 hv = hq4[kg * 4 + 0];         // k-words 0..3
      a0 = sdot4(hv.x, wv[0], a0);  a0 = sdot4(hv.y, wv[1], a0);
      a0 = sdot4(hv.z, wv[2], a0);  a0 = sdot4(hv.w, wv[3], a0);
      a1 = sdot4(hv.x, wv[12], a1); a1 = sdot4(hv.y, wv[13], a1);
      a1 = sdot4(hv.z, wv[14], a1); a1 = sdot4(hv.w, wv[15], a1);
      a2 = sdot4(hv.x, wv[24], a2); a2 = sdot4(hv.y, wv[25], a2);
      a2 = sdot4(hv.z, wv[26], a2); a2 = sdot4(hv.w, wv[27], a2);
      a3 = sdot4(hv.x, wv[32], a3); a3 = sdot4(hv.y, wv[33], a3);
      a3 = sdot4(hv.z, wv[34], a3); a3 = sdot4(hv.w, wv[35], a3);
    }
    {
      uint4 hv = hq4[kg * 4 + 1];         // k-words 4..7
      a0 = sdot4(hv.x, wv[4], a0);  a0 = sdot4(hv.y, wv[5], a0);
      a0 = sdot4(hv.z, wv[6], a0);  a0 = sdot4(hv.w, wv[7], a0);
      a1 = sdot4(hv.x, wv[16], a1); a1 = sdot4(hv.y, wv[17], a1);
      a1 = sdot4(hv.z, wv[18], a1); a1 = sdot4(hv.w, wv[19], a1);
      a2 = sdot4(hv.x, wv[28], a2); a2 = sdot4(hv.y, wv[29], a2);
      a2 = sdot4(hv.z, wv[30], a2); a2 = sdot4(hv.w, wv[31], a2);
      a3 = sdot4(hv.x, wv[36], a3); a3 = sdot4(hv.y, wv[37], a3);
      a3 = sdot4(hv.z, wv[38], a3); a3 = sdot4(hv.w, wv[39], a3);
    }
    {
      uint4 hv = hq4[kg * 4 + 2];         // k-words 8..11
      a0 = sdot4(hv.x, wv[8], a0);  a0 = sdot4(hv.y, wv[9], a0);
      a0 = sdot4(hv.z, wv[10], a0); a0 = sdot4(hv.w, wv[11], a0);
      a1 = sdot4(hv.x, wv[20], a1); a1 = sdot4(hv.y, wv[21], a1);
      a1 = sdot4(hv.z, wv[22], a1); a1 = sdot4(hv.w, wv[23], a1);
      uint4 wl = wt4[2 * 1024 + tid];     // gate2 words 8..11
      a2 = sdot4(hv.x, wl.x, a2); a2 = sdot4(hv.y, wl.y, a2);
      a2 = sdot4(hv.z, wl.z, a2); a2 = sdot4(hv.w, wl.w, a2);
      wl = wt4[4 * 1024 + tid];           // gate3 words 8..11
      a3 = sdot4(hv.x, wl.x, a3); a3 = sdot4(hv.y, wl.y, a3);
      a3 = sdot4(hv.z, wl.z, a3); a3 = sdot4(hv.w, wl.w, a3);
    }
    {
      uint4 hv = hq4[kg * 4 + 3];         // k-words 12..15
      uint4 wl = wt4[0 * 1024 + tid];     // gate0 words 12..15
      a0 = sdot4(hv.x, wl.x, a0); a0 = sdot4(hv.y, wl.y, a0);
      a0 = sdot4(hv.z, wl.z, a0); a0 = sdot4(hv.w, wl.w, a0);
      wl = wt4[1 * 1024 + tid];           // gate1 words 12..15
      a1 = sdot4(hv.x, wl.x, a1); a1 = sdot4(hv.y, wl.y, a1);
      a1 = sdot4(hv.z, wl.z, a1); a1 = sdot4(hv.w, wl.w, a1);
      wl = wt4[3 * 1024 + tid];           // gate2 words 12..15
      a2 = sdot4(hv.x, wl.x, a2); a2 = sdot4(hv.y, wl.y, a2);
      a2 = sdot4(hv.z, wl.z, a2); a2 = sdot4(hv.w, wl.w, a2);
      wl = wt4[5 * 1024 + tid];           // gate3 words 12..15
      a3 = sdot4(hv.x, wl.x, a3); a3 = sdot4(hv.y, wl.y, a3);
      a3 = sdot4(hv.z, wl.z, a3); a3 = sdot4(hv.w, wl.w, a3);
    }

    part[(tid & 255) * 5 + kg] = int4{a0, a1, a2, a3};
    __syncthreads();

    if (tid < 256) {
      int4 q0 = part[tid * 5 + 0], q1 = part[tid * 5 + 1];
      int4 q2 = part[tid * 5 + 2], q3 = part[tid * 5 + 3];
      float gi = (float)(q0.x + q1.x + q2.x + q3.x) * sc0 + p0;
      float gf = (float)(q0.y + q1.y + q2.y + q3.y) * sc1 + p1;
      float gg = (float)(q0.z + q1.z + q2.z + q3.z) * sc2 + p2;
      float go = (float)(q0.w + q1.w + q2.w + q3.w) * sc3 + p3;
      float si = fsig(gi), sf = fsig(gf), so = fsig(go);
      cst = sf * cst + si * ftanh(gg);
      float h = so * ftanh(cst);
      int qi = __float2int_rn(h * 127.f);
      ((signed char*)hq)[tid] = (signed char)qi;
      const int orow = outPerm ? prow_lds[st] : (img * 128 + st);
      if (out_bf)  out_bf[(size_t)orow * out_ld + dir * 256 + tid] = __float2bfloat16(h);
      if (out_f32) out_f32[(size_t)orow * f32_ld + f32_off + dir * 256 + tid] = h;
    }
    __syncthreads();
    p0 = n0; p1 = n1; p2 = n2; p3 = n3;
    st = dir ? (st - 1) : (st + 1);
  }
}

// ---------------------------------------------------------------------------
// Fused: per-row argmax over dists[:,1:151) (first max wins) + edge build.
// edge_in = [embed2[pred] (200) | enc (512, from FE) | fmaps (2048)] bf16
// ---------------------------------------------------------------------------
__global__ void argmax_edge_kernel(const float* __restrict__ dists,
                                   const float* __restrict__ embed2,
                                   const float* __restrict__ fmaps,
                                   const __hip_bfloat16* __restrict__ FE,
                                   __hip_bfloat16* __restrict__ EDGE)
{
  __shared__ float rv[256];
  __shared__ int   ri[256];
  const int row = blockIdx.x, t = threadIdx.x;

  float best = (t < 150) ? dists[(size_t)row * 663 + 1 + t] : -3.4e38f;
  int   bi   = (t < 150) ? (1 + t) : 1000;
  rv[t] = best; ri[t] = bi;
  __syncthreads();
  for (int s = 128; s > 0; s >>= 1) {
    if (t < s) {
      float ov = rv[t + s]; int oi = ri[t + s];
      if (ov > rv[t] || (ov == rv[t] && oi < ri[t])) { rv[t] = ov; ri[t] = oi; }
    }
    __syncthreads();
  }
  const int pr = ri[0];

  for (int c0 = t; c0 < 200; c0 += 256)
    EDGE[(size_t)row * EDGE_LD + c0] = __float2bfloat16(embed2[(size_t)pr * 200 + c0]);
  for (int c0 = t; c0 < 512; c0 += 256)
    EDGE[(size_t)row * EDGE_LD + 200 + c0] = FE[(size_t)row * FE_LD + c0];
  for (int c0 = t; c0 < 2048; c0 += 256)
    EDGE[(size_t)row * EDGE_LD + 712 + c0] = __float2bfloat16(fmaps[(size_t)row * 2048 + c0]);
}

// ---------------------------------------------------------------------------
extern "C" void kernel_launch(void* const* d_in, const int* in_sizes, int n_in,
                              void* d_out, int out_size, void* d_ws, size_t ws_size,
                              hipStream_t stream)
{
  const float* obj_fmaps    = (const float*)d_in[0];
  const float* obj_logits   = (const float*)d_in[1];
  const float* boxes        = (const float*)d_in[2];
  const float* obj_embed_w  = (const float*)d_in[4];
  const float* obj_embed2_w = (const float*)d_in[5];
  const float* bn_g = (const float*)d_in[6];
  const float* bn_b = (const float*)d_in[7];
  const float* bn_m = (const float*)d_in[8];
  const float* bn_v = (const float*)d_in[9];
  const float* pos_w = (const float*)d_in[10];
  const float* pos_b = (const float*)d_in[11];
  const float* obj_wih0 = (const float*)d_in[12];
  const float* obj_whh0 = (const float*)d_in[13];
  const float* obj_b0   = (const float*)d_in[14];
  const float* obj_wih1 = (const float*)d_in[15];
  const float* obj_whh1 = (const float*)d_in[16];
  const float* obj_b1   = (const float*)d_in[17];
  const float* edge_wih0 = (const float*)d_in[18];
  const float* edge_whh0 = (const float*)d_in[19];
  const float* edge_b0   = (const float*)d_in[20];
  const float* edge_wih1 = (const float*)d_in[21];
  const float* edge_whh1 = (const float*)d_in[22];
  const float* edge_b1   = (const float*)d_in[23];
  const float* dec_w = (const float*)d_in[24];
  const float* dec_b = (const float*)d_in[25];
  float* out = (float*)d_out;

  char* ws = (char*)d_ws;
  auto alloc = [&](size_t bytes) -> char* {
    char* p = ws; ws += (bytes + 255) & ~(size_t)255; return p;
  };
  __hip_bfloat16* FE     = (__hip_bfloat16*)alloc(4096ull * FE_LD * 2);
  __hip_bfloat16* EDGE   = (__hip_bfloat16*)alloc(4096ull * EDGE_LD * 2);
  __hip_bfloat16* Pbuf   = (__hip_bfloat16*)alloc(4096ull * 2048 * 2);
  __hip_bfloat16* hseq   = (__hip_bfloat16*)alloc(4096ull * 512 * 2);
  __hip_bfloat16* probsb = (__hip_bfloat16*)alloc(4096ull * 192 * 2);
  __hip_bfloat16* wih0T  = (__hip_bfloat16*)alloc(2048ull * 2432 * 2);
  __hip_bfloat16* wih1T  = (__hip_bfloat16*)alloc(2048ull * 512 * 2);
  __hip_bfloat16* ewih0T = (__hip_bfloat16*)alloc(2048ull * 2816 * 2);
  __hip_bfloat16* ewih1T = (__hip_bfloat16*)alloc(2048ull * 512 * 2);
  __hip_bfloat16* embedT = (__hip_bfloat16*)alloc(256ull * 192 * 2);
  __hip_bfloat16* decT   = (__hip_bfloat16*)alloc(256ull * 2944 * 2);
  // packed whh set: wreg 81920 u32 | wlds 49152 u32 | wsc 2048 f32
  u32* whh0pk  = (u32*)alloc(133120ull * 4);
  u32* whh1pk  = (u32*)alloc(133120ull * 4);
  u32* ewhh0pk = (u32*)alloc(133120ull * 4);
  u32* ewhh1pk = (u32*)alloc(133120ull * 4);
  int*   perm  = (int*)alloc(4096 * 4);
  float* conf  = (float*)alloc(4096 * 4);
  (void)in_sizes; (void)n_in; (void)out_size; (void)ws_size;

  // ---- batched transposes (one launch) ----
  TrOps tr{};
  int nt = 0, base = 0;
  auto addTr = [&](const float* src, __hip_bfloat16* dst, int srcK, int srcN,
                   int dstR, int dstC, int split, int soff) {
    tr.src[nt] = src; tr.dst[nt] = dst;
    tr.srcK[nt] = srcK; tr.srcN[nt] = srcN; tr.dstR[nt] = dstR; tr.dstC[nt] = dstC;
    tr.split[nt] = split; tr.soff[nt] = soff;
    int tx = (dstC + 31) / 32, ty = (dstR + 31) / 32;
    tr.tileBase[nt] = base; tr.tilesX[nt] = tx;
    base += tx * ty; nt++;
  };
  for (int d = 0; d < 2; d++) {
    addTr(obj_wih0 + (size_t)d * 2376 * 1024, wih0T + (size_t)d * 1024 * 2432, 2376, 1024, 1024, 2432, 0, 0);
    addTr(obj_wih1 + (size_t)d * 512 * 1024,  wih1T + (size_t)d * 1024 * 512,  512, 1024, 1024, 512, 0, 0);
    addTr(edge_wih0 + (size_t)d * 2760 * 1024, ewih0T + (size_t)d * 1024 * 2816, 2760, 1024, 1024, 2816, 0, 0);
    addTr(edge_wih1 + (size_t)d * 512 * 1024,  ewih1T + (size_t)d * 1024 * 512,  512, 1024, 1024, 512, 0, 0);
  }
  addTr(obj_embed_w, embedT, 151, 200, 256, 192, 0, 0);
  addTr(dec_w, decT, 2888, 151, 256, 2944, 512, 2376);  // [enc|feats] remap
  transpose_batch<<<dim3(base), dim3(256), 0, stream>>>(tr);

  // ---- batched whh packs (one launch) ----
  PkOps pk{};
  const float* whhs[4] = {obj_whh0, obj_whh1, edge_whh0, edge_whh1};
  u32* pks[4] = {whh0pk, whh1pk, ewhh0pk, ewhh1pk};
  for (int i = 0; i < 4; i++) {
    pk.whh[i] = whhs[i];
    pk.wreg[i] = pks[i];
    pk.wlds[i] = pks[i] + 81920;
    pk.wsc[i]  = (float*)(pks[i] + 131072);
  }
  pack_batch<<<dim3(8, 4), dim3(256), 0, stream>>>(pk);

  prep_kernel<<<dim3(4096), dim3(256), 0, stream>>>(
      obj_logits, obj_fmaps, boxes, bn_g, bn_b, bn_m, bn_v, pos_w, pos_b, FE, probsb, conf);
  sort_kernel<<<dim3(32), dim3(128), 0, stream>>>(conf, perm);

  auto gemm = [&](const void* A, int lda, const void* B, int ldb, int K, int N,
                  float* oF, __hip_bfloat16* oB, int ldc, const float* bias) {
    dim3 g(32, (N + 127) / 128);
    gemm_kernel<<<g, dim3(256), 0, stream>>>(
        (const u16*)A, lda, (const u16*)B, ldb, K, N, oF, oB, ldc, bias);
  };
  auto rec = [&](const __hip_bfloat16* P, const u32* wpk, int gat, int op,
                 __hip_bfloat16* ob, int old_, float* of, int fld, int foff) {
    rec_kernel<<<dim3(64), dim3(1024), 0, stream>>>(
        P, perm, wpk, (const uint4*)(wpk + 81920), (const float*)(wpk + 131072),
        gat, op, ob, old_, of, fld, foff);
  };

  // obj_embed -> FE cols [2560,2760)
  gemm(probsb, 192, embedT, 192, 192, 200, nullptr, FE + 2560, FE_LD, nullptr);
  // obj layer 0
  gemm((const u16*)FE + 512, FE_LD, wih0T, 2432, 2432, 2048, nullptr, Pbuf, 2048, obj_b0);
  rec(Pbuf, whh0pk, 1, 0, hseq, 512, nullptr, 0, 0);
  // obj layer 1 -> enc into FE cols [0,512)
  gemm(hseq, 512, wih1T, 512, 512, 2048, nullptr, Pbuf, 2048, obj_b1);
  rec(Pbuf, whh1pk, 0, 1, FE, FE_LD, nullptr, 0, 0);
  // decoder -> out cols [0,151)
  gemm(FE, FE_LD, decT, 2944, 2944, 151, out, nullptr, 663, dec_b);
  // fused argmax + edge build
  argmax_edge_kernel<<<dim3(4096), dim3(256), 0, stream>>>(
      out, obj_embed2_w, obj_fmaps, FE, EDGE);
  // edge layer 0
  gemm(EDGE, EDGE_LD, ewih0T, 2816, 2816, 2048, nullptr, Pbuf, 2048, edge_b0);
  rec(Pbuf, ewhh0pk, 1, 0, hseq, 512, nullptr, 0, 0);
  // edge layer 1 -> out cols [151,663)
  gemm(hseq, 512, ewih1T, 512, 512, 2048, nullptr, Pbuf, 2048, edge_b1);
  rec(Pbuf, ewhh1pk, 0, 1, nullptr, 0, out, 663, 151);
}

// Round 14
// 864.183 us; speedup vs baseline: 1.2498x; 1.0066x over previous
//
#include <hip/hip_runtime.h>
#include <hip/hip_bf16.h>
#include <hip/hip_fp16.h>

typedef unsigned short u16;
typedef unsigned char u8;
typedef unsigned int u32;
typedef short s16x8 __attribute__((ext_vector_type(8)));
typedef float f32x4 __attribute__((ext_vector_type(4)));
typedef int i32x4 __attribute__((ext_vector_type(4)));

#define FE_LD 2944
#define EDGE_LD 2816

static __device__ __forceinline__ int sdot4(u32 a, u32 b, int acc) {
  return __builtin_amdgcn_sdot4((int)a, (int)b, acc, false);
}
static __device__ __forceinline__ float fsig(float x) {
  return __builtin_amdgcn_rcpf(1.f + __expf(-x));
}
static __device__ __forceinline__ float ftanh(float x) {
  return 1.f - 2.f * __builtin_amdgcn_rcpf(1.f + __expf(2.f * x));
}

#define GLD_LDS16(gsrc, ldst) \
  __builtin_amdgcn_global_load_lds((const __attribute__((address_space(1))) void*)(gsrc), \
                                   (__attribute__((address_space(3))) void*)(ldst), 16, 0, 0)

// XCD-aware swizzle: 1-D grid (nwg % 8 == 0), consecutive work shares A-panel.
static __device__ __forceinline__ void xcd_map(int gy, int* bx, int* by) {
  int lin = blockIdx.x;
  int q = gridDim.x >> 3;
  int wg = (lin & 7) * q + (lin >> 3);
  *bx = wg / gy; *by = wg % gy;
}

// ---------------------------------------------------------------------------
// Generic bf16 MFMA GEMM: C[M=4096][N] = A[M][K] * B^T[N][K] (+bias), K%64==0.
// 128x128 tile, 4 waves (2x2), 4x4 frags of 16x16x32. XCD-swizzled 1-D grid.
// ---------------------------------------------------------------------------
__global__ __launch_bounds__(256) void gemm_kernel(
    const u16* __restrict__ A, int lda,
    const u16* __restrict__ B, int ldb,
    int K, int N, int gy,
    float* __restrict__ outF, __hip_bfloat16* __restrict__ outB, int ldc,
    const float* __restrict__ bias)
{
  __shared__ __align__(16) u16 As[128*64];
  __shared__ __align__(16) u16 Bs[128*64];
  const int tid = threadIdx.x;
  const int w = tid >> 6, lane = tid & 63;
  const int wm = w >> 1, wn = w & 1;
  int bxi, byi; xcd_map(gy, &bxi, &byi);
  const long bm = (long)bxi * 128;
  const long bn = (long)byi * 128;
  f32x4 acc[4][4] = {};

  for (int k0 = 0; k0 < K; k0 += 64) {
    #pragma unroll
    for (int rr = 0; rr < 4; rr++) {
      int idx = rr * 256 + tid;
      int row = idx >> 3;
      int g   = idx & 7;
      int gs  = g ^ (row & 7);
      int ldst = (rr * 256 + (w << 6)) * 8;
      GLD_LDS16(A + (bm + row) * (long)lda + k0 + gs * 8, &As[ldst]);
      GLD_LDS16(B + (bn + row) * (long)ldb + k0 + gs * 8, &Bs[ldst]);
    }
    __syncthreads();
    #pragma unroll
    for (int kk = 0; kk < 2; kk++) {
      s16x8 af[4], bfr[4];
      #pragma unroll
      for (int i = 0; i < 4; i++) {
        int ra = wm * 64 + i * 16 + (lane & 15);
        int rb = wn * 64 + i * 16 + (lane & 15);
        int gg = kk * 4 + (lane >> 4);
        af[i]  = *(const s16x8*)&As[ra * 64 + ((gg ^ (ra & 7)) << 3)];
        bfr[i] = *(const s16x8*)&Bs[rb * 64 + ((gg ^ (rb & 7)) << 3)];
      }
      #pragma unroll
      for (int i = 0; i < 4; i++)
        #pragma unroll
        for (int j = 0; j < 4; j++)
          acc[i][j] = __builtin_amdgcn_mfma_f32_16x16x32_bf16(af[i], bfr[j], acc[i][j], 0, 0, 0);
    }
    __syncthreads();
  }

  #pragma unroll
  for (int i = 0; i < 4; i++)
    #pragma unroll
    for (int j = 0; j < 4; j++)
      #pragma unroll
      for (int v = 0; v < 4; v++) {
        long rr = bm + wm * 64 + i * 16 + (lane >> 4) * 4 + v;
        int  cc = (int)bn + wn * 64 + j * 16 + (lane & 15);
        if (cc < N) {
          float val = acc[i][j][v] + (bias ? bias[cc] : 0.f);
          if (outF) outF[rr * (long)ldc + cc] = val;
          else      outB[rr * (long)ldc + cc] = __float2bfloat16(val);
        }
      }
}

// ---------------------------------------------------------------------------
// i8 MFMA GEMM: C = A(i8,[M][K]) * B^T(i8,[N][K]) with per-row/col scales.
// 128x128 tile, BK=128 i8 (128B rows, 8x16B groups — same swizzle as bf16).
// v_mfma_i32_16x16x64_i8. out bf16 = acc*asc[r]*bsc[c] + bias[c].
// ---------------------------------------------------------------------------
__global__ __launch_bounds__(256) void gemm_i8_kernel(
    const u8* __restrict__ A, int lda,
    const u8* __restrict__ B, int ldb,
    int K, int N, int gy,
    const float* __restrict__ asc, const float* __restrict__ bsc,
    __hip_bfloat16* __restrict__ outB, int ldc,
    const float* __restrict__ bias)
{
  __shared__ __align__(16) u8 As[128*128];
  __shared__ __align__(16) u8 Bs[128*128];
  const int tid = threadIdx.x;
  const int w = tid >> 6, lane = tid & 63;
  const int wm = w >> 1, wn = w & 1;
  int bxi, byi; xcd_map(gy, &bxi, &byi);
  const long bm = (long)bxi * 128;
  const long bn = (long)byi * 128;
  i32x4 acc[4][4] = {};

  for (int k0 = 0; k0 < K; k0 += 128) {
    #pragma unroll
    for (int rr = 0; rr < 4; rr++) {
      int idx = rr * 256 + tid;
      int row = idx >> 3;
      int g   = idx & 7;
      int gs  = g ^ (row & 7);
      int ldst = (rr * 256 + (w << 6)) * 16;   // bytes
      GLD_LDS16(A + (bm + row) * (long)lda + k0 + gs * 16, &As[ldst]);
      GLD_LDS16(B + (bn + row) * (long)ldb + k0 + gs * 16, &Bs[ldst]);
    }
    __syncthreads();
    #pragma unroll
    for (int kk = 0; kk < 2; kk++) {
      i32x4 af[4], bfr[4];
      #pragma unroll
      for (int i = 0; i < 4; i++) {
        int ra = wm * 64 + i * 16 + (lane & 15);
        int rb = wn * 64 + i * 16 + (lane & 15);
        int gg = kk * 4 + (lane >> 4);
        af[i]  = __builtin_bit_cast(i32x4, *(const uint4*)&As[ra * 128 + ((gg ^ (ra & 7)) << 4)]);
        bfr[i] = __builtin_bit_cast(i32x4, *(const uint4*)&Bs[rb * 128 + ((gg ^ (rb & 7)) << 4)]);
      }
      #pragma unroll
      for (int i = 0; i < 4; i++)
        #pragma unroll
        for (int j = 0; j < 4; j++)
          acc[i][j] = __builtin_amdgcn_mfma_i32_16x16x64_i8(af[i], bfr[j], acc[i][j], 0, 0, 0);
    }
    __syncthreads();
  }

  #pragma unroll
  for (int i = 0; i < 4; i++)
    #pragma unroll
    for (int j = 0; j < 4; j++)
      #pragma unroll
      for (int v = 0; v < 4; v++) {
        long rr = bm + wm * 64 + i * 16 + (lane >> 4) * 4 + v;
        int  cc = (int)bn + wn * 64 + j * 16 + (lane & 15);
        if (cc < N) {
          float val = (float)acc[i][j][v] * asc[rr] * bsc[cc] + (bias ? bias[cc] : 0.f);
          outB[rr * (long)ldc + cc] = __float2bfloat16(val);
        }
      }
}

// ---------------------------------------------------------------------------
// Per-row symmetric i8 quantization of a bf16 matrix slice.
// dst[row][k] i8, scale[row] = maxabs/127.
// ---------------------------------------------------------------------------
__global__ void quant_rows(const u16* __restrict__ src, long ld, int K,
                           u8* __restrict__ dst, long dld, float* __restrict__ scale)
{
  __shared__ float red[256];
  const int row = blockIdx.x, t = threadIdx.x;
  const u16* s = src + (size_t)row * ld;
  float mx = 0.f;
  for (int c = t; c < K; c += 256) {
    u32 u = (u32)s[c] << 16;
    mx = fmaxf(mx, fabsf(__builtin_bit_cast(float, u)));
  }
  red[t] = mx; __syncthreads();
  for (int st = 128; st > 0; st >>= 1) { if (t < st) red[t] = fmaxf(red[t], red[t + st]); __syncthreads(); }
  mx = red[0];
  float inv = (mx > 0.f) ? 127.f / mx : 0.f;
  if (t == 0) scale[row] = (mx > 0.f) ? mx / 127.f : 0.f;
  u32* d32 = (u32*)(dst + (size_t)row * dld);
  for (int wd = t; wd < (K >> 2); wd += 256) {
    u32 v = 0;
    #pragma unroll
    for (int b = 0; b < 4; b++) {
      u32 u = (u32)s[4 * wd + b] << 16;
      int q = __float2int_rn(__builtin_bit_cast(float, u) * inv);
      q = max(-127, min(127, q));
      v |= ((u32)(q & 0xff)) << (8 * b);
    }
    d32[wd] = v;
  }
}

// ---------------------------------------------------------------------------
// Batched tiled transpose + cast fp32 -> bf16 (10 ops in one launch).
// ---------------------------------------------------------------------------
#define N_TROPS 10
struct TrOps {
  const float* src[N_TROPS];
  __hip_bfloat16* dst[N_TROPS];
  int srcK[N_TROPS], srcN[N_TROPS], dstR[N_TROPS], dstC[N_TROPS];
  int split[N_TROPS], soff[N_TROPS];
  int tileBase[N_TROPS], tilesX[N_TROPS];
};
__global__ void transpose_batch(TrOps ops)
{
  __shared__ float tile[32][33];
  int bid = blockIdx.x;
  int op = 0;
  #pragma unroll
  for (int i = 1; i < N_TROPS; i++) if (bid >= ops.tileBase[i]) op = i;
  const int local = bid - ops.tileBase[op];
  const int kt = (local % ops.tilesX[op]) * 32;
  const int nt = (local / ops.tilesX[op]) * 32;
  const float* src = ops.src[op];
  __hip_bfloat16* dst = ops.dst[op];
  const int srcK = ops.srcK[op], srcN = ops.srcN[op];
  const int dstR = ops.dstR[op], dstC = ops.dstC[op];
  const int split = ops.split[op], soff = ops.soff[op];

  const int tx = threadIdx.x & 31, ty = threadIdx.x >> 5;
  for (int i = ty; i < 32; i += 8) {
    int k = kt + i;
    int srck = (k < split) ? (soff + k) : (k - split);
    int n = nt + tx;
    tile[i][tx] = (srck < srcK && n < srcN) ? src[(size_t)srck * srcN + n] : 0.f;
  }
  __syncthreads();
  for (int i = ty; i < 32; i += 8) {
    int n = nt + i, k = kt + tx;
    if (n < dstR && k < dstC)
      dst[(size_t)n * dstC + k] = __float2bfloat16(tile[tx][i]);
  }
}

// ---------------------------------------------------------------------------
// Batched whh quantize (4 sets, blockIdx.y = set). i8, kg-split, 40reg/24lds.
// ---------------------------------------------------------------------------
struct PkOps {
  const float* whh[4];
  u32* wreg[4];
  u32* wlds[4];
  float* wsc[4];
};
__global__ void pack_batch(PkOps ops)
{
  const int set = blockIdx.y;
  const float* whh = ops.whh[set];
  u32* wreg = ops.wreg[set];
  u32* wlds = ops.wlds[set];
  float* wsc = ops.wsc[set];

  const int idx = blockIdx.x * 256 + threadIdx.x;   // 0..2047
  const int d = idx >> 10, col = idx & 1023;
  const int c4 = col >> 8, j = col & 255;
  const float* s = whh + (size_t)d * 256 * 1024 + col;
  float mx = 0.f;
  for (int k = 0; k < 256; k++) mx = fmaxf(mx, fabsf(s[(size_t)k * 1024]));
  float inv = (mx > 0.f) ? 127.f / mx : 0.f;
  wsc[d * 1024 + col] = (mx > 0.f) ? mx / (127.f * 127.f) : 0.f;
  const int rc = (c4 < 2) ? 12 : 8;
  const int rb = (c4 == 0) ? 0 : (c4 == 1) ? 12 : (c4 == 2) ? 24 : 32;
  for (int kg = 0; kg < 4; kg++) {
    const int slot = kg * 256 + j;
    for (int w = 0; w < 16; w++) {
      u32 v = 0;
      #pragma unroll
      for (int b = 0; b < 4; b++) {
        int q = __float2int_rn(s[(size_t)(kg * 64 + 4 * w + b) * 1024] * inv);
        q = max(-127, min(127, q));
        v |= ((u32)(q & 0xff)) << (8 * b);
      }
      if (w < rc) {
        wreg[(size_t)(d * 40 + rb + w) * 1024 + slot] = v;
      } else {
        int qq, comp;
        if (c4 == 0)      { qq = 0; comp = w - 12; }
        else if (c4 == 1) { qq = 1; comp = w - 12; }
        else if (c4 == 2) { qq = 2 + ((w - 8) >> 2); comp = (w - 8) & 3; }
        else              { qq = 4 + ((w - 8) >> 2); comp = (w - 8) & 3; }
        wlds[((size_t)(d * 6 + qq) * 1024 + slot) * 4 + comp] = v;
      }
    }
  }
}

// ---------------------------------------------------------------------------
// prep: softmax(151), probs->bf16 (padded 192), conf=max(probs[1:]),
// pos = relu(BN(center_size(boxes)) @ pos_w + pos_b), fmaps -> FE bf16.
// ---------------------------------------------------------------------------
__global__ void prep_kernel(
    const float* __restrict__ logits, const float* __restrict__ fmaps,
    const float* __restrict__ boxes,
    const float* __restrict__ bn_g, const float* __restrict__ bn_b,
    const float* __restrict__ bn_m, const float* __restrict__ bn_v,
    const float* __restrict__ pos_w, const float* __restrict__ pos_b,
    __hip_bfloat16* __restrict__ FE, __hip_bfloat16* __restrict__ probsb,
    float* __restrict__ conf)
{
  __shared__ float red[256];
  const int row = blockIdx.x, t = threadIdx.x;
  float v = (t < 151) ? logits[(size_t)row * 151 + t] : -3.0e38f;
  red[t] = v; __syncthreads();
  for (int s = 128; s > 0; s >>= 1) { if (t < s) red[t] = fmaxf(red[t], red[t + s]); __syncthreads(); }
  float mx = red[0]; __syncthreads();
  float p = (t < 151) ? expf(v - mx) : 0.f;
  red[t] = p; __syncthreads();
  for (int s = 128; s > 0; s >>= 1) { if (t < s) red[t] += red[t + s]; __syncthreads(); }
  float sum = red[0]; __syncthreads();
  p = p / sum;
  if (t < 192) probsb[(size_t)row * 192 + t] = __float2bfloat16((t < 151) ? p : 0.f);
  red[t] = (t >= 1 && t < 151) ? p : 0.f; __syncthreads();
  for (int s = 128; s > 0; s >>= 1) { if (t < s) red[t] = fmaxf(red[t], red[t + s]); __syncthreads(); }
  if (t == 0) conf[row] = red[0];

  if (t < 128) {
    float x1 = boxes[row * 4 + 0], y1 = boxes[row * 4 + 1];
    float x2 = boxes[row * 4 + 2], y2 = boxes[row * 4 + 3];
    float cs[4] = { (x1 + x2) * 0.5f, (y1 + y2) * 0.5f, x2 - x1, y2 - y1 };
    float a = pos_b[t];
    #pragma unroll
    for (int j = 0; j < 4; j++) {
      float cn = (cs[j] - bn_m[j]) * rsqrtf(bn_v[j] + 1e-5f) * bn_g[j] + bn_b[j];
      a += cn * pos_w[j * 128 + t];
    }
    FE[(size_t)row * FE_LD + 2760 + t] = __float2bfloat16(fmaxf(a, 0.f));
  }
  for (int c0 = t; c0 < 2048; c0 += 256)
    FE[(size_t)row * FE_LD + 512 + c0] = __float2bfloat16(fmaps[(size_t)row * 2048 + c0]);
}

// ---------------------------------------------------------------------------
// Per-image bitonic sort of conf desc (tie: index asc) -> perm (global rows).
// ---------------------------------------------------------------------------
__global__ void sort_kernel(const float* __restrict__ conf, int* __restrict__ perm)
{
  __shared__ float key[128];
  __shared__ int   idx[128];
  const int b = blockIdx.x, t = threadIdx.x;
  key[t] = conf[b * 128 + t]; idx[t] = t;
  __syncthreads();
  for (int k = 2; k <= 128; k <<= 1)
    for (int j = k >> 1; j > 0; j >>= 1) {
      int ixj = t ^ j;
      if (ixj > t) {
        bool up = (t & k) == 0;
        float ka = key[t], kb = key[ixj];
        int ia = idx[t], ib = idx[ixj];
        bool before = (ka > kb) || (ka == kb && ia < ib);
        if (before != up) { key[t] = kb; key[ixj] = ka; idx[t] = ib; idx[ixj] = ia; }
      }
      __syncthreads();
    }
  perm[b * 128 + t] = b * 128 + idx[t];
}

// ---------------------------------------------------------------------------
// LSTM scan, i8 weights, kg-split, 40 resident weight regs (unchanged R12).
// ---------------------------------------------------------------------------
__global__ __launch_bounds__(1024) void rec_kernel(
    const __hip_bfloat16* __restrict__ P,
    const int* __restrict__ perm,
    const u32* __restrict__ wreg_g,
    const uint4* __restrict__ wlds_g,
    const float* __restrict__ wsc_g,
    int gatherPerm, int outPerm,
    __hip_bfloat16* __restrict__ out_bf, int out_ld,
    float* __restrict__ out_f32, int f32_ld, int f32_off)
{
  __shared__ __align__(16) uint4 wt4[6 * 1024];
  __shared__ __align__(16) int4 part[256 * 5];
  __shared__ __align__(16) u32 hq[64];
  __shared__ int prow_lds[128];
  const int tid = threadIdx.x;
  const int kg = tid >> 8;
  const int img = blockIdx.x & 31, dir = blockIdx.x >> 5;

  u32 wv[40];
  {
    const u32* rp = wreg_g + (size_t)dir * 40960 + tid;
    #pragma unroll
    for (int i = 0; i < 40; i++) wv[i] = rp[(size_t)i * 1024];
  }
  #pragma unroll
  for (int i = 0; i < 40; i++) asm volatile("" : "+v"(wv[i]));
  {
    const uint4* lp = wlds_g + (size_t)dir * 6144 + tid;
    #pragma unroll
    for (int q = 0; q < 6; q++) wt4[q * 1024 + tid] = lp[(size_t)q * 1024];
  }
  if (tid < 128) prow_lds[tid] = perm[img * 128 + tid];
  if (tid < 64) hq[tid] = 0;

  float sc0 = 0.f, sc1 = 0.f, sc2 = 0.f, sc3 = 0.f, cst = 0.f;
  if (tid < 256) {
    const float* sp = wsc_g + dir * 1024 + tid;
    sc0 = sp[0]; sc1 = sp[256]; sc2 = sp[512]; sc3 = sp[768];
  }
  __syncthreads();

  const uint4* hq4 = (const uint4*)hq;

  int st = dir ? 127 : 0;
  float p0 = 0.f, p1 = 0.f, p2 = 0.f, p3 = 0.f;
  if (tid < 256) {
    int prow0 = gatherPerm ? prow_lds[st] : (img * 128 + st);
    const __hip_bfloat16* pp = P + (size_t)prow0 * 2048 + dir * 1024 + tid;
    p0 = __bfloat162float(pp[0]);   p1 = __bfloat162float(pp[256]);
    p2 = __bfloat162float(pp[512]); p3 = __bfloat162float(pp[768]);
  }

  for (int t = 0; t < 128; t++) {
    float n0 = 0.f, n1 = 0.f, n2 = 0.f, n3 = 0.f;
    if (tid < 256 && t < 127) {
      int stn = dir ? (126 - t) : (t + 1);
      int prn = gatherPerm ? prow_lds[stn] : (img * 128 + stn);
      const __hip_bfloat16* pp = P + (size_t)prn * 2048 + dir * 1024 + tid;
      n0 = __bfloat162float(pp[0]);   n1 = __bfloat162float(pp[256]);
      n2 = __bfloat162float(pp[512]); n3 = __bfloat162float(pp[768]);
    }

    int a0 = 0, a1 = 0, a2 = 0, a3 = 0;
    {
      uint4 hv = hq4[kg * 4 + 0];
      a0 = sdot4(hv.x, wv[0], a0);  a0 = sdot4(hv.y, wv[1], a0);
      a0 = sdot4(hv.z, wv[2], a0);  a0 = sdot4(hv.w, wv[3], a0);
      a1 = sdot4(hv.x, wv[12], a1); a1 = sdot4(hv.y, wv[13], a1);
      a1 = sdot4(hv.z, wv[14], a1); a1 = sdot4(hv.w, wv[15], a1);
      a2 = sdot4(hv.x, wv[24], a2); a2 = sdot4(hv.y, wv[25], a2);
      a2 = sdot4(hv.z, wv[26], a2); a2 = sdot4(hv.w, wv[27], a2);
      a3 = sdot4(hv.x, wv[32], a3); a3 = sdot4(hv.y, wv[33], a3);
      a3 = sdot4(hv.z, wv[34], a3); a3 = sdot4(hv.w, wv[35], a3);
    }
    {
      uint4 hv = hq4[kg * 4 + 1];
      a0 = sdot4(hv.x, wv[4], a0);  a0 = sdot4(hv.y, wv[5], a0);
      a0 = sdot4(hv.z, wv[6], a0);  a0 = sdot4(hv.w, wv[7], a0);
      a1 = sdot4(hv.x, wv[16], a1); a1 = sdot4(hv.y, wv[17], a1);
      a1 = sdot4(hv.z, wv[18], a1); a1 = sdot4(hv.w, wv[19], a1);
      a2 = sdot4(hv.x, wv[28], a2); a2 = sdot4(hv.y, wv[29], a2);
      a2 = sdot4(hv.z, wv[30], a2); a2 = sdot4(hv.w, wv[31], a2);
      a3 = sdot4(hv.x, wv[36], a3); a3 = sdot4(hv.y, wv[37], a3);
      a3 = sdot4(hv.z, wv[38], a3); a3 = sdot4(hv.w, wv[39], a3);
    }
    {
      uint4 hv = hq4[kg * 4 + 2];
      a0 = sdot4(hv.x, wv[8], a0);  a0 = sdot4(hv.y, wv[9], a0);
      a0 = sdot4(hv.z, wv[10], a0); a0 = sdot4(hv.w, wv[11], a0);
      a1 = sdot4(hv.x, wv[20], a1); a1 = sdot4(hv.y, wv[21], a1);
      a1 = sdot4(hv.z, wv[22], a1); a1 = sdot4(hv.w, wv[23], a1);
      uint4 wl = wt4[2 * 1024 + tid];
      a2 = sdot4(hv.x, wl.x, a2); a2 = sdot4(hv.y, wl.y, a2);
      a2 = sdot4(hv.z, wl.z, a2); a2 = sdot4(hv.w, wl.w, a2);
      wl = wt4[4 * 1024 + tid];
      a3 = sdot4(hv.x, wl.x, a3); a3 = sdot4(hv.y, wl.y, a3);
      a3 = sdot4(hv.z, wl.z, a3); a3 = sdot4(hv.w, wl.w, a3);
    }
    {
      uint4 hv = hq4[kg * 4 + 3];
      uint4 wl = wt4[0 * 1024 + tid];
      a0 = sdot4(hv.x, wl.x, a0); a0 = sdot4(hv.y, wl.y, a0);
      a0 = sdot4(hv.z, wl.z, a0); a0 = sdot4(hv.w, wl.w, a0);
      wl = wt4[1 * 1024 + tid];
      a1 = sdot4(hv.x, wl.x, a1); a1 = sdot4(hv.y, wl.y, a1);
      a1 = sdot4(hv.z, wl.z, a1); a1 = sdot4(hv.w, wl.w, a1);
      wl = wt4[3 * 1024 + tid];
      a2 = sdot4(hv.x, wl.x, a2); a2 = sdot4(hv.y, wl.y, a2);
      a2 = sdot4(hv.z, wl.z, a2); a2 = sdot4(hv.w, wl.w, a2);
      wl = wt4[5 * 1024 + tid];
      a3 = sdot4(hv.x, wl.x, a3); a3 = sdot4(hv.y, wl.y, a3);
      a3 = sdot4(hv.z, wl.z, a3); a3 = sdot4(hv.w, wl.w, a3);
    }

    part[(tid & 255) * 5 + kg] = int4{a0, a1, a2, a3};
    __syncthreads();

    if (tid < 256) {
      int4 q0 = part[tid * 5 + 0], q1 = part[tid * 5 + 1];
      int4 q2 = part[tid * 5 + 2], q3 = part[tid * 5 + 3];
      float gi = (float)(q0.x + q1.x + q2.x + q3.x) * sc0 + p0;
      float gf = (float)(q0.y + q1.y + q2.y + q3.y) * sc1 + p1;
      float gg = (float)(q0.z + q1.z + q2.z + q3.z) * sc2 + p2;
      float go = (float)(q0.w + q1.w + q2.w + q3.w) * sc3 + p3;
      float si = fsig(gi), sf = fsig(gf), so = fsig(go);
      cst = sf * cst + si * ftanh(gg);
      float h = so * ftanh(cst);
      int qi = __float2int_rn(h * 127.f);
      ((signed char*)hq)[tid] = (signed char)qi;
      const int orow = outPerm ? prow_lds[st] : (img * 128 + st);
      if (out_bf)  out_bf[(size_t)orow * out_ld + dir * 256 + tid] = __float2bfloat16(h);
      if (out_f32) out_f32[(size_t)orow * f32_ld + f32_off + dir * 256 + tid] = h;
    }
    __syncthreads();
    p0 = n0; p1 = n1; p2 = n2; p3 = n3;
    st = dir ? (st - 1) : (st + 1);
  }
}

// ---------------------------------------------------------------------------
// Fused argmax over dists[:,1:151) + edge build.
// ---------------------------------------------------------------------------
__global__ void argmax_edge_kernel(const float* __restrict__ dists,
                                   const float* __restrict__ embed2,
                                   const float* __restrict__ fmaps,
                                   const __hip_bfloat16* __restrict__ FE,
                                   __hip_bfloat16* __restrict__ EDGE)
{
  __shared__ float rv[256];
  __shared__ int   ri[256];
  const int row = blockIdx.x, t = threadIdx.x;

  float best = (t < 150) ? dists[(size_t)row * 663 + 1 + t] : -3.4e38f;
  int   bi   = (t < 150) ? (1 + t) : 1000;
  rv[t] = best; ri[t] = bi;
  __syncthreads();
  for (int s = 128; s > 0; s >>= 1) {
    if (t < s) {
      float ov = rv[t + s]; int oi = ri[t + s];
      if (ov > rv[t] || (ov == rv[t] && oi < ri[t])) { rv[t] = ov; ri[t] = oi; }
    }
    __syncthreads();
  }
  const int pr = ri[0];

  for (int c0 = t; c0 < 200; c0 += 256)
    EDGE[(size_t)row * EDGE_LD + c0] = __float2bfloat16(embed2[(size_t)pr * 200 + c0]);
  for (int c0 = t; c0 < 512; c0 += 256)
    EDGE[(size_t)row * EDGE_LD + 200 + c0] = FE[(size_t)row * FE_LD + c0];
  for (int c0 = t; c0 < 2048; c0 += 256)
    EDGE[(size_t)row * EDGE_LD + 712 + c0] = __float2bfloat16(fmaps[(size_t)row * 2048 + c0]);
}

// ---------------------------------------------------------------------------
extern "C" void kernel_launch(void* const* d_in, const int* in_sizes, int n_in,
                              void* d_out, int out_size, void* d_ws, size_t ws_size,
                              hipStream_t stream)
{
  const float* obj_fmaps    = (const float*)d_in[0];
  const float* obj_logits   = (const float*)d_in[1];
  const float* boxes        = (const float*)d_in[2];
  const float* obj_embed_w  = (const float*)d_in[4];
  const float* obj_embed2_w = (const float*)d_in[5];
  const float* bn_g = (const float*)d_in[6];
  const float* bn_b = (const float*)d_in[7];
  const float* bn_m = (const float*)d_in[8];
  const float* bn_v = (const float*)d_in[9];
  const float* pos_w = (const float*)d_in[10];
  const float* pos_b = (const float*)d_in[11];
  const float* obj_wih0 = (const float*)d_in[12];
  const float* obj_whh0 = (const float*)d_in[13];
  const float* obj_b0   = (const float*)d_in[14];
  const float* obj_wih1 = (const float*)d_in[15];
  const float* obj_whh1 = (const float*)d_in[16];
  const float* obj_b1   = (const float*)d_in[17];
  const float* edge_wih0 = (const float*)d_in[18];
  const float* edge_whh0 = (const float*)d_in[19];
  const float* edge_b0   = (const float*)d_in[20];
  const float* edge_wih1 = (const float*)d_in[21];
  const float* edge_whh1 = (const float*)d_in[22];
  const float* edge_b1   = (const float*)d_in[23];
  const float* dec_w = (const float*)d_in[24];
  const float* dec_b = (const float*)d_in[25];
  float* out = (float*)d_out;

  char* ws = (char*)d_ws;
  auto alloc = [&](size_t bytes) -> char* {
    char* p = ws; ws += (bytes + 255) & ~(size_t)255; return p;
  };
  __hip_bfloat16* FE     = (__hip_bfloat16*)alloc(4096ull * FE_LD * 2);
  __hip_bfloat16* EDGE   = (__hip_bfloat16*)alloc(4096ull * EDGE_LD * 2);
  __hip_bfloat16* Pbuf   = (__hip_bfloat16*)alloc(4096ull * 2048 * 2);
  __hip_bfloat16* hseq   = (__hip_bfloat16*)alloc(4096ull * 512 * 2);
  __hip_bfloat16* probsb = (__hip_bfloat16*)alloc(4096ull * 192 * 2);
  __hip_bfloat16* wih0T  = (__hip_bfloat16*)alloc(2048ull * 2432 * 2);
  __hip_bfloat16* wih1T  = (__hip_bfloat16*)alloc(2048ull * 512 * 2);
  __hip_bfloat16* ewih0T = (__hip_bfloat16*)alloc(2048ull * 2816 * 2);
  __hip_bfloat16* ewih1T = (__hip_bfloat16*)alloc(2048ull * 512 * 2);
  __hip_bfloat16* embedT = (__hip_bfloat16*)alloc(256ull * 192 * 2);
  __hip_bfloat16* decT   = (__hip_bfloat16*)alloc(256ull * 2944 * 2);
  u32* whh0pk  = (u32*)alloc(133120ull * 4);
  u32* whh1pk  = (u32*)alloc(133120ull * 4);
  u32* ewhh0pk = (u32*)alloc(133120ull * 4);
  u32* ewhh1pk = (u32*)alloc(133120ull * 4);
  u8*  FEq     = (u8*)alloc(4096ull * 2432);
  u8*  EDGEq   = (u8*)alloc(4096ull * 2816);
  u8*  wih0q   = (u8*)alloc(2048ull * 2432);
  u8*  ewih0q  = (u8*)alloc(2048ull * 2816);
  float* ascFE   = (float*)alloc(4096 * 4);
  float* ascEDGE = (float*)alloc(4096 * 4);
  float* bsc0    = (float*)alloc(2048 * 4);
  float* bsc1    = (float*)alloc(2048 * 4);
  int*   perm  = (int*)alloc(4096 * 4);
  float* conf  = (float*)alloc(4096 * 4);
  (void)in_sizes; (void)n_in; (void)out_size; (void)ws_size;

  // ---- batched transposes ----
  TrOps tr{};
  int nt = 0, base = 0;
  auto addTr = [&](const float* src, __hip_bfloat16* dst, int srcK, int srcN,
                   int dstR, int dstC, int split, int soff) {
    tr.src[nt] = src; tr.dst[nt] = dst;
    tr.srcK[nt] = srcK; tr.srcN[nt] = srcN; tr.dstR[nt] = dstR; tr.dstC[nt] = dstC;
    tr.split[nt] = split; tr.soff[nt] = soff;
    int tx = (dstC + 31) / 32, ty = (dstR + 31) / 32;
    tr.tileBase[nt] = base; tr.tilesX[nt] = tx;
    base += tx * ty; nt++;
  };
  for (int d = 0; d < 2; d++) {
    addTr(obj_wih0 + (size_t)d * 2376 * 1024, wih0T + (size_t)d * 1024 * 2432, 2376, 1024, 1024, 2432, 0, 0);
    addTr(obj_wih1 + (size_t)d * 512 * 1024,  wih1T + (size_t)d * 1024 * 512,  512, 1024, 1024, 512, 0, 0);
    addTr(edge_wih0 + (size_t)d * 2760 * 1024, ewih0T + (size_t)d * 1024 * 2816, 2760, 1024, 1024, 2816, 0, 0);
    addTr(edge_wih1 + (size_t)d * 512 * 1024,  ewih1T + (size_t)d * 1024 * 512,  512, 1024, 1024, 512, 0, 0);
  }
  addTr(obj_embed_w, embedT, 151, 200, 256, 192, 0, 0);
  addTr(dec_w, decT, 2888, 151, 256, 2944, 512, 2376);
  transpose_batch<<<dim3(base), dim3(256), 0, stream>>>(tr);

  // ---- batched whh packs ----
  PkOps pk{};
  const float* whhs[4] = {obj_whh0, obj_whh1, edge_whh0, edge_whh1};
  u32* pks[4] = {whh0pk, whh1pk, ewhh0pk, ewhh1pk};
  for (int i = 0; i < 4; i++) {
    pk.whh[i] = whhs[i];
    pk.wreg[i] = pks[i];
    pk.wlds[i] = pks[i] + 81920;
    pk.wsc[i]  = (float*)(pks[i] + 131072);
  }
  pack_batch<<<dim3(8, 4), dim3(256), 0, stream>>>(pk);

  // ---- B-side i8 quant for the two big GEMMs ----
  quant_rows<<<dim3(2048), dim3(256), 0, stream>>>((const u16*)wih0T, 2432, 2432, wih0q, 2432, bsc0);
  quant_rows<<<dim3(2048), dim3(256), 0, stream>>>((const u16*)ewih0T, 2816, 2816, ewih0q, 2816, bsc1);

  prep_kernel<<<dim3(4096), dim3(256), 0, stream>>>(
      obj_logits, obj_fmaps, boxes, bn_g, bn_b, bn_m, bn_v, pos_w, pos_b, FE, probsb, conf);
  sort_kernel<<<dim3(32), dim3(128), 0, stream>>>(conf, perm);

  auto gemm = [&](const void* A, int lda, const void* B, int ldb, int K, int N,
                  float* oF, __hip_bfloat16* oB, int ldc, const float* bias) {
    int gy = (N + 127) / 128;
    gemm_kernel<<<dim3(32 * gy), dim3(256), 0, stream>>>(
        (const u16*)A, lda, (const u16*)B, ldb, K, N, gy, oF, oB, ldc, bias);
  };
  auto gemm_i8 = [&](const u8* A, int lda, const u8* B, int ldb, int K, int N,
                     const float* asc, const float* bsc,
                     __hip_bfloat16* oB, int ldc, const float* bias) {
    int gy = (N + 127) / 128;
    gemm_i8_kernel<<<dim3(32 * gy), dim3(256), 0, stream>>>(
        A, lda, B, ldb, K, N, gy, asc, bsc, oB, ldc, bias);
  };
  auto rec = [&](const __hip_bfloat16* P, const u32* wpk, int gat, int op,
                 __hip_bfloat16* ob, int old_, float* of, int fld, int foff) {
    rec_kernel<<<dim3(64), dim3(1024), 0, stream>>>(
        P, perm, wpk, (const uint4*)(wpk + 81920), (const float*)(wpk + 131072),
        gat, op, ob, old_, of, fld, foff);
  };

  // obj_embed -> FE cols [2560,2760)
  gemm(probsb, 192, embedT, 192, 192, 200, nullptr, FE + 2560, FE_LD, nullptr);
  // quantize FE feature slice, then obj layer 0 (i8)
  quant_rows<<<dim3(4096), dim3(256), 0, stream>>>((const u16*)FE + 512, FE_LD, 2432, FEq, 2432, ascFE);
  gemm_i8(FEq, 2432, wih0q, 2432, 2432, 2048, ascFE, bsc0, Pbuf, 2048, obj_b0);
  rec(Pbuf, whh0pk, 1, 0, hseq, 512, nullptr, 0, 0);
  // obj layer 1 -> enc into FE cols [0,512)
  gemm(hseq, 512, wih1T, 512, 512, 2048, nullptr, Pbuf, 2048, obj_b1);
  rec(Pbuf, whh1pk, 0, 1, FE, FE_LD, nullptr, 0, 0);
  // decoder -> out cols [0,151)
  gemm(FE, FE_LD, decT, 2944, 2944, 151, out, nullptr, 663, dec_b);
  // fused argmax + edge build
  argmax_edge_kernel<<<dim3(4096), dim3(256), 0, stream>>>(
      out, obj_embed2_w, obj_fmaps, FE, EDGE);
  // quantize EDGE, then edge layer 0 (i8)
  quant_rows<<<dim3(4096), dim3(256), 0, stream>>>((const u16*)EDGE, EDGE_LD, 2816, EDGEq, 2816, ascEDGE);
  gemm_i8(EDGEq, 2816, ewih0q, 2816, 2816, 2048, ascEDGE, bsc1, Pbuf, 2048, edge_b0);
  rec(Pbuf, ewhh0pk, 1, 0, hseq, 512, nullptr, 0, 0);
  // edge layer 1 -> out cols [151,663)
  gemm(hseq, 512, ewih1T, 512, 512, 2048, nullptr, Pbuf, 2048, edge_b1);
  rec(Pbuf, ewhh1pk, 0, 1, nullptr, 0, out, 663, 151);
}

// Round 15
// 822.378 us; speedup vs baseline: 1.3134x; 1.0508x over previous
//
#include <hip/hip_runtime.h>
#include <hip/hip_bf16.h>
#include <hip/hip_fp16.h>

typedef unsigned short u16;
typedef unsigned char u8;
typedef unsigned int u32;
typedef short s16x8 __attribute__((ext_vector_type(8)));
typedef float f32x4 __attribute__((ext_vector_type(4)));
typedef int i32x4 __attribute__((ext_vector_type(4)));

#define FE_LD 2944
#define EDGE_LD 2816

static __device__ __forceinline__ int sdot4(u32 a, u32 b, int acc) {
  return __builtin_amdgcn_sdot4((int)a, (int)b, acc, false);
}
static __device__ __forceinline__ float fsig(float x) {
  return __builtin_amdgcn_rcpf(1.f + __expf(-x));
}
static __device__ __forceinline__ float ftanh(float x) {
  return 1.f - 2.f * __builtin_amdgcn_rcpf(1.f + __expf(2.f * x));
}

#define GLD_LDS16(gsrc, ldst) \
  __builtin_amdgcn_global_load_lds((const __attribute__((address_space(1))) void*)(gsrc), \
                                   (__attribute__((address_space(3))) void*)(ldst), 16, 0, 0)

// XCD-aware swizzle: 1-D grid (nwg % 8 == 0).
static __device__ __forceinline__ void xcd_map(int gy, int* bx, int* by) {
  int lin = blockIdx.x;
  int q = gridDim.x >> 3;
  int wg = (lin & 7) * q + (lin >> 3);
  *bx = wg / gy; *by = wg % gy;
}

// ---------------------------------------------------------------------------
// bf16 MFMA GEMM (unchanged R14)
// ---------------------------------------------------------------------------
__global__ __launch_bounds__(256) void gemm_kernel(
    const u16* __restrict__ A, int lda,
    const u16* __restrict__ B, int ldb,
    int K, int N, int gy,
    float* __restrict__ outF, __hip_bfloat16* __restrict__ outB, int ldc,
    const float* __restrict__ bias)
{
  __shared__ __align__(16) u16 As[128*64];
  __shared__ __align__(16) u16 Bs[128*64];
  const int tid = threadIdx.x;
  const int w = tid >> 6, lane = tid & 63;
  const int wm = w >> 1, wn = w & 1;
  int bxi, byi; xcd_map(gy, &bxi, &byi);
  const long bm = (long)bxi * 128;
  const long bn = (long)byi * 128;
  f32x4 acc[4][4] = {};

  for (int k0 = 0; k0 < K; k0 += 64) {
    #pragma unroll
    for (int rr = 0; rr < 4; rr++) {
      int idx = rr * 256 + tid;
      int row = idx >> 3;
      int g   = idx & 7;
      int gs  = g ^ (row & 7);
      int ldst = (rr * 256 + (w << 6)) * 8;
      GLD_LDS16(A + (bm + row) * (long)lda + k0 + gs * 8, &As[ldst]);
      GLD_LDS16(B + (bn + row) * (long)ldb + k0 + gs * 8, &Bs[ldst]);
    }
    __syncthreads();
    #pragma unroll
    for (int kk = 0; kk < 2; kk++) {
      s16x8 af[4], bfr[4];
      #pragma unroll
      for (int i = 0; i < 4; i++) {
        int ra = wm * 64 + i * 16 + (lane & 15);
        int rb = wn * 64 + i * 16 + (lane & 15);
        int gg = kk * 4 + (lane >> 4);
        af[i]  = *(const s16x8*)&As[ra * 64 + ((gg ^ (ra & 7)) << 3)];
        bfr[i] = *(const s16x8*)&Bs[rb * 64 + ((gg ^ (rb & 7)) << 3)];
      }
      #pragma unroll
      for (int i = 0; i < 4; i++)
        #pragma unroll
        for (int j = 0; j < 4; j++)
          acc[i][j] = __builtin_amdgcn_mfma_f32_16x16x32_bf16(af[i], bfr[j], acc[i][j], 0, 0, 0);
    }
    __syncthreads();
  }

  #pragma unroll
  for (int i = 0; i < 4; i++)
    #pragma unroll
    for (int j = 0; j < 4; j++)
      #pragma unroll
      for (int v = 0; v < 4; v++) {
        long rr = bm + wm * 64 + i * 16 + (lane >> 4) * 4 + v;
        int  cc = (int)bn + wn * 64 + j * 16 + (lane & 15);
        if (cc < N) {
          float val = acc[i][j][v] + (bias ? bias[cc] : 0.f);
          if (outF) outF[rr * (long)ldc + cc] = val;
          else      outB[rr * (long)ldc + cc] = __float2bfloat16(val);
        }
      }
}

// ---------------------------------------------------------------------------
// i8 MFMA GEMM (unchanged R14)
// ---------------------------------------------------------------------------
__global__ __launch_bounds__(256) void gemm_i8_kernel(
    const u8* __restrict__ A, int lda,
    const u8* __restrict__ B, int ldb,
    int K, int N, int gy,
    const float* __restrict__ asc, const float* __restrict__ bsc,
    __hip_bfloat16* __restrict__ outB, int ldc,
    const float* __restrict__ bias)
{
  __shared__ __align__(16) u8 As[128*128];
  __shared__ __align__(16) u8 Bs[128*128];
  const int tid = threadIdx.x;
  const int w = tid >> 6, lane = tid & 63;
  const int wm = w >> 1, wn = w & 1;
  int bxi, byi; xcd_map(gy, &bxi, &byi);
  const long bm = (long)bxi * 128;
  const long bn = (long)byi * 128;
  i32x4 acc[4][4] = {};

  for (int k0 = 0; k0 < K; k0 += 128) {
    #pragma unroll
    for (int rr = 0; rr < 4; rr++) {
      int idx = rr * 256 + tid;
      int row = idx >> 3;
      int g   = idx & 7;
      int gs  = g ^ (row & 7);
      int ldst = (rr * 256 + (w << 6)) * 16;
      GLD_LDS16(A + (bm + row) * (long)lda + k0 + gs * 16, &As[ldst]);
      GLD_LDS16(B + (bn + row) * (long)ldb + k0 + gs * 16, &Bs[ldst]);
    }
    __syncthreads();
    #pragma unroll
    for (int kk = 0; kk < 2; kk++) {
      i32x4 af[4], bfr[4];
      #pragma unroll
      for (int i = 0; i < 4; i++) {
        int ra = wm * 64 + i * 16 + (lane & 15);
        int rb = wn * 64 + i * 16 + (lane & 15);
        int gg = kk * 4 + (lane >> 4);
        af[i]  = __builtin_bit_cast(i32x4, *(const uint4*)&As[ra * 128 + ((gg ^ (ra & 7)) << 4)]);
        bfr[i] = __builtin_bit_cast(i32x4, *(const uint4*)&Bs[rb * 128 + ((gg ^ (rb & 7)) << 4)]);
      }
      #pragma unroll
      for (int i = 0; i < 4; i++)
        #pragma unroll
        for (int j = 0; j < 4; j++)
          acc[i][j] = __builtin_amdgcn_mfma_i32_16x16x64_i8(af[i], bfr[j], acc[i][j], 0, 0, 0);
    }
    __syncthreads();
  }

  #pragma unroll
  for (int i = 0; i < 4; i++)
    #pragma unroll
    for (int j = 0; j < 4; j++)
      #pragma unroll
      for (int v = 0; v < 4; v++) {
        long rr = bm + wm * 64 + i * 16 + (lane >> 4) * 4 + v;
        int  cc = (int)bn + wn * 64 + j * 16 + (lane & 15);
        if (cc < N) {
          float val = (float)acc[i][j][v] * asc[rr] * bsc[cc] + (bias ? bias[cc] : 0.f);
          outB[rr * (long)ldc + cc] = __float2bfloat16(val);
        }
      }
}

// ---------------------------------------------------------------------------
// Setup mega-kernel: block ranges = [transposes | whh packs | prep rows].
// prep: softmax -> conf; embed=probs@W (fp32); stage full feature row in LDS;
// write FE bf16 (fmaps/embed/pos, pad zero) AND FEq i8 + ascFE.
// ---------------------------------------------------------------------------
#define N_TROPS 9
struct SetupOps {
  // transposes
  const float* src[N_TROPS];
  __hip_bfloat16* dst[N_TROPS];
  int srcK[N_TROPS], srcN[N_TROPS], dstR[N_TROPS], dstC[N_TROPS];
  int split[N_TROPS], soff[N_TROPS];
  int tileBase[N_TROPS], tilesX[N_TROPS];
  int trEnd, pkEnd;          // block-range boundaries (prep follows pkEnd)
  // packs
  const float* whh[4];
  u32* wreg[4]; u32* wlds[4]; float* wsc[4];
  // prep
  const float* logits; const float* fmaps; const float* boxes;
  const float* bn_g; const float* bn_b; const float* bn_m; const float* bn_v;
  const float* pos_w; const float* pos_b; const float* embw;
  __hip_bfloat16* FE; u8* FEq; float* ascFE; float* conf;
};
__global__ __launch_bounds__(256) void setup_kernel(SetupOps ops)
{
  __shared__ float stage[2432];
  __shared__ float red[256];
  __shared__ float pf[151];
  const int bid = blockIdx.x, t = threadIdx.x;

  if (bid < ops.trEnd) {
    __shared__ float tile[32][33];
    int op = 0;
    #pragma unroll
    for (int i = 1; i < N_TROPS; i++) if (bid >= ops.tileBase[i]) op = i;
    const int local = bid - ops.tileBase[op];
    const int kt = (local % ops.tilesX[op]) * 32;
    const int nt = (local / ops.tilesX[op]) * 32;
    const float* src = ops.src[op];
    __hip_bfloat16* dst = ops.dst[op];
    const int srcK = ops.srcK[op], srcN = ops.srcN[op];
    const int dstR = ops.dstR[op], dstC = ops.dstC[op];
    const int split = ops.split[op], soff = ops.soff[op];
    const int tx = t & 31, ty = t >> 5;
    for (int i = ty; i < 32; i += 8) {
      int k = kt + i;
      int srck = (k < split) ? (soff + k) : (k - split);
      int n = nt + tx;
      tile[i][tx] = (srck < srcK && n < srcN) ? src[(size_t)srck * srcN + n] : 0.f;
    }
    __syncthreads();
    for (int i = ty; i < 32; i += 8) {
      int n = nt + i, k = kt + tx;
      if (n < dstR && k < dstC)
        dst[(size_t)n * dstC + k] = __float2bfloat16(tile[tx][i]);
    }
    return;
  }

  if (bid < ops.pkEnd) {
    const int local = bid - ops.trEnd;      // 0..31
    const int set = local >> 3;
    const int idx = (local & 7) * 256 + t;  // 0..2047
    const float* whh = ops.whh[set];
    u32* wreg = ops.wreg[set];
    u32* wlds = ops.wlds[set];
    float* wsc = ops.wsc[set];
    const int d = idx >> 10, col = idx & 1023;
    const int c4 = col >> 8, j = col & 255;
    const float* s = whh + (size_t)d * 256 * 1024 + col;
    float mx = 0.f;
    for (int k = 0; k < 256; k++) mx = fmaxf(mx, fabsf(s[(size_t)k * 1024]));
    float inv = (mx > 0.f) ? 127.f / mx : 0.f;
    wsc[d * 1024 + col] = (mx > 0.f) ? mx / (127.f * 127.f) : 0.f;
    const int rc = (c4 < 2) ? 12 : 8;
    const int rb = (c4 == 0) ? 0 : (c4 == 1) ? 12 : (c4 == 2) ? 24 : 32;
    for (int kg = 0; kg < 4; kg++) {
      const int slot = kg * 256 + j;
      for (int w = 0; w < 16; w++) {
        u32 v = 0;
        #pragma unroll
        for (int b = 0; b < 4; b++) {
          int q = __float2int_rn(s[(size_t)(kg * 64 + 4 * w + b) * 1024] * inv);
          q = max(-127, min(127, q));
          v |= ((u32)(q & 0xff)) << (8 * b);
        }
        if (w < rc) {
          wreg[(size_t)(d * 40 + rb + w) * 1024 + slot] = v;
        } else {
          int qq, comp;
          if (c4 == 0)      { qq = 0; comp = w - 12; }
          else if (c4 == 1) { qq = 1; comp = w - 12; }
          else if (c4 == 2) { qq = 2 + ((w - 8) >> 2); comp = (w - 8) & 3; }
          else              { qq = 4 + ((w - 8) >> 2); comp = (w - 8) & 3; }
          wlds[((size_t)(d * 6 + qq) * 1024 + slot) * 4 + comp] = v;
        }
      }
    }
    return;
  }

  // ---- prep rows ----
  const int row = bid - ops.pkEnd;
  float v = (t < 151) ? ops.logits[(size_t)row * 151 + t] : -3.0e38f;
  red[t] = v; __syncthreads();
  for (int s = 128; s > 0; s >>= 1) { if (t < s) red[t] = fmaxf(red[t], red[t + s]); __syncthreads(); }
  float mx = red[0]; __syncthreads();
  float p = (t < 151) ? expf(v - mx) : 0.f;
  red[t] = p; __syncthreads();
  for (int s = 128; s > 0; s >>= 1) { if (t < s) red[t] += red[t + s]; __syncthreads(); }
  float sum = red[0]; __syncthreads();
  p = p / sum;
  if (t < 151) pf[t] = p;
  red[t] = (t >= 1 && t < 151) ? p : 0.f; __syncthreads();
  for (int s = 128; s > 0; s >>= 1) { if (t < s) red[t] = fmaxf(red[t], red[t + s]); __syncthreads(); }
  if (t == 0) ops.conf[row] = red[0];
  __syncthreads();

  __hip_bfloat16* FE = ops.FE + (size_t)row * FE_LD;
  // fmaps -> stage[0..2048), FE[512..2560)
  for (int c0 = t; c0 < 2048; c0 += 256) {
    float f = ops.fmaps[(size_t)row * 2048 + c0];
    stage[c0] = f;
    FE[512 + c0] = __float2bfloat16(f);
  }
  // embed -> stage[2048..2248), FE[2560..2760)
  for (int c = t; c < 200; c += 256) {
    float e = 0.f;
    for (int k = 0; k < 151; k++) e += pf[k] * ops.embw[(size_t)k * 200 + c];
    stage[2048 + c] = e;
    FE[2560 + c] = __float2bfloat16(e);
  }
  // pos -> stage[2248..2376), FE[2760..2888)
  if (t < 128) {
    float x1 = ops.boxes[row * 4 + 0], y1 = ops.boxes[row * 4 + 1];
    float x2 = ops.boxes[row * 4 + 2], y2 = ops.boxes[row * 4 + 3];
    float cs[4] = { (x1 + x2) * 0.5f, (y1 + y2) * 0.5f, x2 - x1, y2 - y1 };
    float a = ops.pos_b[t];
    #pragma unroll
    for (int j = 0; j < 4; j++) {
      float cn = (cs[j] - ops.bn_m[j]) * rsqrtf(ops.bn_v[j] + 1e-5f) * ops.bn_g[j] + ops.bn_b[j];
      a += cn * ops.pos_w[j * 128 + t];
    }
    a = fmaxf(a, 0.f);
    stage[2248 + t] = a;
    FE[2760 + t] = __float2bfloat16(a);
  }
  // pad -> zero, stage[2376..2432), FE[2888..2944)
  if (t < 56) { stage[2376 + t] = 0.f; FE[2888 + t] = __float2bfloat16(0.f); }
  __syncthreads();

  // row quant of stage[0..2432) -> FEq + ascFE
  float qm = 0.f;
  for (int c = t; c < 2432; c += 256) qm = fmaxf(qm, fabsf(stage[c]));
  red[t] = qm; __syncthreads();
  for (int s = 128; s > 0; s >>= 1) { if (t < s) red[t] = fmaxf(red[t], red[t + s]); __syncthreads(); }
  qm = red[0];
  float inv = (qm > 0.f) ? 127.f / qm : 0.f;
  if (t == 0) ops.ascFE[row] = (qm > 0.f) ? qm / 127.f : 0.f;
  u32* d32 = (u32*)(ops.FEq + (size_t)row * 2432);
  for (int wd = t; wd < 608; wd += 256) {
    u32 vv = 0;
    #pragma unroll
    for (int b = 0; b < 4; b++) {
      int q = __float2int_rn(stage[4 * wd + b] * inv);
      q = max(-127, min(127, q));
      vv |= ((u32)(q & 0xff)) << (8 * b);
    }
    d32[wd] = vv;
  }
}

// ---------------------------------------------------------------------------
// quant-weights (2x2048 rows) + per-image sort, one launch via block ranges.
// ---------------------------------------------------------------------------
__global__ __launch_bounds__(256) void quantw_sort_kernel(
    const u16* __restrict__ w0, u8* __restrict__ w0q, float* __restrict__ bsc0,
    const u16* __restrict__ w1, u8* __restrict__ w1q, float* __restrict__ bsc1,
    const float* __restrict__ conf, int* __restrict__ perm)
{
  const int bid = blockIdx.x, t = threadIdx.x;
  if (bid < 4096) {
    __shared__ float red[256];
    const int row = (bid < 2048) ? bid : (bid - 2048);
    const u16* src = (bid < 2048) ? w0 : w1;
    u8* dst = (bid < 2048) ? w0q : w1q;
    float* sc = (bid < 2048) ? bsc0 : bsc1;
    const int K = (bid < 2048) ? 2432 : 2816;
    const u16* s = src + (size_t)row * K;
    float mx = 0.f;
    for (int c = t; c < K; c += 256) {
      u32 u = (u32)s[c] << 16;
      mx = fmaxf(mx, fabsf(__builtin_bit_cast(float, u)));
    }
    red[t] = mx; __syncthreads();
    for (int st = 128; st > 0; st >>= 1) { if (t < st) red[t] = fmaxf(red[t], red[t + st]); __syncthreads(); }
    mx = red[0];
    float inv = (mx > 0.f) ? 127.f / mx : 0.f;
    if (t == 0) sc[row] = (mx > 0.f) ? mx / 127.f : 0.f;
    u32* d32 = (u32*)(dst + (size_t)row * K);
    for (int wd = t; wd < (K >> 2); wd += 256) {
      u32 v = 0;
      #pragma unroll
      for (int b = 0; b < 4; b++) {
        u32 u = (u32)s[4 * wd + b] << 16;
        int q = __float2int_rn(__builtin_bit_cast(float, u) * inv);
        q = max(-127, min(127, q));
        v |= ((u32)(q & 0xff)) << (8 * b);
      }
      d32[wd] = v;
    }
    return;
  }
  // sort range: blocks 4096..4128
  {
    __shared__ float key[128];
    __shared__ int   idx[128];
    const int b = bid - 4096;
    if (t < 128) { key[t] = conf[b * 128 + t]; idx[t] = t; }
    __syncthreads();
    for (int k = 2; k <= 128; k <<= 1)
      for (int j = k >> 1; j > 0; j >>= 1) {
        if (t < 128) {
          int ixj = t ^ j;
          if (ixj > t) {
            bool up = (t & k) == 0;
            float ka = key[t], kb = key[ixj];
            int ia = idx[t], ib = idx[ixj];
            bool before = (ka > kb) || (ka == kb && ia < ib);
            if (before != up) { key[t] = kb; key[ixj] = ka; idx[t] = ib; idx[ixj] = ia; }
          }
        }
        __syncthreads();
      }
    if (t < 128) perm[b * 128 + t] = b * 128 + idx[t];
  }
}

// ---------------------------------------------------------------------------
// LSTM scan (unchanged R12 structure).
// ---------------------------------------------------------------------------
__global__ __launch_bounds__(1024) void rec_kernel(
    const __hip_bfloat16* __restrict__ P,
    const int* __restrict__ perm,
    const u32* __restrict__ wreg_g,
    const uint4* __restrict__ wlds_g,
    const float* __restrict__ wsc_g,
    int gatherPerm, int outPerm,
    __hip_bfloat16* __restrict__ out_bf, int out_ld,
    float* __restrict__ out_f32, int f32_ld, int f32_off)
{
  __shared__ __align__(16) uint4 wt4[6 * 1024];
  __shared__ __align__(16) int4 part[256 * 5];
  __shared__ __align__(16) u32 hq[64];
  __shared__ int prow_lds[128];
  const int tid = threadIdx.x;
  const int kg = tid >> 8;
  const int img = blockIdx.x & 31, dir = blockIdx.x >> 5;

  u32 wv[40];
  {
    const u32* rp = wreg_g + (size_t)dir * 40960 + tid;
    #pragma unroll
    for (int i = 0; i < 40; i++) wv[i] = rp[(size_t)i * 1024];
  }
  #pragma unroll
  for (int i = 0; i < 40; i++) asm volatile("" : "+v"(wv[i]));
  {
    const uint4* lp = wlds_g + (size_t)dir * 6144 + tid;
    #pragma unroll
    for (int q = 0; q < 6; q++) wt4[q * 1024 + tid] = lp[(size_t)q * 1024];
  }
  if (tid < 128) prow_lds[tid] = perm[img * 128 + tid];
  if (tid < 64) hq[tid] = 0;

  float sc0 = 0.f, sc1 = 0.f, sc2 = 0.f, sc3 = 0.f, cst = 0.f;
  if (tid < 256) {
    const float* sp = wsc_g + dir * 1024 + tid;
    sc0 = sp[0]; sc1 = sp[256]; sc2 = sp[512]; sc3 = sp[768];
  }
  __syncthreads();

  const uint4* hq4 = (const uint4*)hq;

  int st = dir ? 127 : 0;
  float p0 = 0.f, p1 = 0.f, p2 = 0.f, p3 = 0.f;
  if (tid < 256) {
    int prow0 = gatherPerm ? prow_lds[st] : (img * 128 + st);
    const __hip_bfloat16* pp = P + (size_t)prow0 * 2048 + dir * 1024 + tid;
    p0 = __bfloat162float(pp[0]);   p1 = __bfloat162float(pp[256]);
    p2 = __bfloat162float(pp[512]); p3 = __bfloat162float(pp[768]);
  }

  for (int t = 0; t < 128; t++) {
    float n0 = 0.f, n1 = 0.f, n2 = 0.f, n3 = 0.f;
    if (tid < 256 && t < 127) {
      int stn = dir ? (126 - t) : (t + 1);
      int prn = gatherPerm ? prow_lds[stn] : (img * 128 + stn);
      const __hip_bfloat16* pp = P + (size_t)prn * 2048 + dir * 1024 + tid;
      n0 = __bfloat162float(pp[0]);   n1 = __bfloat162float(pp[256]);
      n2 = __bfloat162float(pp[512]); n3 = __bfloat162float(pp[768]);
    }

    int a0 = 0, a1 = 0, a2 = 0, a3 = 0;
    {
      uint4 hv = hq4[kg * 4 + 0];
      a0 = sdot4(hv.x, wv[0], a0);  a0 = sdot4(hv.y, wv[1], a0);
      a0 = sdot4(hv.z, wv[2], a0);  a0 = sdot4(hv.w, wv[3], a0);
      a1 = sdot4(hv.x, wv[12], a1); a1 = sdot4(hv.y, wv[13], a1);
      a1 = sdot4(hv.z, wv[14], a1); a1 = sdot4(hv.w, wv[15], a1);
      a2 = sdot4(hv.x, wv[24], a2); a2 = sdot4(hv.y, wv[25], a2);
      a2 = sdot4(hv.z, wv[26], a2); a2 = sdot4(hv.w, wv[27], a2);
      a3 = sdot4(hv.x, wv[32], a3); a3 = sdot4(hv.y, wv[33], a3);
      a3 = sdot4(hv.z, wv[34], a3); a3 = sdot4(hv.w, wv[35], a3);
    }
    {
      uint4 hv = hq4[kg * 4 + 1];
      a0 = sdot4(hv.x, wv[4], a0);  a0 = sdot4(hv.y, wv[5], a0);
      a0 = sdot4(hv.z, wv[6], a0);  a0 = sdot4(hv.w, wv[7], a0);
      a1 = sdot4(hv.x, wv[16], a1); a1 = sdot4(hv.y, wv[17], a1);
      a1 = sdot4(hv.z, wv[18], a1); a1 = sdot4(hv.w, wv[19], a1);
      a2 = sdot4(hv.x, wv[28], a2); a2 = sdot4(hv.y, wv[29], a2);
      a2 = sdot4(hv.z, wv[30], a2); a2 = sdot4(hv.w, wv[31], a2);
      a3 = sdot4(hv.x, wv[36], a3); a3 = sdot4(hv.y, wv[37], a3);
      a3 = sdot4(hv.z, wv[38], a3); a3 = sdot4(hv.w, wv[39], a3);
    }
    {
      uint4 hv = hq4[kg * 4 + 2];
      a0 = sdot4(hv.x, wv[8], a0);  a0 = sdot4(hv.y, wv[9], a0);
      a0 = sdot4(hv.z, wv[10], a0); a0 = sdot4(hv.w, wv[11], a0);
      a1 = sdot4(hv.x, wv[20], a1); a1 = sdot4(hv.y, wv[21], a1);
      a1 = sdot4(hv.z, wv[22], a1); a1 = sdot4(hv.w, wv[23], a1);
      uint4 wl = wt4[2 * 1024 + tid];
      a2 = sdot4(hv.x, wl.x, a2); a2 = sdot4(hv.y, wl.y, a2);
      a2 = sdot4(hv.z, wl.z, a2); a2 = sdot4(hv.w, wl.w, a2);
      wl = wt4[4 * 1024 + tid];
      a3 = sdot4(hv.x, wl.x, a3); a3 = sdot4(hv.y, wl.y, a3);
      a3 = sdot4(hv.z, wl.z, a3); a3 = sdot4(hv.w, wl.w, a3);
    }
    {
      uint4 hv = hq4[kg * 4 + 3];
      uint4 wl = wt4[0 * 1024 + tid];
      a0 = sdot4(hv.x, wl.x, a0); a0 = sdot4(hv.y, wl.y, a0);
      a0 = sdot4(hv.z, wl.z, a0); a0 = sdot4(hv.w, wl.w, a0);
      wl = wt4[1 * 1024 + tid];
      a1 = sdot4(hv.x, wl.x, a1); a1 = sdot4(hv.y, wl.y, a1);
      a1 = sdot4(hv.z, wl.z, a1); a1 = sdot4(hv.w, wl.w, a1);
      wl = wt4[3 * 1024 + tid];
      a2 = sdot4(hv.x, wl.x, a2); a2 = sdot4(hv.y, wl.y, a2);
      a2 = sdot4(hv.z, wl.z, a2); a2 = sdot4(hv.w, wl.w, a2);
      wl = wt4[5 * 1024 + tid];
      a3 = sdot4(hv.x, wl.x, a3); a3 = sdot4(hv.y, wl.y, a3);
      a3 = sdot4(hv.z, wl.z, a3); a3 = sdot4(hv.w, wl.w, a3);
    }

    part[(tid & 255) * 5 + kg] = int4{a0, a1, a2, a3};
    __syncthreads();

    if (tid < 256) {
      int4 q0 = part[tid * 5 + 0], q1 = part[tid * 5 + 1];
      int4 q2 = part[tid * 5 + 2], q3 = part[tid * 5 + 3];
      float gi = (float)(q0.x + q1.x + q2.x + q3.x) * sc0 + p0;
      float gf = (float)(q0.y + q1.y + q2.y + q3.y) * sc1 + p1;
      float gg = (float)(q0.z + q1.z + q2.z + q3.z) * sc2 + p2;
      float go = (float)(q0.w + q1.w + q2.w + q3.w) * sc3 + p3;
      float si = fsig(gi), sf = fsig(gf), so = fsig(go);
      cst = sf * cst + si * ftanh(gg);
      float h = so * ftanh(cst);
      int qi = __float2int_rn(h * 127.f);
      ((signed char*)hq)[tid] = (signed char)qi;
      const int orow = outPerm ? prow_lds[st] : (img * 128 + st);
      if (out_bf)  out_bf[(size_t)orow * out_ld + dir * 256 + tid] = __float2bfloat16(h);
      if (out_f32) out_f32[(size_t)orow * f32_ld + f32_off + dir * 256 + tid] = h;
    }
    __syncthreads();
    p0 = n0; p1 = n1; p2 = n2; p3 = n3;
    st = dir ? (st - 1) : (st + 1);
  }
}

// ---------------------------------------------------------------------------
// Fused argmax + edge-row build + i8 quant (no bf16 EDGE buffer).
// edge row = [embed2[pred] 200 | enc 512 | fmaps 2048 | pad 56] -> EDGEq, asc.
// ---------------------------------------------------------------------------
__global__ __launch_bounds__(256) void argmax_edge_kernel(
    const float* __restrict__ dists,
    const float* __restrict__ embed2,
    const float* __restrict__ fmaps,
    const __hip_bfloat16* __restrict__ FE,
    u8* __restrict__ EDGEq, float* __restrict__ ascEDGE)
{
  __shared__ float stage[EDGE_LD];
  __shared__ float rv[256];
  __shared__ int   ri[256];
  const int row = blockIdx.x, t = threadIdx.x;

  float best = (t < 150) ? dists[(size_t)row * 663 + 1 + t] : -3.4e38f;
  int   bi   = (t < 150) ? (1 + t) : 1000;
  rv[t] = best; ri[t] = bi;
  __syncthreads();
  for (int s = 128; s > 0; s >>= 1) {
    if (t < s) {
      float ov = rv[t + s]; int oi = ri[t + s];
      if (ov > rv[t] || (ov == rv[t] && oi < ri[t])) { rv[t] = ov; ri[t] = oi; }
    }
    __syncthreads();
  }
  const int pr = ri[0];

  for (int c0 = t; c0 < 200; c0 += 256)
    stage[c0] = embed2[(size_t)pr * 200 + c0];
  for (int c0 = t; c0 < 512; c0 += 256)
    stage[200 + c0] = __bfloat162float(FE[(size_t)row * FE_LD + c0]);
  for (int c0 = t; c0 < 2048; c0 += 256)
    stage[712 + c0] = fmaps[(size_t)row * 2048 + c0];
  if (t < 56) stage[2760 + t] = 0.f;
  __syncthreads();

  float qm = 0.f;
  for (int c = t; c < EDGE_LD; c += 256) qm = fmaxf(qm, fabsf(stage[c]));
  rv[t] = qm; __syncthreads();
  for (int s = 128; s > 0; s >>= 1) { if (t < s) rv[t] = fmaxf(rv[t], rv[t + s]); __syncthreads(); }
  qm = rv[0];
  float inv = (qm > 0.f) ? 127.f / qm : 0.f;
  if (t == 0) ascEDGE[row] = (qm > 0.f) ? qm / 127.f : 0.f;
  u32* d32 = (u32*)(EDGEq + (size_t)row * EDGE_LD);
  for (int wd = t; wd < (EDGE_LD >> 2); wd += 256) {
    u32 vv = 0;
    #pragma unroll
    for (int b = 0; b < 4; b++) {
      int q = __float2int_rn(stage[4 * wd + b] * inv);
      q = max(-127, min(127, q));
      vv |= ((u32)(q & 0xff)) << (8 * b);
    }
    d32[wd] = vv;
  }
}

// ---------------------------------------------------------------------------
extern "C" void kernel_launch(void* const* d_in, const int* in_sizes, int n_in,
                              void* d_out, int out_size, void* d_ws, size_t ws_size,
                              hipStream_t stream)
{
  const float* obj_fmaps    = (const float*)d_in[0];
  const float* obj_logits   = (const float*)d_in[1];
  const float* boxes        = (const float*)d_in[2];
  const float* obj_embed_w  = (const float*)d_in[4];
  const float* obj_embed2_w = (const float*)d_in[5];
  const float* bn_g = (const float*)d_in[6];
  const float* bn_b = (const float*)d_in[7];
  const float* bn_m = (const float*)d_in[8];
  const float* bn_v = (const float*)d_in[9];
  const float* pos_w = (const float*)d_in[10];
  const float* pos_b = (const float*)d_in[11];
  const float* obj_wih0 = (const float*)d_in[12];
  const float* obj_whh0 = (const float*)d_in[13];
  const float* obj_b0   = (const float*)d_in[14];
  const float* obj_wih1 = (const float*)d_in[15];
  const float* obj_whh1 = (const float*)d_in[16];
  const float* obj_b1   = (const float*)d_in[17];
  const float* edge_wih0 = (const float*)d_in[18];
  const float* edge_whh0 = (const float*)d_in[19];
  const float* edge_b0   = (const float*)d_in[20];
  const float* edge_wih1 = (const float*)d_in[21];
  const float* edge_whh1 = (const float*)d_in[22];
  const float* edge_b1   = (const float*)d_in[23];
  const float* dec_w = (const float*)d_in[24];
  const float* dec_b = (const float*)d_in[25];
  float* out = (float*)d_out;

  char* ws = (char*)d_ws;
  auto alloc = [&](size_t bytes) -> char* {
    char* p = ws; ws += (bytes + 255) & ~(size_t)255; return p;
  };
  __hip_bfloat16* FE     = (__hip_bfloat16*)alloc(4096ull * FE_LD * 2);
  __hip_bfloat16* Pbuf   = (__hip_bfloat16*)alloc(4096ull * 2048 * 2);
  __hip_bfloat16* hseq   = (__hip_bfloat16*)alloc(4096ull * 512 * 2);
  __hip_bfloat16* wih0T  = (__hip_bfloat16*)alloc(2048ull * 2432 * 2);
  __hip_bfloat16* wih1T  = (__hip_bfloat16*)alloc(2048ull * 512 * 2);
  __hip_bfloat16* ewih0T = (__hip_bfloat16*)alloc(2048ull * 2816 * 2);
  __hip_bfloat16* ewih1T = (__hip_bfloat16*)alloc(2048ull * 512 * 2);
  __hip_bfloat16* decT   = (__hip_bfloat16*)alloc(256ull * 2944 * 2);
  u32* whh0pk  = (u32*)alloc(133120ull * 4);
  u32* whh1pk  = (u32*)alloc(133120ull * 4);
  u32* ewhh0pk = (u32*)alloc(133120ull * 4);
  u32* ewhh1pk = (u32*)alloc(133120ull * 4);
  u8*  FEq     = (u8*)alloc(4096ull * 2432);
  u8*  EDGEq   = (u8*)alloc(4096ull * 2816);
  u8*  wih0q   = (u8*)alloc(2048ull * 2432);
  u8*  ewih0q  = (u8*)alloc(2048ull * 2816);
  float* ascFE   = (float*)alloc(4096 * 4);
  float* ascEDGE = (float*)alloc(4096 * 4);
  float* bsc0    = (float*)alloc(2048 * 4);
  float* bsc1    = (float*)alloc(2048 * 4);
  int*   perm  = (int*)alloc(4096 * 4);
  float* conf  = (float*)alloc(4096 * 4);
  (void)in_sizes; (void)n_in; (void)out_size; (void)ws_size;

  // ---- setup mega-launch: transposes + packs + prep ----
  SetupOps so{};
  int nt = 0, base = 0;
  auto addTr = [&](const float* src, __hip_bfloat16* dst, int srcK, int srcN,
                   int dstR, int dstC, int split, int soff) {
    so.src[nt] = src; so.dst[nt] = dst;
    so.srcK[nt] = srcK; so.srcN[nt] = srcN; so.dstR[nt] = dstR; so.dstC[nt] = dstC;
    so.split[nt] = split; so.soff[nt] = soff;
    int tx = (dstC + 31) / 32, ty = (dstR + 31) / 32;
    so.tileBase[nt] = base; so.tilesX[nt] = tx;
    base += tx * ty; nt++;
  };
  for (int d = 0; d < 2; d++) {
    addTr(obj_wih0 + (size_t)d * 2376 * 1024, wih0T + (size_t)d * 1024 * 2432, 2376, 1024, 1024, 2432, 0, 0);
    addTr(obj_wih1 + (size_t)d * 512 * 1024,  wih1T + (size_t)d * 1024 * 512,  512, 1024, 1024, 512, 0, 0);
    addTr(edge_wih0 + (size_t)d * 2760 * 1024, ewih0T + (size_t)d * 1024 * 2816, 2760, 1024, 1024, 2816, 0, 0);
    addTr(edge_wih1 + (size_t)d * 512 * 1024,  ewih1T + (size_t)d * 1024 * 512,  512, 1024, 1024, 512, 0, 0);
  }
  addTr(dec_w, decT, 2888, 151, 256, 2944, 512, 2376);
  so.trEnd = base;
  so.pkEnd = base + 32;
  const float* whhs[4] = {obj_whh0, obj_whh1, edge_whh0, edge_whh1};
  u32* pks[4] = {whh0pk, whh1pk, ewhh0pk, ewhh1pk};
  for (int i = 0; i < 4; i++) {
    so.whh[i] = whhs[i];
    so.wreg[i] = pks[i];
    so.wlds[i] = pks[i] + 81920;
    so.wsc[i]  = (float*)(pks[i] + 131072);
  }
  so.logits = obj_logits; so.fmaps = obj_fmaps; so.boxes = boxes;
  so.bn_g = bn_g; so.bn_b = bn_b; so.bn_m = bn_m; so.bn_v = bn_v;
  so.pos_w = pos_w; so.pos_b = pos_b; so.embw = obj_embed_w;
  so.FE = FE; so.FEq = FEq; so.ascFE = ascFE; so.conf = conf;
  setup_kernel<<<dim3(so.pkEnd + 4096), dim3(256), 0, stream>>>(so);

  // ---- weight quant + sort ----
  quantw_sort_kernel<<<dim3(4128), dim3(256), 0, stream>>>(
      (const u16*)wih0T, wih0q, bsc0, (const u16*)ewih0T, ewih0q, bsc1, conf, perm);

  auto gemm = [&](const void* A, int lda, const void* B, int ldb, int K, int N,
                  float* oF, __hip_bfloat16* oB, int ldc, const float* bias) {
    int gy = (N + 127) / 128;
    gemm_kernel<<<dim3(32 * gy), dim3(256), 0, stream>>>(
        (const u16*)A, lda, (const u16*)B, ldb, K, N, gy, oF, oB, ldc, bias);
  };
  auto gemm_i8 = [&](const u8* A, int lda, const u8* B, int ldb, int K, int N,
                     const float* asc, const float* bsc,
                     __hip_bfloat16* oB, int ldc, const float* bias) {
    int gy = (N + 127) / 128;
    gemm_i8_kernel<<<dim3(32 * gy), dim3(256), 0, stream>>>(
        A, lda, B, ldb, K, N, gy, asc, bsc, oB, ldc, bias);
  };
  auto rec = [&](const __hip_bfloat16* P, const u32* wpk, int gat, int op,
                 __hip_bfloat16* ob, int old_, float* of, int fld, int foff) {
    rec_kernel<<<dim3(64), dim3(1024), 0, stream>>>(
        P, perm, wpk, (const uint4*)(wpk + 81920), (const float*)(wpk + 131072),
        gat, op, ob, old_, of, fld, foff);
  };

  // obj layer 0 (i8)
  gemm_i8(FEq, 2432, wih0q, 2432, 2432, 2048, ascFE, bsc0, Pbuf, 2048, obj_b0);
  rec(Pbuf, whh0pk, 1, 0, hseq, 512, nullptr, 0, 0);
  // obj layer 1 -> enc into FE cols [0,512)
  gemm(hseq, 512, wih1T, 512, 512, 2048, nullptr, Pbuf, 2048, obj_b1);
  rec(Pbuf, whh1pk, 0, 1, FE, FE_LD, nullptr, 0, 0);
  // decoder -> out cols [0,151)
  gemm(FE, FE_LD, decT, 2944, 2944, 151, out, nullptr, 663, dec_b);
  // fused argmax + edge build + quant
  argmax_edge_kernel<<<dim3(4096), dim3(256), 0, stream>>>(
      out, obj_embed2_w, obj_fmaps, FE, EDGEq, ascEDGE);
  // edge layer 0 (i8)
  gemm_i8(EDGEq, 2816, ewih0q, 2816, 2816, 2048, ascEDGE, bsc1, Pbuf, 2048, edge_b0);
  rec(Pbuf, ewhh0pk, 1, 0, hseq, 512, nullptr, 0, 0);
  // edge layer 1 -> out cols [151,663)
  gemm(hseq, 512, ewih1T, 512, 512, 2048, nullptr, Pbuf, 2048, edge_b1);
  rec(Pbuf, ewhh1pk, 0, 1, nullptr, 0, out, 663, 151);
}

// Round 17
// 821.664 us; speedup vs baseline: 1.3145x; 1.0009x over previous
//
#include <hip/hip_runtime.h>
#include <hip/hip_bf16.h>
#include <hip/hip_fp16.h>

typedef unsigned short u16;
typedef unsigned char u8;
typedef unsigned int u32;
typedef short s16x8 __attribute__((ext_vector_type(8)));
typedef float f32x4 __attribute__((ext_vector_type(4)));
typedef int i32x4 __attribute__((ext_vector_type(4)));

#define FE_LD 2944
#define EDGE_LD 2816

static __device__ __forceinline__ int sdot4(u32 a, u32 b, int acc) {
  return __builtin_amdgcn_sdot4((int)a, (int)b, acc, false);
}
static __device__ __forceinline__ float fsig(float x) {
  return __builtin_amdgcn_rcpf(1.f + __expf(-x));
}
static __device__ __forceinline__ float ftanh(float x) {
  return 1.f - 2.f * __builtin_amdgcn_rcpf(1.f + __expf(2.f * x));
}
static __device__ __forceinline__ u16 f2bf_raw(float f) {
  return __builtin_bit_cast(u16, __float2bfloat16(f));
}

#define GLD_LDS16(gsrc, ldst) \
  __builtin_amdgcn_global_load_lds((const __attribute__((address_space(1))) void*)(gsrc), \
                                   (__attribute__((address_space(3))) void*)(ldst), 16, 0, 0)

// XCD-aware swizzle: 1-D grid (nwg % 8 == 0).
static __device__ __forceinline__ void xcd_map(int gy, int* bx, int* by) {
  int lin = blockIdx.x;
  int q = gridDim.x >> 3;
  int wg = (lin & 7) * q + (lin >> 3);
  *bx = wg / gy; *by = wg % gy;
}

// ---------------------------------------------------------------------------
// bf16 MFMA GEMM (unchanged)
// ---------------------------------------------------------------------------
__global__ __launch_bounds__(256) void gemm_kernel(
    const u16* __restrict__ A, int lda,
    const u16* __restrict__ B, int ldb,
    int K, int N, int gy,
    float* __restrict__ outF, __hip_bfloat16* __restrict__ outB, int ldc,
    const float* __restrict__ bias)
{
  __shared__ __align__(16) u16 As[128*64];
  __shared__ __align__(16) u16 Bs[128*64];
  const int tid = threadIdx.x;
  const int w = tid >> 6, lane = tid & 63;
  const int wm = w >> 1, wn = w & 1;
  int bxi, byi; xcd_map(gy, &bxi, &byi);
  const long bm = (long)bxi * 128;
  const long bn = (long)byi * 128;
  f32x4 acc[4][4] = {};

  for (int k0 = 0; k0 < K; k0 += 64) {
    #pragma unroll
    for (int rr = 0; rr < 4; rr++) {
      int idx = rr * 256 + tid;
      int row = idx >> 3;
      int g   = idx & 7;
      int gs  = g ^ (row & 7);
      int ldst = (rr * 256 + (w << 6)) * 8;
      GLD_LDS16(A + (bm + row) * (long)lda + k0 + gs * 8, &As[ldst]);
      GLD_LDS16(B + (bn + row) * (long)ldb + k0 + gs * 8, &Bs[ldst]);
    }
    __syncthreads();
    #pragma unroll
    for (int kk = 0; kk < 2; kk++) {
      s16x8 af[4], bfr[4];
      #pragma unroll
      for (int i = 0; i < 4; i++) {
        int ra = wm * 64 + i * 16 + (lane & 15);
        int rb = wn * 64 + i * 16 + (lane & 15);
        int gg = kk * 4 + (lane >> 4);
        af[i]  = *(const s16x8*)&As[ra * 64 + ((gg ^ (ra & 7)) << 3)];
        bfr[i] = *(const s16x8*)&Bs[rb * 64 + ((gg ^ (rb & 7)) << 3)];
      }
      #pragma unroll
      for (int i = 0; i < 4; i++)
        #pragma unroll
        for (int j = 0; j < 4; j++)
          acc[i][j] = __builtin_amdgcn_mfma_f32_16x16x32_bf16(af[i], bfr[j], acc[i][j], 0, 0, 0);
    }
    __syncthreads();
  }

  #pragma unroll
  for (int i = 0; i < 4; i++)
    #pragma unroll
    for (int j = 0; j < 4; j++)
      #pragma unroll
      for (int v = 0; v < 4; v++) {
        long rr = bm + wm * 64 + i * 16 + (lane >> 4) * 4 + v;
        int  cc = (int)bn + wn * 64 + j * 16 + (lane & 15);
        if (cc < N) {
          float val = acc[i][j][v] + (bias ? bias[cc] : 0.f);
          if (outF) outF[rr * (long)ldc + cc] = val;
          else      outB[rr * (long)ldc + cc] = __float2bfloat16(val);
        }
      }
}

// ---------------------------------------------------------------------------
// i8 MFMA GEMM (unchanged)
// ---------------------------------------------------------------------------
__global__ __launch_bounds__(256) void gemm_i8_kernel(
    const u8* __restrict__ A, int lda,
    const u8* __restrict__ B, int ldb,
    int K, int N, int gy,
    const float* __restrict__ asc, const float* __restrict__ bsc,
    __hip_bfloat16* __restrict__ outB, int ldc,
    const float* __restrict__ bias)
{
  __shared__ __align__(16) u8 As[128*128];
  __shared__ __align__(16) u8 Bs[128*128];
  const int tid = threadIdx.x;
  const int w = tid >> 6, lane = tid & 63;
  const int wm = w >> 1, wn = w & 1;
  int bxi, byi; xcd_map(gy, &bxi, &byi);
  const long bm = (long)bxi * 128;
  const long bn = (long)byi * 128;
  i32x4 acc[4][4] = {};

  for (int k0 = 0; k0 < K; k0 += 128) {
    #pragma unroll
    for (int rr = 0; rr < 4; rr++) {
      int idx = rr * 256 + tid;
      int row = idx >> 3;
      int g   = idx & 7;
      int gs  = g ^ (row & 7);
      int ldst = (rr * 256 + (w << 6)) * 16;
      GLD_LDS16(A + (bm + row) * (long)lda + k0 + gs * 16, &As[ldst]);
      GLD_LDS16(B + (bn + row) * (long)ldb + k0 + gs * 16, &Bs[ldst]);
    }
    __syncthreads();
    #pragma unroll
    for (int kk = 0; kk < 2; kk++) {
      i32x4 af[4], bfr[4];
      #pragma unroll
      for (int i = 0; i < 4; i++) {
        int ra = wm * 64 + i * 16 + (lane & 15);
        int rb = wn * 64 + i * 16 + (lane & 15);
        int gg = kk * 4 + (lane >> 4);
        af[i]  = __builtin_bit_cast(i32x4, *(const uint4*)&As[ra * 128 + ((gg ^ (ra & 7)) << 4)]);
        bfr[i] = __builtin_bit_cast(i32x4, *(const uint4*)&Bs[rb * 128 + ((gg ^ (rb & 7)) << 4)]);
      }
      #pragma unroll
      for (int i = 0; i < 4; i++)
        #pragma unroll
        for (int j = 0; j < 4; j++)
          acc[i][j] = __builtin_amdgcn_mfma_i32_16x16x64_i8(af[i], bfr[j], acc[i][j], 0, 0, 0);
    }
    __syncthreads();
  }

  #pragma unroll
  for (int i = 0; i < 4; i++)
    #pragma unroll
    for (int j = 0; j < 4; j++)
      #pragma unroll
      for (int v = 0; v < 4; v++) {
        long rr = bm + wm * 64 + i * 16 + (lane >> 4) * 4 + v;
        int  cc = (int)bn + wn * 64 + j * 16 + (lane & 15);
        if (cc < N) {
          float val = (float)acc[i][j][v] * asc[rr] * bsc[cc] + (bias ? bias[cc] : 0.f);
          outB[rr * (long)ldc + cc] = __float2bfloat16(val);
        }
      }
}

// ---------------------------------------------------------------------------
// Setup mega-kernel: [64x64 transposes | whh packs | prep rows].
// ---------------------------------------------------------------------------
#define N_TROPS 9
struct SetupOps {
  const float* src[N_TROPS];
  __hip_bfloat16* dst[N_TROPS];
  int srcK[N_TROPS], srcN[N_TROPS], dstR[N_TROPS], dstC[N_TROPS];
  int split[N_TROPS], soff[N_TROPS];
  int tileBase[N_TROPS], tilesX[N_TROPS];
  int trEnd, pkEnd;
  const float* whh[4];
  u32* wreg[4]; u32* wlds[4]; float* wsc[4];
  const float* logits; const float* fmaps; const float* boxes;
  const float* bn_g; const float* bn_b; const float* bn_m; const float* bn_v;
  const float* pos_w; const float* pos_b; const float* embw;
  __hip_bfloat16* FE; u8* FEq; float* ascFE; float* conf;
};
__global__ __launch_bounds__(256) void setup_kernel(SetupOps ops)
{
  __shared__ __align__(16) float stage[2432];
  __shared__ float red[256];
  __shared__ float pf[151];
  const int bid = blockIdx.x, t = threadIdx.x;

  if (bid < ops.trEnd) {
    __shared__ float tile[64][65];
    int op = 0;
    #pragma unroll
    for (int i = 1; i < N_TROPS; i++) if (bid >= ops.tileBase[i]) op = i;
    const int local = bid - ops.tileBase[op];
    const int kt = (local % ops.tilesX[op]) * 64;
    const int nt = (local / ops.tilesX[op]) * 64;
    const float* src = ops.src[op];
    __hip_bfloat16* dst = ops.dst[op];
    const int srcK = ops.srcK[op], srcN = ops.srcN[op];
    const int dstR = ops.dstR[op], dstC = ops.dstC[op];
    const int split = ops.split[op], soff = ops.soff[op];
    const int tx = t & 63, ty = t >> 6;     // 64 cols x 4 row-groups
    #pragma unroll
    for (int i0 = 0; i0 < 16; i0++) {
      int i = i0 * 4 + ty;
      int k = kt + i;
      int srck = (k < split) ? (soff + k) : (k - split);
      int n = nt + tx;
      tile[i][tx] = (srck < srcK && n < srcN) ? src[(size_t)srck * srcN + n] : 0.f;
    }
    __syncthreads();
    #pragma unroll
    for (int i0 = 0; i0 < 16; i0++) {
      int i = i0 * 4 + ty;
      int n = nt + i, k = kt + tx;
      if (n < dstR && k < dstC)
        dst[(size_t)n * dstC + k] = __float2bfloat16(tile[tx][i]);
    }
    return;
  }

  if (bid < ops.pkEnd) {
    const int local = bid - ops.trEnd;
    const int set = local >> 3;
    const int idx = (local & 7) * 256 + t;
    const float* whh = ops.whh[set];
    u32* wreg = ops.wreg[set];
    u32* wlds = ops.wlds[set];
    float* wsc = ops.wsc[set];
    const int d = idx >> 10, col = idx & 1023;
    const int c4 = col >> 8, j = col & 255;
    const float* s = whh + (size_t)d * 256 * 1024 + col;
    float mx = 0.f;
    for (int k = 0; k < 256; k++) mx = fmaxf(mx, fabsf(s[(size_t)k * 1024]));
    float inv = (mx > 0.f) ? 127.f / mx : 0.f;
    wsc[d * 1024 + col] = (mx > 0.f) ? mx / (127.f * 127.f) : 0.f;
    const int rc = (c4 < 2) ? 12 : 8;
    const int rb = (c4 == 0) ? 0 : (c4 == 1) ? 12 : (c4 == 2) ? 24 : 32;
    for (int kg = 0; kg < 4; kg++) {
      const int slot = kg * 256 + j;
      for (int w = 0; w < 16; w++) {
        u32 v = 0;
        #pragma unroll
        for (int b = 0; b < 4; b++) {
          int q = __float2int_rn(s[(size_t)(kg * 64 + 4 * w + b) * 1024] * inv);
          q = max(-127, min(127, q));
          v |= ((u32)(q & 0xff)) << (8 * b);
        }
        if (w < rc) {
          wreg[(size_t)(d * 40 + rb + w) * 1024 + slot] = v;
        } else {
          int qq, comp;
          if (c4 == 0)      { qq = 0; comp = w - 12; }
          else if (c4 == 1) { qq = 1; comp = w - 12; }
          else if (c4 == 2) { qq = 2 + ((w - 8) >> 2); comp = (w - 8) & 3; }
          else              { qq = 4 + ((w - 8) >> 2); comp = (w - 8) & 3; }
          wlds[((size_t)(d * 6 + qq) * 1024 + slot) * 4 + comp] = v;
        }
      }
    }
    return;
  }

  // ---- prep rows ----
  const int row = bid - ops.pkEnd;
  float v = (t < 151) ? ops.logits[(size_t)row * 151 + t] : -3.0e38f;
  red[t] = v; __syncthreads();
  for (int s = 128; s > 0; s >>= 1) { if (t < s) red[t] = fmaxf(red[t], red[t + s]); __syncthreads(); }
  float mx = red[0]; __syncthreads();
  float p = (t < 151) ? expf(v - mx) : 0.f;
  red[t] = p; __syncthreads();
  for (int s = 128; s > 0; s >>= 1) { if (t < s) red[t] += red[t + s]; __syncthreads(); }
  float sum = red[0]; __syncthreads();
  p = p / sum;
  if (t < 151) pf[t] = p;
  red[t] = (t >= 1 && t < 151) ? p : 0.f; __syncthreads();
  for (int s = 128; s > 0; s >>= 1) { if (t < s) red[t] = fmaxf(red[t], red[t + s]); __syncthreads(); }
  if (t == 0) ops.conf[row] = red[0];
  __syncthreads();

  __hip_bfloat16* FE = ops.FE + (size_t)row * FE_LD;
  // fmaps (vectorized: float4 read, ushort4 bf16 write)
  {
    const float4* fm4 = (const float4*)(ops.fmaps + (size_t)row * 2048);
    for (int q4 = t; q4 < 512; q4 += 256) {
      float4 f = fm4[q4];
      *(float4*)&stage[q4 * 4] = f;
      ushort4 h;
      h.x = f2bf_raw(f.x); h.y = f2bf_raw(f.y); h.z = f2bf_raw(f.z); h.w = f2bf_raw(f.w);
      *(ushort4*)&FE[512 + q4 * 4] = h;
    }
  }
  // embed
  for (int c = t; c < 200; c += 256) {
    float e = 0.f;
    for (int k = 0; k < 151; k++) e += pf[k] * ops.embw[(size_t)k * 200 + c];
    stage[2048 + c] = e;
    FE[2560 + c] = __float2bfloat16(e);
  }
  // pos
  if (t < 128) {
    float x1 = ops.boxes[row * 4 + 0], y1 = ops.boxes[row * 4 + 1];
    float x2 = ops.boxes[row * 4 + 2], y2 = ops.boxes[row * 4 + 3];
    float cs[4] = { (x1 + x2) * 0.5f, (y1 + y2) * 0.5f, x2 - x1, y2 - y1 };
    float a = ops.pos_b[t];
    #pragma unroll
    for (int j = 0; j < 4; j++) {
      float cn = (cs[j] - ops.bn_m[j]) * rsqrtf(ops.bn_v[j] + 1e-5f) * ops.bn_g[j] + ops.bn_b[j];
      a += cn * ops.pos_w[j * 128 + t];
    }
    a = fmaxf(a, 0.f);
    stage[2248 + t] = a;
    FE[2760 + t] = __float2bfloat16(a);
  }
  if (t < 56) { stage[2376 + t] = 0.f; FE[2888 + t] = __float2bfloat16(0.f); }
  __syncthreads();

  float qm = 0.f;
  for (int c = t; c < 2432; c += 256) qm = fmaxf(qm, fabsf(stage[c]));
  red[t] = qm; __syncthreads();
  for (int s = 128; s > 0; s >>= 1) { if (t < s) red[t] = fmaxf(red[t], red[t + s]); __syncthreads(); }
  qm = red[0];
  float inv = (qm > 0.f) ? 127.f / qm : 0.f;
  if (t == 0) ops.ascFE[row] = (qm > 0.f) ? qm / 127.f : 0.f;
  u32* d32 = (u32*)(ops.FEq + (size_t)row * 2432);
  for (int wd = t; wd < 608; wd += 256) {
    u32 vv = 0;
    #pragma unroll
    for (int b = 0; b < 4; b++) {
      int q = __float2int_rn(stage[4 * wd + b] * inv);
      q = max(-127, min(127, q));
      vv |= ((u32)(q & 0xff)) << (8 * b);
    }
    d32[wd] = vv;
  }
}

// ---------------------------------------------------------------------------
// quant-weights (vectorized uint4 reads, uint2 writes) + per-image sort.
// ---------------------------------------------------------------------------
__global__ __launch_bounds__(256) void quantw_sort_kernel(
    const u16* __restrict__ w0, u8* __restrict__ w0q, float* __restrict__ bsc0,
    const u16* __restrict__ w1, u8* __restrict__ w1q, float* __restrict__ bsc1,
    const float* __restrict__ conf, int* __restrict__ perm)
{
  const int bid = blockIdx.x, t = threadIdx.x;
  if (bid < 4096) {
    __shared__ float red[256];
    const int row = (bid < 2048) ? bid : (bid - 2048);
    const u16* src = (bid < 2048) ? w0 : w1;
    u8* dst = (bid < 2048) ? w0q : w1q;
    float* sc = (bid < 2048) ? bsc0 : bsc1;
    const int K = (bid < 2048) ? 2432 : 2816;
    const uint4* s4 = (const uint4*)(src + (size_t)row * K);
    const int K8 = K >> 3;
    float mx = 0.f;
    for (int c8 = t; c8 < K8; c8 += 256) {
      uint4 v = s4[c8];
      #pragma unroll
      for (int wi = 0; wi < 4; wi++) {
        u32 w = (wi == 0) ? v.x : (wi == 1) ? v.y : (wi == 2) ? v.z : v.w;
        mx = fmaxf(mx, fabsf(__builtin_bit_cast(float, w << 16)));
        mx = fmaxf(mx, fabsf(__builtin_bit_cast(float, w & 0xffff0000u)));
      }
    }
    red[t] = mx; __syncthreads();
    for (int st = 128; st > 0; st >>= 1) { if (t < st) red[t] = fmaxf(red[t], red[t + st]); __syncthreads(); }
    mx = red[0];
    float inv = (mx > 0.f) ? 127.f / mx : 0.f;
    if (t == 0) sc[row] = (mx > 0.f) ? mx / 127.f : 0.f;
    uint2* d64 = (uint2*)(dst + (size_t)row * K);
    for (int c8 = t; c8 < K8; c8 += 256) {
      uint4 v = s4[c8];
      u32 out[2] = {0, 0};
      #pragma unroll
      for (int wi = 0; wi < 4; wi++) {
        u32 w = (wi == 0) ? v.x : (wi == 1) ? v.y : (wi == 2) ? v.z : v.w;
        float f0 = __builtin_bit_cast(float, w << 16);
        float f1 = __builtin_bit_cast(float, w & 0xffff0000u);
        int q0 = max(-127, min(127, __float2int_rn(f0 * inv)));
        int q1 = max(-127, min(127, __float2int_rn(f1 * inv)));
        out[wi >> 1] |= ((u32)(q0 & 0xff)) << (16 * (wi & 1));
        out[wi >> 1] |= ((u32)(q1 & 0xff)) << (16 * (wi & 1) + 8);
      }
      d64[c8] = uint2{out[0], out[1]};
    }
    return;
  }
  {
    __shared__ float key[128];
    __shared__ int   idx[128];
    const int b = bid - 4096;
    if (t < 128) { key[t] = conf[b * 128 + t]; idx[t] = t; }
    __syncthreads();
    for (int k = 2; k <= 128; k <<= 1)
      for (int j = k >> 1; j > 0; j >>= 1) {
        if (t < 128) {
          int ixj = t ^ j;
          if (ixj > t) {
            bool up = (t & k) == 0;
            float ka = key[t], kb = key[ixj];
            int ia = idx[t], ib = idx[ixj];
            bool before = (ka > kb) || (ka == kb && ia < ib);
            if (before != up) { key[t] = kb; key[ixj] = ka; idx[t] = ib; idx[ixj] = ia; }
          }
        }
        __syncthreads();
      }
    if (t < 128) perm[b * 128 + t] = b * 128 + idx[t];
  }
}

// ---------------------------------------------------------------------------
// LSTM scan (unchanged R12 structure).
// ---------------------------------------------------------------------------
__global__ __launch_bounds__(1024) void rec_kernel(
    const __hip_bfloat16* __restrict__ P,
    const int* __restrict__ perm,
    const u32* __restrict__ wreg_g,
    const uint4* __restrict__ wlds_g,
    const float* __restrict__ wsc_g,
    int gatherPerm, int outPerm,
    __hip_bfloat16* __restrict__ out_bf, int out_ld,
    float* __restrict__ out_f32, int f32_ld, int f32_off)
{
  __shared__ __align__(16) uint4 wt4[6 * 1024];
  __shared__ __align__(16) int4 part[256 * 5];
  __shared__ __align__(16) u32 hq[64];
  __shared__ int prow_lds[128];
  const int tid = threadIdx.x;
  const int kg = tid >> 8;
  const int img = blockIdx.x & 31, dir = blockIdx.x >> 5;

  u32 wv[40];
  {
    const u32* rp = wreg_g + (size_t)dir * 40960 + tid;
    #pragma unroll
    for (int i = 0; i < 40; i++) wv[i] = rp[(size_t)i * 1024];
  }
  #pragma unroll
  for (int i = 0; i < 40; i++) asm volatile("" : "+v"(wv[i]));
  {
    const uint4* lp = wlds_g + (size_t)dir * 6144 + tid;
    #pragma unroll
    for (int q = 0; q < 6; q++) wt4[q * 1024 + tid] = lp[(size_t)q * 1024];
  }
  if (tid < 128) prow_lds[tid] = perm[img * 128 + tid];
  if (tid < 64) hq[tid] = 0;

  float sc0 = 0.f, sc1 = 0.f, sc2 = 0.f, sc3 = 0.f, cst = 0.f;
  if (tid < 256) {
    const float* sp = wsc_g + dir * 1024 + tid;
    sc0 = sp[0]; sc1 = sp[256]; sc2 = sp[512]; sc3 = sp[768];
  }
  __syncthreads();

  const uint4* hq4 = (const uint4*)hq;

  int st = dir ? 127 : 0;
  float p0 = 0.f, p1 = 0.f, p2 = 0.f, p3 = 0.f;
  if (tid < 256) {
    int prow0 = gatherPerm ? prow_lds[st] : (img * 128 + st);
    const __hip_bfloat16* pp = P + (size_t)prow0 * 2048 + dir * 1024 + tid;
    p0 = __bfloat162float(pp[0]);   p1 = __bfloat162float(pp[256]);
    p2 = __bfloat162float(pp[512]); p3 = __bfloat162float(pp[768]);
  }

  for (int t = 0; t < 128; t++) {
    float n0 = 0.f, n1 = 0.f, n2 = 0.f, n3 = 0.f;
    if (tid < 256 && t < 127) {
      int stn = dir ? (126 - t) : (t + 1);
      int prn = gatherPerm ? prow_lds[stn] : (img * 128 + stn);
      const __hip_bfloat16* pp = P + (size_t)prn * 2048 + dir * 1024 + tid;
      n0 = __bfloat162float(pp[0]);   n1 = __bfloat162float(pp[256]);
      n2 = __bfloat162float(pp[512]); n3 = __bfloat162float(pp[768]);
    }

    int a0 = 0, a1 = 0, a2 = 0, a3 = 0;
    {
      uint4 hv = hq4[kg * 4 + 0];
      a0 = sdot4(hv.x, wv[0], a0);  a0 = sdot4(hv.y, wv[1], a0);
      a0 = sdot4(hv.z, wv[2], a0);  a0 = sdot4(hv.w, wv[3], a0);
      a1 = sdot4(hv.x, wv[12], a1); a1 = sdot4(hv.y, wv[13], a1);
      a1 = sdot4(hv.z, wv[14], a1); a1 = sdot4(hv.w, wv[15], a1);
      a2 = sdot4(hv.x, wv[24], a2); a2 = sdot4(hv.y, wv[25], a2);
      a2 = sdot4(hv.z, wv[26], a2); a2 = sdot4(hv.w, wv[27], a2);
      a3 = sdot4(hv.x, wv[32], a3); a3 = sdot4(hv.y, wv[33], a3);
      a3 = sdot4(hv.z, wv[34], a3); a3 = sdot4(hv.w, wv[35], a3);
    }
    {
      uint4 hv = hq4[kg * 4 + 1];
      a0 = sdot4(hv.x, wv[4], a0);  a0 = sdot4(hv.y, wv[5], a0);
      a0 = sdot4(hv.z, wv[6], a0);  a0 = sdot4(hv.w, wv[7], a0);
      a1 = sdot4(hv.x, wv[16], a1); a1 = sdot4(hv.y, wv[17], a1);
      a1 = sdot4(hv.z, wv[18], a1); a1 = sdot4(hv.w, wv[19], a1);
      a2 = sdot4(hv.x, wv[28], a2); a2 = sdot4(hv.y, wv[29], a2);
      a2 = sdot4(hv.z, wv[30], a2); a2 = sdot4(hv.w, wv[31], a2);
      a3 = sdot4(hv.x, wv[36], a3); a3 = sdot4(hv.y, wv[37], a3);
      a3 = sdot4(hv.z, wv[38], a3); a3 = sdot4(hv.w, wv[39], a3);
    }
    {
      uint4 hv = hq4[kg * 4 + 2];
      a0 = sdot4(hv.x, wv[8], a0);  a0 = sdot4(hv.y, wv[9], a0);
      a0 = sdot4(hv.z, wv[10], a0); a0 = sdot4(hv.w, wv[11], a0);
      a1 = sdot4(hv.x, wv[20], a1); a1 = sdot4(hv.y, wv[21], a1);
      a1 = sdot4(hv.z, wv[22], a1); a1 = sdot4(hv.w, wv[23], a1);
      uint4 wl = wt4[2 * 1024 + tid];
      a2 = sdot4(hv.x, wl.x, a2); a2 = sdot4(hv.y, wl.y, a2);
      a2 = sdot4(hv.z, wl.z, a2); a2 = sdot4(hv.w, wl.w, a2);
      wl = wt4[4 * 1024 + tid];
      a3 = sdot4(hv.x, wl.x, a3); a3 = sdot4(hv.y, wl.y, a3);
      a3 = sdot4(hv.z, wl.z, a3); a3 = sdot4(hv.w, wl.w, a3);
    }
    {
      uint4 hv = hq4[kg * 4 + 3];
      uint4 wl = wt4[0 * 1024 + tid];
      a0 = sdot4(hv.x, wl.x, a0); a0 = sdot4(hv.y, wl.y, a0);
      a0 = sdot4(hv.z, wl.z, a0); a0 = sdot4(hv.w, wl.w, a0);
      wl = wt4[1 * 1024 + tid];
      a1 = sdot4(hv.x, wl.x, a1); a1 = sdot4(hv.y, wl.y, a1);
      a1 = sdot4(hv.z, wl.z, a1); a1 = sdot4(hv.w, wl.w, a1);
      wl = wt4[3 * 1024 + tid];
      a2 = sdot4(hv.x, wl.x, a2); a2 = sdot4(hv.y, wl.y, a2);
      a2 = sdot4(hv.z, wl.z, a2); a2 = sdot4(hv.w, wl.w, a2);
      wl = wt4[5 * 1024 + tid];
      a3 = sdot4(hv.x, wl.x, a3); a3 = sdot4(hv.y, wl.y, a3);
      a3 = sdot4(hv.z, wl.z, a3); a3 = sdot4(hv.w, wl.w, a3);
    }

    part[(tid & 255) * 5 + kg] = int4{a0, a1, a2, a3};
    __syncthreads();

    if (tid < 256) {
      int4 q0 = part[tid * 5 + 0], q1 = part[tid * 5 + 1];
      int4 q2 = part[tid * 5 + 2], q3 = part[tid * 5 + 3];
      float gi = (float)(q0.x + q1.x + q2.x + q3.x) * sc0 + p0;
      float gf = (float)(q0.y + q1.y + q2.y + q3.y) * sc1 + p1;
      float gg = (float)(q0.z + q1.z + q2.z + q3.z) * sc2 + p2;
      float go = (float)(q0.w + q1.w + q2.w + q3.w) * sc3 + p3;
      float si = fsig(gi), sf = fsig(gf), so = fsig(go);
      cst = sf * cst + si * ftanh(gg);
      float h = so * ftanh(cst);
      int qi = __float2int_rn(h * 127.f);
      ((signed char*)hq)[tid] = (signed char)qi;
      const int orow = outPerm ? prow_lds[st] : (img * 128 + st);
      if (out_bf)  out_bf[(size_t)orow * out_ld + dir * 256 + tid] = __float2bfloat16(h);
      if (out_f32) out_f32[(size_t)orow * f32_ld + f32_off + dir * 256 + tid] = h;
    }
    __syncthreads();
    p0 = n0; p1 = n1; p2 = n2; p3 = n3;
    st = dir ? (st - 1) : (st + 1);
  }
}

// ---------------------------------------------------------------------------
// Fused argmax + edge-row build + i8 quant (vectorized loads).
// ---------------------------------------------------------------------------
__global__ __launch_bounds__(256) void argmax_edge_kernel(
    const float* __restrict__ dists,
    const float* __restrict__ embed2,
    const float* __restrict__ fmaps,
    const __hip_bfloat16* __restrict__ FE,
    u8* __restrict__ EDGEq, float* __restrict__ ascEDGE)
{
  __shared__ __align__(16) float stage[EDGE_LD];
  __shared__ float rv[256];
  __shared__ int   ri[256];
  const int row = blockIdx.x, t = threadIdx.x;

  float best = (t < 150) ? dists[(size_t)row * 663 + 1 + t] : -3.4e38f;
  int   bi   = (t < 150) ? (1 + t) : 1000;
  rv[t] = best; ri[t] = bi;
  __syncthreads();
  for (int s = 128; s > 0; s >>= 1) {
    if (t < s) {
      float ov = rv[t + s]; int oi = ri[t + s];
      if (ov > rv[t] || (ov == rv[t] && oi < ri[t])) { rv[t] = ov; ri[t] = oi; }
    }
    __syncthreads();
  }
  const int pr = ri[0];

  for (int c0 = t; c0 < 200; c0 += 256)
    stage[c0] = embed2[(size_t)pr * 200 + c0];
  if (t < 64) {
    const uint4* e4 = (const uint4*)(FE + (size_t)row * FE_LD);
    uint4 v = e4[t];
    #pragma unroll
    for (int wi = 0; wi < 4; wi++) {
      u32 w = (wi == 0) ? v.x : (wi == 1) ? v.y : (wi == 2) ? v.z : v.w;
      stage[200 + t * 8 + wi * 2]     = __builtin_bit_cast(float, w << 16);
      stage[200 + t * 8 + wi * 2 + 1] = __builtin_bit_cast(float, w & 0xffff0000u);
    }
  }
  {
    const float4* fm4 = (const float4*)(fmaps + (size_t)row * 2048);
    for (int c4 = t; c4 < 512; c4 += 256)
      *(float4*)&stage[712 + c4 * 4] = fm4[c4];
  }
  if (t < 56) stage[2760 + t] = 0.f;
  __syncthreads();

  float qm = 0.f;
  for (int c = t; c < EDGE_LD; c += 256) qm = fmaxf(qm, fabsf(stage[c]));
  rv[t] = qm; __syncthreads();
  for (int s = 128; s > 0; s >>= 1) { if (t < s) rv[t] = fmaxf(rv[t], rv[t + s]); __syncthreads(); }
  qm = rv[0];
  float inv = (qm > 0.f) ? 127.f / qm : 0.f;
  if (t == 0) ascEDGE[row] = (qm > 0.f) ? qm / 127.f : 0.f;
  uint2* d64 = (uint2*)(EDGEq + (size_t)row * EDGE_LD);
  for (int wd8 = t; wd8 < (EDGE_LD >> 3); wd8 += 256) {
    u32 out[2] = {0, 0};
    #pragma unroll
    for (int b = 0; b < 8; b++) {
      int q = __float2int_rn(stage[8 * wd8 + b] * inv);
      q = max(-127, min(127, q));
      out[b >> 2] |= ((u32)(q & 0xff)) << (8 * (b & 3));
    }
    d64[wd8] = uint2{out[0], out[1]};
  }
}

// ---------------------------------------------------------------------------
extern "C" void kernel_launch(void* const* d_in, const int* in_sizes, int n_in,
                              void* d_out, int out_size, void* d_ws, size_t ws_size,
                              hipStream_t stream)
{
  const float* obj_fmaps    = (const float*)d_in[0];
  const float* obj_logits   = (const float*)d_in[1];
  const float* boxes        = (const float*)d_in[2];
  const float* obj_embed_w  = (const float*)d_in[4];
  const float* obj_embed2_w = (const float*)d_in[5];
  const float* bn_g = (const float*)d_in[6];
  const float* bn_b = (const float*)d_in[7];
  const float* bn_m = (const float*)d_in[8];
  const float* bn_v = (const float*)d_in[9];
  const float* pos_w = (const float*)d_in[10];
  const float* pos_b = (const float*)d_in[11];
  const float* obj_wih0 = (const float*)d_in[12];
  const float* obj_whh0 = (const float*)d_in[13];
  const float* obj_b0   = (const float*)d_in[14];
  const float* obj_wih1 = (const float*)d_in[15];
  const float* obj_whh1 = (const float*)d_in[16];
  const float* obj_b1   = (const float*)d_in[17];
  const float* edge_wih0 = (const float*)d_in[18];
  const float* edge_whh0 = (const float*)d_in[19];
  const float* edge_b0   = (const float*)d_in[20];
  const float* edge_wih1 = (const float*)d_in[21];
  const float* edge_whh1 = (const float*)d_in[22];
  const float* edge_b1   = (const float*)d_in[23];
  const float* dec_w = (const float*)d_in[24];
  const float* dec_b = (const float*)d_in[25];
  float* out = (float*)d_out;

  char* ws = (char*)d_ws;
  auto alloc = [&](size_t bytes) -> char* {
    char* p = ws; ws += (bytes + 255) & ~(size_t)255; return p;
  };
  __hip_bfloat16* FE     = (__hip_bfloat16*)alloc(4096ull * FE_LD * 2);
  __hip_bfloat16* Pbuf   = (__hip_bfloat16*)alloc(4096ull * 2048 * 2);
  __hip_bfloat16* hseq   = (__hip_bfloat16*)alloc(4096ull * 512 * 2);
  __hip_bfloat16* wih0T  = (__hip_bfloat16*)alloc(2048ull * 2432 * 2);
  __hip_bfloat16* wih1T  = (__hip_bfloat16*)alloc(2048ull * 512 * 2);
  __hip_bfloat16* ewih0T = (__hip_bfloat16*)alloc(2048ull * 2816 * 2);
  __hip_bfloat16* ewih1T = (__hip_bfloat16*)alloc(2048ull * 512 * 2);
  __hip_bfloat16* decT   = (__hip_bfloat16*)alloc(256ull * 2944 * 2);
  u32* whh0pk  = (u32*)alloc(133120ull * 4);
  u32* whh1pk  = (u32*)alloc(133120ull * 4);
  u32* ewhh0pk = (u32*)alloc(133120ull * 4);
  u32* ewhh1pk = (u32*)alloc(133120ull * 4);
  u8*  FEq     = (u8*)alloc(4096ull * 2432);
  u8*  EDGEq   = (u8*)alloc(4096ull * 2816);
  u8*  wih0q   = (u8*)alloc(2048ull * 2432);
  u8*  ewih0q  = (u8*)alloc(2048ull * 2816);
  float* ascFE   = (float*)alloc(4096 * 4);
  float* ascEDGE = (float*)alloc(4096 * 4);
  float* bsc0    = (float*)alloc(2048 * 4);
  float* bsc1    = (float*)alloc(2048 * 4);
  int*   perm  = (int*)alloc(4096 * 4);
  float* conf  = (float*)alloc(4096 * 4);
  (void)in_sizes; (void)n_in; (void)out_size; (void)ws_size;

  // ---- setup mega-launch ----
  SetupOps so{};
  int nt = 0, base = 0;
  auto addTr = [&](const float* src, __hip_bfloat16* dst, int srcK, int srcN,
                   int dstR, int dstC, int split, int soff) {
    so.src[nt] = src; so.dst[nt] = dst;
    so.srcK[nt] = srcK; so.srcN[nt] = srcN; so.dstR[nt] = dstR; so.dstC[nt] = dstC;
    so.split[nt] = split; so.soff[nt] = soff;
    int tx = (dstC + 63) / 64, ty = (dstR + 63) / 64;
    so.tileBase[nt] = base; so.tilesX[nt] = tx;
    base += tx * ty; nt++;
  };
  for (int d = 0; d < 2; d++) {
    addTr(obj_wih0 + (size_t)d * 2376 * 1024, wih0T + (size_t)d * 1024 * 2432, 2376, 1024, 1024, 2432, 0, 0);
    addTr(obj_wih1 + (size_t)d * 512 * 1024,  wih1T + (size_t)d * 1024 * 512,  512, 1024, 1024, 512, 0, 0);
    addTr(edge_wih0 + (size_t)d * 2760 * 1024, ewih0T + (size_t)d * 1024 * 2816, 2760, 1024, 1024, 2816, 0, 0);
    addTr(edge_wih1 + (size_t)d * 512 * 1024,  ewih1T + (size_t)d * 1024 * 512,  512, 1024, 1024, 512, 0, 0);
  }
  addTr(dec_w, decT, 2888, 151, 256, 2944, 512, 2376);
  so.trEnd = base;
  so.pkEnd = base + 32;
  const float* whhs[4] = {obj_whh0, obj_whh1, edge_whh0, edge_whh1};
  u32* pks[4] = {whh0pk, whh1pk, ewhh0pk, ewhh1pk};
  for (int i = 0; i < 4; i++) {
    so.whh[i] = whhs[i];
    so.wreg[i] = pks[i];
    so.wlds[i] = pks[i] + 81920;
    so.wsc[i]  = (float*)(pks[i] + 131072);
  }
  so.logits = obj_logits; so.fmaps = obj_fmaps; so.boxes = boxes;
  so.bn_g = bn_g; so.bn_b = bn_b; so.bn_m = bn_m; so.bn_v = bn_v;
  so.pos_w = pos_w; so.pos_b = pos_b; so.embw = obj_embed_w;
  so.FE = FE; so.FEq = FEq; so.ascFE = ascFE; so.conf = conf;
  setup_kernel<<<dim3(so.pkEnd + 4096), dim3(256), 0, stream>>>(so);

  quantw_sort_kernel<<<dim3(4128), dim3(256), 0, stream>>>(
      (const u16*)wih0T, wih0q, bsc0, (const u16*)ewih0T, ewih0q, bsc1, conf, perm);

  auto gemm = [&](const void* A, int lda, const void* B, int ldb, int K, int N,
                  float* oF, __hip_bfloat16* oB, int ldc, const float* bias) {
    int gy = (N + 127) / 128;
    gemm_kernel<<<dim3(32 * gy), dim3(256), 0, stream>>>(
        (const u16*)A, lda, (const u16*)B, ldb, K, N, gy, oF, oB, ldc, bias);
  };
  auto gemm_i8 = [&](const u8* A, int lda, const u8* B, int ldb, int K, int N,
                     const float* asc, const float* bsc,
                     __hip_bfloat16* oB, int ldc, const float* bias) {
    int gy = (N + 127) / 128;
    gemm_i8_kernel<<<dim3(32 * gy), dim3(256), 0, stream>>>(
        A, lda, B, ldb, K, N, gy, asc, bsc, oB, ldc, bias);
  };
  auto rec = [&](const __hip_bfloat16* P, const u32* wpk, int gat, int op,
                 __hip_bfloat16* ob, int old_, float* of, int fld, int foff) {
    rec_kernel<<<dim3(64), dim3(1024), 0, stream>>>(
        P, perm, wpk, (const uint4*)(wpk + 81920), (const float*)(wpk + 131072),
        gat, op, ob, old_, of, fld, foff);
  };

  // obj layer 0 (i8)
  gemm_i8(FEq, 2432, wih0q, 2432, 2432, 2048, ascFE, bsc0, Pbuf, 2048, obj_b0);
  rec(Pbuf, whh0pk, 1, 0, hseq, 512, nullptr, 0, 0);
  // obj layer 1 -> enc into FE cols [0,512)
  gemm(hseq, 512, wih1T, 512, 512, 2048, nullptr, Pbuf, 2048, obj_b1);
  rec(Pbuf, whh1pk, 0, 1, FE, FE_LD, nullptr, 0, 0);
  // decoder -> out cols [0,151)
  gemm(FE, FE_LD, decT, 2944, 2944, 151, out, nullptr, 663, dec_b);
  // fused argmax + edge build + quant
  argmax_edge_kernel<<<dim3(4096), dim3(256), 0, stream>>>(
      out, obj_embed2_w, obj_fmaps, FE, EDGEq, ascEDGE);
  // edge layer 0 (i8)
  gemm_i8(EDGEq, 2816, ewih0q, 2816, 2816, 2048, ascEDGE, bsc1, Pbuf, 2048, edge_b0);
  rec(Pbuf, ewhh0pk, 1, 0, hseq, 512, nullptr, 0, 0);
  // edge layer 1 -> out cols [151,663)
  gemm(hseq, 512, ewih1T, 512, 512, 2048, nullptr, Pbuf, 2048, edge_b1);
  rec(Pbuf, ewhh1pk, 0, 1, nullptr, 0, out, 663, 151);
}

// Round 18
// 821.302 us; speedup vs baseline: 1.3151x; 1.0004x over previous
//
#include <hip/hip_runtime.h>
#include <hip/hip_bf16.h>
#include <hip/hip_fp16.h>

typedef unsigned short u16;
typedef unsigned char u8;
typedef unsigned int u32;
typedef short s16x8 __attribute__((ext_vector_type(8)));
typedef float f32x4 __attribute__((ext_vector_type(4)));
typedef int i32x4 __attribute__((ext_vector_type(4)));

#define FE_LD 2944
#define EDGE_LD 2816

static __device__ __forceinline__ int sdot4(u32 a, u32 b, int acc) {
  return __builtin_amdgcn_sdot4((int)a, (int)b, acc, false);
}
static __device__ __forceinline__ float fsig(float x) {
  return __builtin_amdgcn_rcpf(1.f + __expf(-x));
}
static __device__ __forceinline__ float ftanh(float x) {
  return 1.f - 2.f * __builtin_amdgcn_rcpf(1.f + __expf(2.f * x));
}
static __device__ __forceinline__ u16 f2bf_raw(float f) {
  return __builtin_bit_cast(u16, __float2bfloat16(f));
}

#define GLD_LDS16(gsrc, ldst) \
  __builtin_amdgcn_global_load_lds((const __attribute__((address_space(1))) void*)(gsrc), \
                                   (__attribute__((address_space(3))) void*)(ldst), 16, 0, 0)

// XCD-aware swizzle: 1-D grid (nwg % 8 == 0).
static __device__ __forceinline__ void xcd_map(int gy, int* bx, int* by) {
  int lin = blockIdx.x;
  int q = gridDim.x >> 3;
  int wg = (lin & 7) * q + (lin >> 3);
  *bx = wg / gy; *by = wg % gy;
}

// ---------------------------------------------------------------------------
// bf16 MFMA GEMM (unchanged)
// ---------------------------------------------------------------------------
__global__ __launch_bounds__(256) void gemm_kernel(
    const u16* __restrict__ A, int lda,
    const u16* __restrict__ B, int ldb,
    int K, int N, int gy,
    float* __restrict__ outF, __hip_bfloat16* __restrict__ outB, int ldc,
    const float* __restrict__ bias)
{
  __shared__ __align__(16) u16 As[128*64];
  __shared__ __align__(16) u16 Bs[128*64];
  const int tid = threadIdx.x;
  const int w = tid >> 6, lane = tid & 63;
  const int wm = w >> 1, wn = w & 1;
  int bxi, byi; xcd_map(gy, &bxi, &byi);
  const long bm = (long)bxi * 128;
  const long bn = (long)byi * 128;
  f32x4 acc[4][4] = {};

  for (int k0 = 0; k0 < K; k0 += 64) {
    #pragma unroll
    for (int rr = 0; rr < 4; rr++) {
      int idx = rr * 256 + tid;
      int row = idx >> 3;
      int g   = idx & 7;
      int gs  = g ^ (row & 7);
      int ldst = (rr * 256 + (w << 6)) * 8;
      GLD_LDS16(A + (bm + row) * (long)lda + k0 + gs * 8, &As[ldst]);
      GLD_LDS16(B + (bn + row) * (long)ldb + k0 + gs * 8, &Bs[ldst]);
    }
    __syncthreads();
    #pragma unroll
    for (int kk = 0; kk < 2; kk++) {
      s16x8 af[4], bfr[4];
      #pragma unroll
      for (int i = 0; i < 4; i++) {
        int ra = wm * 64 + i * 16 + (lane & 15);
        int rb = wn * 64 + i * 16 + (lane & 15);
        int gg = kk * 4 + (lane >> 4);
        af[i]  = *(const s16x8*)&As[ra * 64 + ((gg ^ (ra & 7)) << 3)];
        bfr[i] = *(const s16x8*)&Bs[rb * 64 + ((gg ^ (rb & 7)) << 3)];
      }
      #pragma unroll
      for (int i = 0; i < 4; i++)
        #pragma unroll
        for (int j = 0; j < 4; j++)
          acc[i][j] = __builtin_amdgcn_mfma_f32_16x16x32_bf16(af[i], bfr[j], acc[i][j], 0, 0, 0);
    }
    __syncthreads();
  }

  #pragma unroll
  for (int i = 0; i < 4; i++)
    #pragma unroll
    for (int j = 0; j < 4; j++)
      #pragma unroll
      for (int v = 0; v < 4; v++) {
        long rr = bm + wm * 64 + i * 16 + (lane >> 4) * 4 + v;
        int  cc = (int)bn + wn * 64 + j * 16 + (lane & 15);
        if (cc < N) {
          float val = acc[i][j][v] + (bias ? bias[cc] : 0.f);
          if (outF) outF[rr * (long)ldc + cc] = val;
          else      outB[rr * (long)ldc + cc] = __float2bfloat16(val);
        }
      }
}

// ---------------------------------------------------------------------------
// i8 MFMA GEMM (unchanged)
// ---------------------------------------------------------------------------
__global__ __launch_bounds__(256) void gemm_i8_kernel(
    const u8* __restrict__ A, int lda,
    const u8* __restrict__ B, int ldb,
    int K, int N, int gy,
    const float* __restrict__ asc, const float* __restrict__ bsc,
    __hip_bfloat16* __restrict__ outB, int ldc,
    const float* __restrict__ bias)
{
  __shared__ __align__(16) u8 As[128*128];
  __shared__ __align__(16) u8 Bs[128*128];
  const int tid = threadIdx.x;
  const int w = tid >> 6, lane = tid & 63;
  const int wm = w >> 1, wn = w & 1;
  int bxi, byi; xcd_map(gy, &bxi, &byi);
  const long bm = (long)bxi * 128;
  const long bn = (long)byi * 128;
  i32x4 acc[4][4] = {};

  for (int k0 = 0; k0 < K; k0 += 128) {
    #pragma unroll
    for (int rr = 0; rr < 4; rr++) {
      int idx = rr * 256 + tid;
      int row = idx >> 3;
      int g   = idx & 7;
      int gs  = g ^ (row & 7);
      int ldst = (rr * 256 + (w << 6)) * 16;
      GLD_LDS16(A + (bm + row) * (long)lda + k0 + gs * 16, &As[ldst]);
      GLD_LDS16(B + (bn + row) * (long)ldb + k0 + gs * 16, &Bs[ldst]);
    }
    __syncthreads();
    #pragma unroll
    for (int kk = 0; kk < 2; kk++) {
      i32x4 af[4], bfr[4];
      #pragma unroll
      for (int i = 0; i < 4; i++) {
        int ra = wm * 64 + i * 16 + (lane & 15);
        int rb = wn * 64 + i * 16 + (lane & 15);
        int gg = kk * 4 + (lane >> 4);
        af[i]  = __builtin_bit_cast(i32x4, *(const uint4*)&As[ra * 128 + ((gg ^ (ra & 7)) << 4)]);
        bfr[i] = __builtin_bit_cast(i32x4, *(const uint4*)&Bs[rb * 128 + ((gg ^ (rb & 7)) << 4)]);
      }
      #pragma unroll
      for (int i = 0; i < 4; i++)
        #pragma unroll
        for (int j = 0; j < 4; j++)
          acc[i][j] = __builtin_amdgcn_mfma_i32_16x16x64_i8(af[i], bfr[j], acc[i][j], 0, 0, 0);
    }
    __syncthreads();
  }

  #pragma unroll
  for (int i = 0; i < 4; i++)
    #pragma unroll
    for (int j = 0; j < 4; j++)
      #pragma unroll
      for (int v = 0; v < 4; v++) {
        long rr = bm + wm * 64 + i * 16 + (lane >> 4) * 4 + v;
        int  cc = (int)bn + wn * 64 + j * 16 + (lane & 15);
        if (cc < N) {
          float val = (float)acc[i][j][v] * asc[rr] * bsc[cc] + (bias ? bias[cc] : 0.f);
          outB[rr * (long)ldc + cc] = __float2bfloat16(val);
        }
      }
}

// ---------------------------------------------------------------------------
// Setup mega-kernel: [64x64 transposes | whh packs | prep rows].
// Transposes: ushort2 vectorized writes. Prep embed: coalesced float4 over
// the original [151][200] embw layout (50 threads x 4 cols, pipelined loads).
// ---------------------------------------------------------------------------
#define N_TROPS 9
struct SetupOps {
  const float* src[N_TROPS];
  __hip_bfloat16* dst[N_TROPS];
  int srcK[N_TROPS], srcN[N_TROPS], dstR[N_TROPS], dstC[N_TROPS];
  int split[N_TROPS], soff[N_TROPS];
  int tileBase[N_TROPS], tilesX[N_TROPS];
  int trEnd, pkEnd;
  const float* whh[4];
  u32* wreg[4]; u32* wlds[4]; float* wsc[4];
  const float* logits; const float* fmaps; const float* boxes;
  const float* bn_g; const float* bn_b; const float* bn_m; const float* bn_v;
  const float* pos_w; const float* pos_b; const float* embw;
  __hip_bfloat16* FE; u8* FEq; float* ascFE; float* conf;
};
__global__ __launch_bounds__(256) void setup_kernel(SetupOps ops)
{
  __shared__ __align__(16) float stage[2432];
  __shared__ float red[256];
  __shared__ float pf[151];
  const int bid = blockIdx.x, t = threadIdx.x;

  if (bid < ops.trEnd) {
    __shared__ float tile[64][65];
    int op = 0;
    #pragma unroll
    for (int i = 1; i < N_TROPS; i++) if (bid >= ops.tileBase[i]) op = i;
    const int local = bid - ops.tileBase[op];
    const int kt = (local % ops.tilesX[op]) * 64;
    const int nt = (local / ops.tilesX[op]) * 64;
    const float* src = ops.src[op];
    __hip_bfloat16* dst = ops.dst[op];
    const int srcK = ops.srcK[op], srcN = ops.srcN[op];
    const int dstR = ops.dstR[op], dstC = ops.dstC[op];
    const int split = ops.split[op], soff = ops.soff[op];
    {
      const int tx = t & 63, ty = t >> 6;   // 64 cols x 4 row-groups
      #pragma unroll
      for (int i0 = 0; i0 < 16; i0++) {
        int i = i0 * 4 + ty;
        int k = kt + i;
        int srck = (k < split) ? (soff + k) : (k - split);
        int n = nt + tx;
        tile[i][tx] = (srck < srcK && n < srcN) ? src[(size_t)srck * srcN + n] : 0.f;
      }
    }
    __syncthreads();
    {
      const int cx = t & 31, iy = t >> 5;   // 32 k-pairs x 8 row-groups
      #pragma unroll
      for (int i0 = 0; i0 < 8; i0++) {
        int i = i0 * 8 + iy;
        int n = nt + i, k = kt + 2 * cx;
        if (n < dstR && k < dstC) {
          ushort2 h;
          h.x = f2bf_raw(tile[2 * cx][i]);
          h.y = f2bf_raw(tile[2 * cx + 1][i]);
          *(ushort2*)&dst[(size_t)n * dstC + k] = h;
        }
      }
    }
    return;
  }

  if (bid < ops.pkEnd) {
    const int local = bid - ops.trEnd;
    const int set = local >> 3;
    const int idx = (local & 7) * 256 + t;
    const float* whh = ops.whh[set];
    u32* wreg = ops.wreg[set];
    u32* wlds = ops.wlds[set];
    float* wsc = ops.wsc[set];
    const int d = idx >> 10, col = idx & 1023;
    const int c4 = col >> 8, j = col & 255;
    const float* s = whh + (size_t)d * 256 * 1024 + col;
    float mx = 0.f;
    for (int k = 0; k < 256; k++) mx = fmaxf(mx, fabsf(s[(size_t)k * 1024]));
    float inv = (mx > 0.f) ? 127.f / mx : 0.f;
    wsc[d * 1024 + col] = (mx > 0.f) ? mx / (127.f * 127.f) : 0.f;
    const int rc = (c4 < 2) ? 12 : 8;
    const int rb = (c4 == 0) ? 0 : (c4 == 1) ? 12 : (c4 == 2) ? 24 : 32;
    for (int kg = 0; kg < 4; kg++) {
      const int slot = kg * 256 + j;
      for (int w = 0; w < 16; w++) {
        u32 v = 0;
        #pragma unroll
        for (int b = 0; b < 4; b++) {
          int q = __float2int_rn(s[(size_t)(kg * 64 + 4 * w + b) * 1024] * inv);
          q = max(-127, min(127, q));
          v |= ((u32)(q & 0xff)) << (8 * b);
        }
        if (w < rc) {
          wreg[(size_t)(d * 40 + rb + w) * 1024 + slot] = v;
        } else {
          int qq, comp;
          if (c4 == 0)      { qq = 0; comp = w - 12; }
          else if (c4 == 1) { qq = 1; comp = w - 12; }
          else if (c4 == 2) { qq = 2 + ((w - 8) >> 2); comp = (w - 8) & 3; }
          else              { qq = 4 + ((w - 8) >> 2); comp = (w - 8) & 3; }
          wlds[((size_t)(d * 6 + qq) * 1024 + slot) * 4 + comp] = v;
        }
      }
    }
    return;
  }

  // ---- prep rows ----
  const int row = bid - ops.pkEnd;
  float v = (t < 151) ? ops.logits[(size_t)row * 151 + t] : -3.0e38f;
  red[t] = v; __syncthreads();
  for (int s = 128; s > 0; s >>= 1) { if (t < s) red[t] = fmaxf(red[t], red[t + s]); __syncthreads(); }
  float mx = red[0]; __syncthreads();
  float p = (t < 151) ? expf(v - mx) : 0.f;
  red[t] = p; __syncthreads();
  for (int s = 128; s > 0; s >>= 1) { if (t < s) red[t] += red[t + s]; __syncthreads(); }
  float sum = red[0]; __syncthreads();
  p = p / sum;
  if (t < 151) pf[t] = p;
  red[t] = (t >= 1 && t < 151) ? p : 0.f; __syncthreads();
  for (int s = 128; s > 0; s >>= 1) { if (t < s) red[t] = fmaxf(red[t], red[t + s]); __syncthreads(); }
  if (t == 0) ops.conf[row] = red[0];
  __syncthreads();

  __hip_bfloat16* FE = ops.FE + (size_t)row * FE_LD;
  // fmaps (float4 read, ushort4 bf16 write)
  {
    const float4* fm4 = (const float4*)(ops.fmaps + (size_t)row * 2048);
    for (int q4 = t; q4 < 512; q4 += 256) {
      float4 f = fm4[q4];
      *(float4*)&stage[q4 * 4] = f;
      ushort4 h;
      h.x = f2bf_raw(f.x); h.y = f2bf_raw(f.y); h.z = f2bf_raw(f.z); h.w = f2bf_raw(f.w);
      *(ushort4*)&FE[512 + q4 * 4] = h;
    }
  }
  // embed: 50 threads x 4 cols, coalesced float4 per k (800B row = 50 lanes)
  if (t < 50) {
    const float4* ew4 = (const float4*)(ops.embw);   // [151][50 float4]
    float4 e = {0.f, 0.f, 0.f, 0.f};
    for (int k = 0; k < 151; k++) {
      float4 w = ew4[k * 50 + t];
      float pk = pf[k];
      e.x += pk * w.x; e.y += pk * w.y; e.z += pk * w.z; e.w += pk * w.w;
    }
    *(float4*)&stage[2048 + 4 * t] = e;
    ushort4 h;
    h.x = f2bf_raw(e.x); h.y = f2bf_raw(e.y); h.z = f2bf_raw(e.z); h.w = f2bf_raw(e.w);
    *(ushort4*)&FE[2560 + 4 * t] = h;
  }
  // pos
  if (t < 128) {
    float x1 = ops.boxes[row * 4 + 0], y1 = ops.boxes[row * 4 + 1];
    float x2 = ops.boxes[row * 4 + 2], y2 = ops.boxes[row * 4 + 3];
    float cs[4] = { (x1 + x2) * 0.5f, (y1 + y2) * 0.5f, x2 - x1, y2 - y1 };
    float a = ops.pos_b[t];
    #pragma unroll
    for (int j = 0; j < 4; j++) {
      float cn = (cs[j] - ops.bn_m[j]) * rsqrtf(ops.bn_v[j] + 1e-5f) * ops.bn_g[j] + ops.bn_b[j];
      a += cn * ops.pos_w[j * 128 + t];
    }
    a = fmaxf(a, 0.f);
    stage[2248 + t] = a;
    FE[2760 + t] = __float2bfloat16(a);
  }
  if (t < 56) { stage[2376 + t] = 0.f; FE[2888 + t] = __float2bfloat16(0.f); }
  __syncthreads();

  float qm = 0.f;
  for (int c = t; c < 2432; c += 256) qm = fmaxf(qm, fabsf(stage[c]));
  red[t] = qm; __syncthreads();
  for (int s = 128; s > 0; s >>= 1) { if (t < s) red[t] = fmaxf(red[t], red[t + s]); __syncthreads(); }
  qm = red[0];
  float inv = (qm > 0.f) ? 127.f / qm : 0.f;
  if (t == 0) ops.ascFE[row] = (qm > 0.f) ? qm / 127.f : 0.f;
  u32* d32 = (u32*)(ops.FEq + (size_t)row * 2432);
  for (int wd = t; wd < 608; wd += 256) {
    u32 vv = 0;
    #pragma unroll
    for (int b = 0; b < 4; b++) {
      int q = __float2int_rn(stage[4 * wd + b] * inv);
      q = max(-127, min(127, q));
      vv |= ((u32)(q & 0xff)) << (8 * b);
    }
    d32[wd] = vv;
  }
}

// ---------------------------------------------------------------------------
// quant-weights (vectorized uint4 reads, uint2 writes) + per-image sort.
// ---------------------------------------------------------------------------
__global__ __launch_bounds__(256) void quantw_sort_kernel(
    const u16* __restrict__ w0, u8* __restrict__ w0q, float* __restrict__ bsc0,
    const u16* __restrict__ w1, u8* __restrict__ w1q, float* __restrict__ bsc1,
    const float* __restrict__ conf, int* __restrict__ perm)
{
  const int bid = blockIdx.x, t = threadIdx.x;
  if (bid < 4096) {
    __shared__ float red[256];
    const int row = (bid < 2048) ? bid : (bid - 2048);
    const u16* src = (bid < 2048) ? w0 : w1;
    u8* dst = (bid < 2048) ? w0q : w1q;
    float* sc = (bid < 2048) ? bsc0 : bsc1;
    const int K = (bid < 2048) ? 2432 : 2816;
    const uint4* s4 = (const uint4*)(src + (size_t)row * K);
    const int K8 = K >> 3;
    float mx = 0.f;
    for (int c8 = t; c8 < K8; c8 += 256) {
      uint4 v = s4[c8];
      #pragma unroll
      for (int wi = 0; wi < 4; wi++) {
        u32 w = (wi == 0) ? v.x : (wi == 1) ? v.y : (wi == 2) ? v.z : v.w;
        mx = fmaxf(mx, fabsf(__builtin_bit_cast(float, w << 16)));
        mx = fmaxf(mx, fabsf(__builtin_bit_cast(float, w & 0xffff0000u)));
      }
    }
    red[t] = mx; __syncthreads();
    for (int st = 128; st > 0; st >>= 1) { if (t < st) red[t] = fmaxf(red[t], red[t + st]); __syncthreads(); }
    mx = red[0];
    float inv = (mx > 0.f) ? 127.f / mx : 0.f;
    if (t == 0) sc[row] = (mx > 0.f) ? mx / 127.f : 0.f;
    uint2* d64 = (uint2*)(dst + (size_t)row * K);
    for (int c8 = t; c8 < K8; c8 += 256) {
      uint4 v = s4[c8];
      u32 out[2] = {0, 0};
      #pragma unroll
      for (int wi = 0; wi < 4; wi++) {
        u32 w = (wi == 0) ? v.x : (wi == 1) ? v.y : (wi == 2) ? v.z : v.w;
        float f0 = __builtin_bit_cast(float, w << 16);
        float f1 = __builtin_bit_cast(float, w & 0xffff0000u);
        int q0 = max(-127, min(127, __float2int_rn(f0 * inv)));
        int q1 = max(-127, min(127, __float2int_rn(f1 * inv)));
        out[wi >> 1] |= ((u32)(q0 & 0xff)) << (16 * (wi & 1));
        out[wi >> 1] |= ((u32)(q1 & 0xff)) << (16 * (wi & 1) + 8);
      }
      d64[c8] = uint2{out[0], out[1]};
    }
    return;
  }
  {
    __shared__ float key[128];
    __shared__ int   idx[128];
    const int b = bid - 4096;
    if (t < 128) { key[t] = conf[b * 128 + t]; idx[t] = t; }
    __syncthreads();
    for (int k = 2; k <= 128; k <<= 1)
      for (int j = k >> 1; j > 0; j >>= 1) {
        if (t < 128) {
          int ixj = t ^ j;
          if (ixj > t) {
            bool up = (t & k) == 0;
            float ka = key[t], kb = key[ixj];
            int ia = idx[t], ib = idx[ixj];
            bool before = (ka > kb) || (ka == kb && ia < ib);
            if (before != up) { key[t] = kb; key[ixj] = ka; idx[t] = ib; idx[ixj] = ia; }
          }
        }
        __syncthreads();
      }
    if (t < 128) perm[b * 128 + t] = b * 128 + idx[t];
  }
}

// ---------------------------------------------------------------------------
// LSTM scan (unchanged R12 structure).
// ---------------------------------------------------------------------------
__global__ __launch_bounds__(1024) void rec_kernel(
    const __hip_bfloat16* __restrict__ P,
    const int* __restrict__ perm,
    const u32* __restrict__ wreg_g,
    const uint4* __restrict__ wlds_g,
    const float* __restrict__ wsc_g,
    int gatherPerm, int outPerm,
    __hip_bfloat16* __restrict__ out_bf, int out_ld,
    float* __restrict__ out_f32, int f32_ld, int f32_off)
{
  __shared__ __align__(16) uint4 wt4[6 * 1024];
  __shared__ __align__(16) int4 part[256 * 5];
  __shared__ __align__(16) u32 hq[64];
  __shared__ int prow_lds[128];
  const int tid = threadIdx.x;
  const int kg = tid >> 8;
  const int img = blockIdx.x & 31, dir = blockIdx.x >> 5;

  u32 wv[40];
  {
    const u32* rp = wreg_g + (size_t)dir * 40960 + tid;
    #pragma unroll
    for (int i = 0; i < 40; i++) wv[i] = rp[(size_t)i * 1024];
  }
  #pragma unroll
  for (int i = 0; i < 40; i++) asm volatile("" : "+v"(wv[i]));
  {
    const uint4* lp = wlds_g + (size_t)dir * 6144 + tid;
    #pragma unroll
    for (int q = 0; q < 6; q++) wt4[q * 1024 + tid] = lp[(size_t)q * 1024];
  }
  if (tid < 128) prow_lds[tid] = perm[img * 128 + tid];
  if (tid < 64) hq[tid] = 0;

  float sc0 = 0.f, sc1 = 0.f, sc2 = 0.f, sc3 = 0.f, cst = 0.f;
  if (tid < 256) {
    const float* sp = wsc_g + dir * 1024 + tid;
    sc0 = sp[0]; sc1 = sp[256]; sc2 = sp[512]; sc3 = sp[768];
  }
  __syncthreads();

  const uint4* hq4 = (const uint4*)hq;

  int st = dir ? 127 : 0;
  float p0 = 0.f, p1 = 0.f, p2 = 0.f, p3 = 0.f;
  if (tid < 256) {
    int prow0 = gatherPerm ? prow_lds[st] : (img * 128 + st);
    const __hip_bfloat16* pp = P + (size_t)prow0 * 2048 + dir * 1024 + tid;
    p0 = __bfloat162float(pp[0]);   p1 = __bfloat162float(pp[256]);
    p2 = __bfloat162float(pp[512]); p3 = __bfloat162float(pp[768]);
  }

  for (int t = 0; t < 128; t++) {
    float n0 = 0.f, n1 = 0.f, n2 = 0.f, n3 = 0.f;
    if (tid < 256 && t < 127) {
      int stn = dir ? (126 - t) : (t + 1);
      int prn = gatherPerm ? prow_lds[stn] : (img * 128 + stn);
      const __hip_bfloat16* pp = P + (size_t)prn * 2048 + dir * 1024 + tid;
      n0 = __bfloat162float(pp[0]);   n1 = __bfloat162float(pp[256]);
      n2 = __bfloat162float(pp[512]); n3 = __bfloat162float(pp[768]);
    }

    int a0 = 0, a1 = 0, a2 = 0, a3 = 0;
    {
      uint4 hv = hq4[kg * 4 + 0];
      a0 = sdot4(hv.x, wv[0], a0);  a0 = sdot4(hv.y, wv[1], a0);
      a0 = sdot4(hv.z, wv[2], a0);  a0 = sdot4(hv.w, wv[3], a0);
      a1 = sdot4(hv.x, wv[12], a1); a1 = sdot4(hv.y, wv[13], a1);
      a1 = sdot4(hv.z, wv[14], a1); a1 = sdot4(hv.w, wv[15], a1);
      a2 = sdot4(hv.x, wv[24], a2); a2 = sdot4(hv.y, wv[25], a2);
      a2 = sdot4(hv.z, wv[26], a2); a2 = sdot4(hv.w, wv[27], a2);
      a3 = sdot4(hv.x, wv[32], a3); a3 = sdot4(hv.y, wv[33], a3);
      a3 = sdot4(hv.z, wv[34], a3); a3 = sdot4(hv.w, wv[35], a3);
    }
    {
      uint4 hv = hq4[kg * 4 + 1];
      a0 = sdot4(hv.x, wv[4], a0);  a0 = sdot4(hv.y, wv[5], a0);
      a0 = sdot4(hv.z, wv[6], a0);  a0 = sdot4(hv.w, wv[7], a0);
      a1 = sdot4(hv.x, wv[16], a1); a1 = sdot4(hv.y, wv[17], a1);
      a1 = sdot4(hv.z, wv[18], a1); a1 = sdot4(hv.w, wv[19], a1);
      a2 = sdot4(hv.x, wv[28], a2); a2 = sdot4(hv.y, wv[29], a2);
      a2 = sdot4(hv.z, wv[30], a2); a2 = sdot4(hv.w, wv[31], a2);
      a3 = sdot4(hv.x, wv[36], a3); a3 = sdot4(hv.y, wv[37], a3);
      a3 = sdot4(hv.z, wv[38], a3); a3 = sdot4(hv.w, wv[39], a3);
    }
    {
      uint4 hv = hq4[kg * 4 + 2];
      a0 = sdot4(hv.x, wv[8], a0);  a0 = sdot4(hv.y, wv[9], a0);
      a0 = sdot4(hv.z, wv[10], a0); a0 = sdot4(hv.w, wv[11], a0);
      a1 = sdot4(hv.x, wv[20], a1); a1 = sdot4(hv.y, wv[21], a1);
      a1 = sdot4(hv.z, wv[22], a1); a1 = sdot4(hv.w, wv[23], a1);
      uint4 wl = wt4[2 * 1024 + tid];
      a2 = sdot4(hv.x, wl.x, a2); a2 = sdot4(hv.y, wl.y, a2);
      a2 = sdot4(hv.z, wl.z, a2); a2 = sdot4(hv.w, wl.w, a2);
      wl = wt4[4 * 1024 + tid];
      a3 = sdot4(hv.x, wl.x, a3); a3 = sdot4(hv.y, wl.y, a3);
      a3 = sdot4(hv.z, wl.z, a3); a3 = sdot4(hv.w, wl.w, a3);
    }
    {
      uint4 hv = hq4[kg * 4 + 3];
      uint4 wl = wt4[0 * 1024 + tid];
      a0 = sdot4(hv.x, wl.x, a0); a0 = sdot4(hv.y, wl.y, a0);
      a0 = sdot4(hv.z, wl.z, a0); a0 = sdot4(hv.w, wl.w, a0);
      wl = wt4[1 * 1024 + tid];
      a1 = sdot4(hv.x, wl.x, a1); a1 = sdot4(hv.y, wl.y, a1);
      a1 = sdot4(hv.z, wl.z, a1); a1 = sdot4(hv.w, wl.w, a1);
      wl = wt4[3 * 1024 + tid];
      a2 = sdot4(hv.x, wl.x, a2); a2 = sdot4(hv.y, wl.y, a2);
      a2 = sdot4(hv.z, wl.z, a2); a2 = sdot4(hv.w, wl.w, a2);
      wl = wt4[5 * 1024 + tid];
      a3 = sdot4(hv.x, wl.x, a3); a3 = sdot4(hv.y, wl.y, a3);
      a3 = sdot4(hv.z, wl.z, a3); a3 = sdot4(hv.w, wl.w, a3);
    }

    part[(tid & 255) * 5 + kg] = int4{a0, a1, a2, a3};
    __syncthreads();

    if (tid < 256) {
      int4 q0 = part[tid * 5 + 0], q1 = part[tid * 5 + 1];
      int4 q2 = part[tid * 5 + 2], q3 = part[tid * 5 + 3];
      float gi = (float)(q0.x + q1.x + q2.x + q3.x) * sc0 + p0;
      float gf = (float)(q0.y + q1.y + q2.y + q3.y) * sc1 + p1;
      float gg = (float)(q0.z + q1.z + q2.z + q3.z) * sc2 + p2;
      float go = (float)(q0.w + q1.w + q2.w + q3.w) * sc3 + p3;
      float si = fsig(gi), sf = fsig(gf), so = fsig(go);
      cst = sf * cst + si * ftanh(gg);
      float h = so * ftanh(cst);
      int qi = __float2int_rn(h * 127.f);
      ((signed char*)hq)[tid] = (signed char)qi;
      const int orow = outPerm ? prow_lds[st] : (img * 128 + st);
      if (out_bf)  out_bf[(size_t)orow * out_ld + dir * 256 + tid] = __float2bfloat16(h);
      if (out_f32) out_f32[(size_t)orow * f32_ld + f32_off + dir * 256 + tid] = h;
    }
    __syncthreads();
    p0 = n0; p1 = n1; p2 = n2; p3 = n3;
    st = dir ? (st - 1) : (st + 1);
  }
}

// ---------------------------------------------------------------------------
// Fused argmax + edge-row build + i8 quant (vectorized loads).
// ---------------------------------------------------------------------------
__global__ __launch_bounds__(256) void argmax_edge_kernel(
    const float* __restrict__ dists,
    const float* __restrict__ embed2,
    const float* __restrict__ fmaps,
    const __hip_bfloat16* __restrict__ FE,
    u8* __restrict__ EDGEq, float* __restrict__ ascEDGE)
{
  __shared__ __align__(16) float stage[EDGE_LD];
  __shared__ float rv[256];
  __shared__ int   ri[256];
  const int row = blockIdx.x, t = threadIdx.x;

  float best = (t < 150) ? dists[(size_t)row * 663 + 1 + t] : -3.4e38f;
  int   bi   = (t < 150) ? (1 + t) : 1000;
  rv[t] = best; ri[t] = bi;
  __syncthreads();
  for (int s = 128; s > 0; s >>= 1) {
    if (t < s) {
      float ov = rv[t + s]; int oi = ri[t + s];
      if (ov > rv[t] || (ov == rv[t] && oi < ri[t])) { rv[t] = ov; ri[t] = oi; }
    }
    __syncthreads();
  }
  const int pr = ri[0];

  for (int c0 = t; c0 < 200; c0 += 256)
    stage[c0] = embed2[(size_t)pr * 200 + c0];
  if (t < 64) {
    const uint4* e4 = (const uint4*)(FE + (size_t)row * FE_LD);
    uint4 v = e4[t];
    #pragma unroll
    for (int wi = 0; wi < 4; wi++) {
      u32 w = (wi == 0) ? v.x : (wi == 1) ? v.y : (wi == 2) ? v.z : v.w;
      stage[200 + t * 8 + wi * 2]     = __builtin_bit_cast(float, w << 16);
      stage[200 + t * 8 + wi * 2 + 1] = __builtin_bit_cast(float, w & 0xffff0000u);
    }
  }
  {
    const float4* fm4 = (const float4*)(fmaps + (size_t)row * 2048);
    for (int c4 = t; c4 < 512; c4 += 256)
      *(float4*)&stage[712 + c4 * 4] = fm4[c4];
  }
  if (t < 56) stage[2760 + t] = 0.f;
  __syncthreads();

  float qm = 0.f;
  for (int c = t; c < EDGE_LD; c += 256) qm = fmaxf(qm, fabsf(stage[c]));
  rv[t] = qm; __syncthreads();
  for (int s = 128; s > 0; s >>= 1) { if (t < s) rv[t] = fmaxf(rv[t], rv[t + s]); __syncthreads(); }
  qm = rv[0];
  float inv = (qm > 0.f) ? 127.f / qm : 0.f;
  if (t == 0) ascEDGE[row] = (qm > 0.f) ? qm / 127.f : 0.f;
  uint2* d64 = (uint2*)(EDGEq + (size_t)row * EDGE_LD);
  for (int wd8 = t; wd8 < (EDGE_LD >> 3); wd8 += 256) {
    u32 out[2] = {0, 0};
    #pragma unroll
    for (int b = 0; b < 8; b++) {
      int q = __float2int_rn(stage[8 * wd8 + b] * inv);
      q = max(-127, min(127, q));
      out[b >> 2] |= ((u32)(q & 0xff)) << (8 * (b & 3));
    }
    d64[wd8] = uint2{out[0], out[1]};
  }
}

// ---------------------------------------------------------------------------
extern "C" void kernel_launch(void* const* d_in, const int* in_sizes, int n_in,
                              void* d_out, int out_size, void* d_ws, size_t ws_size,
                              hipStream_t stream)
{
  const float* obj_fmaps    = (const float*)d_in[0];
  const float* obj_logits   = (const float*)d_in[1];
  const float* boxes        = (const float*)d_in[2];
  const float* obj_embed_w  = (const float*)d_in[4];
  const float* obj_embed2_w = (const float*)d_in[5];
  const float* bn_g = (const float*)d_in[6];
  const float* bn_b = (const float*)d_in[7];
  const float* bn_m = (const float*)d_in[8];
  const float* bn_v = (const float*)d_in[9];
  const float* pos_w = (const float*)d_in[10];
  const float* pos_b = (const float*)d_in[11];
  const float* obj_wih0 = (const float*)d_in[12];
  const float* obj_whh0 = (const float*)d_in[13];
  const float* obj_b0   = (const float*)d_in[14];
  const float* obj_wih1 = (const float*)d_in[15];
  const float* obj_whh1 = (const float*)d_in[16];
  const float* obj_b1   = (const float*)d_in[17];
  const float* edge_wih0 = (const float*)d_in[18];
  const float* edge_whh0 = (const float*)d_in[19];
  const float* edge_b0   = (const float*)d_in[20];
  const float* edge_wih1 = (const float*)d_in[21];
  const float* edge_whh1 = (const float*)d_in[22];
  const float* edge_b1   = (const float*)d_in[23];
  const float* dec_w = (const float*)d_in[24];
  const float* dec_b = (const float*)d_in[25];
  float* out = (float*)d_out;

  char* ws = (char*)d_ws;
  auto alloc = [&](size_t bytes) -> char* {
    char* p = ws; ws += (bytes + 255) & ~(size_t)255; return p;
  };
  __hip_bfloat16* FE     = (__hip_bfloat16*)alloc(4096ull * FE_LD * 2);
  __hip_bfloat16* Pbuf   = (__hip_bfloat16*)alloc(4096ull * 2048 * 2);
  __hip_bfloat16* hseq   = (__hip_bfloat16*)alloc(4096ull * 512 * 2);
  __hip_bfloat16* wih0T  = (__hip_bfloat16*)alloc(2048ull * 2432 * 2);
  __hip_bfloat16* wih1T  = (__hip_bfloat16*)alloc(2048ull * 512 * 2);
  __hip_bfloat16* ewih0T = (__hip_bfloat16*)alloc(2048ull * 2816 * 2);
  __hip_bfloat16* ewih1T = (__hip_bfloat16*)alloc(2048ull * 512 * 2);
  __hip_bfloat16* decT   = (__hip_bfloat16*)alloc(256ull * 2944 * 2);
  u32* whh0pk  = (u32*)alloc(133120ull * 4);
  u32* whh1pk  = (u32*)alloc(133120ull * 4);
  u32* ewhh0pk = (u32*)alloc(133120ull * 4);
  u32* ewhh1pk = (u32*)alloc(133120ull * 4);
  u8*  FEq     = (u8*)alloc(4096ull * 2432);
  u8*  EDGEq   = (u8*)alloc(4096ull * 2816);
  u8*  wih0q   = (u8*)alloc(2048ull * 2432);
  u8*  ewih0q  = (u8*)alloc(2048ull * 2816);
  float* ascFE   = (float*)alloc(4096 * 4);
  float* ascEDGE = (float*)alloc(4096 * 4);
  float* bsc0    = (float*)alloc(2048 * 4);
  float* bsc1    = (float*)alloc(2048 * 4);
  int*   perm  = (int*)alloc(4096 * 4);
  float* conf  = (float*)alloc(4096 * 4);
  (void)in_sizes; (void)n_in; (void)out_size; (void)ws_size;

  // ---- setup mega-launch ----
  SetupOps so{};
  int nt = 0, base = 0;
  auto addTr = [&](const float* src, __hip_bfloat16* dst, int srcK, int srcN,
                   int dstR, int dstC, int split, int soff) {
    so.src[nt] = src; so.dst[nt] = dst;
    so.srcK[nt] = srcK; so.srcN[nt] = srcN; so.dstR[nt] = dstR; so.dstC[nt] = dstC;
    so.split[nt] = split; so.soff[nt] = soff;
    int tx = (dstC + 63) / 64, ty = (dstR + 63) / 64;
    so.tileBase[nt] = base; so.tilesX[nt] = tx;
    base += tx * ty; nt++;
  };
  for (int d = 0; d < 2; d++) {
    addTr(obj_wih0 + (size_t)d * 2376 * 1024, wih0T + (size_t)d * 1024 * 2432, 2376, 1024, 1024, 2432, 0, 0);
    addTr(obj_wih1 + (size_t)d * 512 * 1024,  wih1T + (size_t)d * 1024 * 512,  512, 1024, 1024, 512, 0, 0);
    addTr(edge_wih0 + (size_t)d * 2760 * 1024, ewih0T + (size_t)d * 1024 * 2816, 2760, 1024, 1024, 2816, 0, 0);
    addTr(edge_wih1 + (size_t)d * 512 * 1024,  ewih1T + (size_t)d * 1024 * 512,  512, 1024, 1024, 512, 0, 0);
  }
  addTr(dec_w, decT, 2888, 151, 256, 2944, 512, 2376);
  so.trEnd = base;
  so.pkEnd = base + 32;
  const float* whhs[4] = {obj_whh0, obj_whh1, edge_whh0, edge_whh1};
  u32* pks[4] = {whh0pk, whh1pk, ewhh0pk, ewhh1pk};
  for (int i = 0; i < 4; i++) {
    so.whh[i] = whhs[i];
    so.wreg[i] = pks[i];
    so.wlds[i] = pks[i] + 81920;
    so.wsc[i]  = (float*)(pks[i] + 131072);
  }
  so.logits = obj_logits; so.fmaps = obj_fmaps; so.boxes = boxes;
  so.bn_g = bn_g; so.bn_b = bn_b; so.bn_m = bn_m; so.bn_v = bn_v;
  so.pos_w = pos_w; so.pos_b = pos_b; so.embw = obj_embed_w;
  so.FE = FE; so.FEq = FEq; so.ascFE = ascFE; so.conf = conf;
  setup_kernel<<<dim3(so.pkEnd + 4096), dim3(256), 0, stream>>>(so);

  quantw_sort_kernel<<<dim3(4128), dim3(256), 0, stream>>>(
      (const u16*)wih0T, wih0q, bsc0, (const u16*)ewih0T, ewih0q, bsc1, conf, perm);

  auto gemm = [&](const void* A, int lda, const void* B, int ldb, int K, int N,
                  float* oF, __hip_bfloat16* oB, int ldc, const float* bias) {
    int gy = (N + 127) / 128;
    gemm_kernel<<<dim3(32 * gy), dim3(256), 0, stream>>>(
        (const u16*)A, lda, (const u16*)B, ldb, K, N, gy, oF, oB, ldc, bias);
  };
  auto gemm_i8 = [&](const u8* A, int lda, const u8* B, int ldb, int K, int N,
                     const float* asc, const float* bsc,
                     __hip_bfloat16* oB, int ldc, const float* bias) {
    int gy = (N + 127) / 128;
    gemm_i8_kernel<<<dim3(32 * gy), dim3(256), 0, stream>>>(
        A, lda, B, ldb, K, N, gy, asc, bsc, oB, ldc, bias);
  };
  auto rec = [&](const __hip_bfloat16* P, const u32* wpk, int gat, int op,
                 __hip_bfloat16* ob, int old_, float* of, int fld, int foff) {
    rec_kernel<<<dim3(64), dim3(1024), 0, stream>>>(
        P, perm, wpk, (const uint4*)(wpk + 81920), (const float*)(wpk + 131072),
        gat, op, ob, old_, of, fld, foff);
  };

  // obj layer 0 (i8)
  gemm_i8(FEq, 2432, wih0q, 2432, 2432, 2048, ascFE, bsc0, Pbuf, 2048, obj_b0);
  rec(Pbuf, whh0pk, 1, 0, hseq, 512, nullptr, 0, 0);
  // obj layer 1 -> enc into FE cols [0,512)
  gemm(hseq, 512, wih1T, 512, 512, 2048, nullptr, Pbuf, 2048, obj_b1);
  rec(Pbuf, whh1pk, 0, 1, FE, FE_LD, nullptr, 0, 0);
  // decoder -> out cols [0,151)
  gemm(FE, FE_LD, decT, 2944, 2944, 151, out, nullptr, 663, dec_b);
  // fused argmax + edge build + quant
  argmax_edge_kernel<<<dim3(4096), dim3(256), 0, stream>>>(
      out, obj_embed2_w, obj_fmaps, FE, EDGEq, ascEDGE);
  // edge layer 0 (i8)
  gemm_i8(EDGEq, 2816, ewih0q, 2816, 2816, 2048, ascEDGE, bsc1, Pbuf, 2048, edge_b0);
  rec(Pbuf, ewhh0pk, 1, 0, hseq, 512, nullptr, 0, 0);
  // edge layer 1 -> out cols [151,663)
  gemm(hseq, 512, ewih1T, 512, 512, 2048, nullptr, Pbuf, 2048, edge_b1);
  rec(Pbuf, ewhh1pk, 0, 1, nullptr, 0, out, 663, 151);
}